// Round 16
// baseline (242.672 us; speedup 1.0000x reference)
//
#include <hip/hip_runtime.h>
#include <math.h>

// FactorizedSpectralConv2d: pruned-DFT + TT contraction, MFMA everywhere matmul-shaped.
//
//   k_prepTables: split-bf16 A-frag tables FH/IH + FW B-frags + invW E B-frags + a A-frags
//   k_g         : g[r][j][x][y] = sum_k cc[j,x,k]*dc[k,y]  (G in then-dead OF region)
//   k_prepBG    : bf16 frag tables for b (A) and g (B) from G
//   k_stage1m   : W-DFT of x via MFMA -> Yt 4 bf16 planes [h/8][p][8] (LDS-staged twiddles)
//   k_cmfma     : XF[k][p] = sum_h FH[k][h] Yt[h][p]    (split-bf16 complex MFMA)
//   k_contractA : MFMA w-GEMM + fp32 t-update; XF tile staged in LDS (kills 4x per-wave
//                 re-read of shared XF data); t written as bf16-HI frag planes tA (2 planes)
//   k_amfma     : OF[o,(k,b,m)] = sum_i a[o,i] tA[i,(k,b,m)]  (a split, t hi-only; 8 MFMAs)
//   k_ihinv     : FUSED per-bo block: phase1 Z = IH·OF (OF split on the fly, Z -> LDS bf16-hi
//                 XOR-swizzled); phase2 out = Re(Z . E) via MFMA from LDS.

#define TWO_PI 6.28318530717958647692f

typedef __attribute__((ext_vector_type(8))) short short8v;   // 8 bf16 (4 VGPRs)
typedef __attribute__((ext_vector_type(4))) float float4v;   // MFMA C/D

namespace {
constexpr size_t P_ = 32768;            // B*C*KW pixel batch width

// workspace float offsets
constexpr size_t oYT = 0;                     // Yt: 4 planes [32][32768][8] bf16 = 16.77M floats
                                              //   then bA/gB + tA (contract)
constexpr size_t oTA = 1048576;               // tA: 2 planes [8][32768][8] bf16
constexpr size_t oXF = 16777216;              // XF f2 33.5MB
constexpr size_t oOF = 25165824;              // G f2 (2MB, until prepBG) then OF f2 33.5MB
constexpr size_t oBF = 33554432;              // FW B-frag table: 65536 shorts
constexpr size_t oAF1 = 33587200;             // FH frags: 196608 shorts
constexpr size_t oAF2 = 33685504;             // IH frags: 196608 shorts
constexpr size_t oG  = 33792000;              // AFa (98304 shorts) then EF (32768 shorts)
constexpr size_t oEF = oG + 262144;
constexpr size_t WS_FLOATS = oG + 524288;     // ~137.3 MB
}

__device__ __forceinline__ unsigned short f2bf(float f) {   // RNE float->bf16 bits
    unsigned int u = __float_as_uint(f);
    unsigned int r = (u + 0x7FFFu + ((u >> 16) & 1u)) >> 16;
    return (unsigned short)r;
}
__device__ __forceinline__ float bf2f(unsigned short b) {
    return __uint_as_float(((unsigned int)b) << 16);
}

// All static fragment tables in one launch.
__global__ __launch_bounds__(256) void k_prepTables(const float* __restrict__ a1,
                                                    const float* __restrict__ a2,
                                                    unsigned short* __restrict__ AF1,
                                                    unsigned short* __restrict__ AF2,
                                                    unsigned short* __restrict__ BF,
                                                    unsigned short* __restrict__ EF,
                                                    unsigned short* __restrict__ AFa) {
    int idx = blockIdx.x * 256 + threadIdx.x;      // < 589824
    if (idx < 393216) {
        int tbl = (idx >= 196608);
        int id = tbl ? (idx - 196608) : idx;
        int e = id & 7, lane = (id >> 3) & 63;
        int pl = id >> 15;
        float ang;
        if (!tbl) {
            int rt = (id >> 9) & 7, kc = (id >> 12) & 7;
            int r = rt * 16 + (lane & 15);             // k-row (128)
            int s = kc * 32 + 8 * (lane >> 4) + e;     // h (256)
            int kh = r + ((r >= 64) ? 128 : 0);
            int ph = (kh * s) & 255;
            ang = -TWO_PI * (float)ph / 256.0f;
        } else {
            int rt = (id >> 9) & 15, kc = (id >> 13) & 3;
            int r = rt * 16 + (lane & 15);             // h (256)
            int s = kc * 32 + 8 * (lane >> 4) + e;     // k (128)
            int kh = s + ((s >= 64) ? 128 : 0);
            int ph = (kh * r) & 255;
            ang = TWO_PI * (float)ph / 256.0f;
        }
        float sn, cs; sincosf(ang, &sn, &cs);
        float base = (pl < 2) ? cs : ((pl < 4) ? sn : -sn);
        unsigned short hi = f2bf(base);
        unsigned short out = (pl & 1) ? f2bf(base - bf2f(hi)) : hi;
        (tbl ? AF2 : AF1)[id] = out;
    } else if (idx < 458752) {
        int id = idx - 393216;                          // < 65536
        int e = id & 7, lane = (id >> 3) & 63;
        int nt = (id >> 9) & 3, kc = (id >> 11) & 7;
        int pl = id >> 14;                              // 0..3
        int kw = nt * 16 + (lane & 15);
        int w = kc * 32 + 8 * (lane >> 4) + e;
        int ph = (w * kw) & 255;
        float ang = -TWO_PI * (float)ph / 256.0f;
        float sn, cs; sincosf(ang, &sn, &cs);
        float base = (pl < 2) ? cs : sn;
        unsigned short hi = f2bf(base);
        unsigned short out = (pl & 1) ? f2bf(base - bf2f(hi)) : hi;
        BF[id] = out;
    } else if (idx < 491520) {
        int id = idx - 458752;                          // < 32768
        int e = id & 7, lane = (id >> 3) & 63;
        int nt = (id >> 9) & 15, kc = (id >> 13) & 1, pl = id >> 14;
        int w = nt * 16 + (lane & 15);
        int kw = kc * 32 + 8 * (lane >> 4) + e;
        int ph = (kw * w) & 255;
        float ang = TWO_PI * (float)ph / 256.0f;
        float sn, cs; sincosf(ang, &sn, &cs);
        float sc = ((kw == 0) ? 1.0f : 2.0f) / 65536.0f;
        float v = (pl == 0) ? (sc * cs) : (-sc * sn);
        EF[id] = f2bf(v);
    } else {
        int id = idx - 491520;                          // < 98304
        int e = id & 7, lane = (id >> 3) & 63;
        int rt = (id >> 9) & 7, kc = (id >> 12) & 1;
        int plreg = id >> 13;                           // 0..11
        int reg = plreg / 6, pl = plreg % 6;
        int o = rt * 16 + (lane & 15);
        int i = kc * 32 + 8 * (lane >> 4) + e;
        const float* ap = reg ? a2 : a1;
        float ar = ap[(o * 64 + i) * 2 + 0];
        float ai = ap[(o * 64 + i) * 2 + 1];
        float base = (pl < 2) ? ar : ((pl < 4) ? ai : -ai);
        unsigned short hi = f2bf(base);
        unsigned short out = (pl & 1) ? f2bf(base - bf2f(hi)) : hi;
        AFa[id] = out;
    }
}

// g[r][j][x][y] = sum_k cc[j,x,k] * dc[k,y]
__global__ __launch_bounds__(256) void k_g(const float* __restrict__ c1, const float* __restrict__ d1,
                                           const float* __restrict__ c2, const float* __restrict__ d2,
                                           float2* __restrict__ G) {
    int idx = blockIdx.x * 256 + threadIdx.x;      // < 262144
    int r = idx >> 17;
    int rem = idx & 131071;
    int j = rem >> 12;
    int xy = rem & 4095;
    int xm = xy >> 6, ym = xy & 63;
    const float* cp = r ? c2 : c1;
    const float* dp = r ? d2 : d1;
    float sr = 0.f, si = 0.f;
    for (int kk = 0; kk < 32; ++kk) {
        float cr = cp[((j * 64 + xm) * 32 + kk) * 2 + 0];
        float ci = cp[((j * 64 + xm) * 32 + kk) * 2 + 1];
        float dr = dp[(kk * 64 + ym) * 2 + 0];
        float di = dp[(kk * 64 + ym) * 2 + 1];
        sr = fmaf(cr, dr, fmaf(-ci, di, sr));
        si = fmaf(cr, di, fmaf( ci, dr, si));
    }
    G[(size_t)(r * 32 + j) * 4096 + xy] = make_float2(sr, si);
}

// bf16 fragment tables for the contraction (reads G).
__global__ __launch_bounds__(256) void k_prepBG(const float* __restrict__ b1, const float* __restrict__ b2,
                                                const float2* __restrict__ G,
                                                unsigned short* __restrict__ bA,
                                                unsigned short* __restrict__ gB) {
    size_t idx = (size_t)blockIdx.x * 256 + threadIdx.x;
    if (idx < 1048576) {
        int e     = idx & 7;
        int lane  = (idx >> 3) & 63;
        int c     = (idx >> 9) & 127;
        int itile = (idx >> 16) & 3;
        int reg   = (idx >> 18) & 1;
        int plane = (idx >> 19) & 1;
        int i = itile * 16 + (lane & 15);
        int j = 8 * (lane >> 4) + e;
        const float* bp = reg ? b2 : b1;
        float v = bp[((size_t)(i * 128 + c) * 32 + j) * 2 + plane];
        bA[idx] = f2bf(v);
    } else if (idx < 1048576 + 786432) {
        size_t i2 = idx - 1048576;
        int e     = i2 & 7;
        int lane  = (i2 >> 3) & 63;
        int ytile = (i2 >> 9) & 3;
        int x     = (i2 >> 11) & 63;
        int reg   = (i2 >> 17) & 1;
        int plane = (int)(i2 >> 18);           // 0,1,2
        int y = ytile * 16 + (lane & 15);
        int j = 8 * (lane >> 4) + e;
        float2 gv = G[(size_t)(reg * 32 + j) * 4096 + x * 64 + y];
        float v = (plane == 0) ? gv.x : ((plane == 1) ? gv.y : -gv.y);
        gB[i2] = f2bf(v);
    }
}

// MFMA W-DFT v4: BF staged via LDS in 32KB barrier-synced phases (2 kc each).
__global__ __launch_bounds__(256) void k_stage1m(const float* __restrict__ x,
                                                 const unsigned short* __restrict__ BF,
                                                 unsigned short* __restrict__ Yt) {
    __shared__ __align__(16) unsigned short es[16384];   // 32 KB
    int t = threadIdx.x;
    int wave = t >> 6, lane = t & 63;
    size_t row0 = (size_t)blockIdx.x * 128 + (size_t)wave * 32;
    int colp = lane & 15, rowq = lane >> 4;
    const short8v* esv = (const short8v*)es;

    float4v accR[2][4], accI[2][4];
#pragma unroll
    for (int rt = 0; rt < 2; ++rt)
#pragma unroll
        for (int nt = 0; nt < 4; ++nt) {
            accR[rt][nt] = (float4v){0.f, 0.f, 0.f, 0.f};
            accI[rt][nt] = (float4v){0.f, 0.f, 0.f, 0.f};
        }

    const float* xb0 = x + (row0 + colp) * 256 + 8 * rowq;
    const float* xb1 = xb0 + 16 * 256;
    float4 nv[2][2];
    nv[0][0] = *(const float4*)(xb0);  nv[0][1] = *(const float4*)(xb0 + 4);
    nv[1][0] = *(const float4*)(xb1);  nv[1][1] = *(const float4*)(xb1 + 4);

    const float4* bf4 = (const float4*)BF;
    for (int ph = 0; ph < 4; ++ph) {
        __syncthreads();
        {
#pragma unroll
            for (int i = 0; i < 8; ++i) {
                int idx = t + 256 * i;
                int li  = idx & 63;
                int nt  = (idx >> 6) & 3;
                int kcl = (idx >> 8) & 1;
                int pl  = idx >> 9;
                ((float4*)es)[idx] = bf4[((size_t)(pl * 8 + ph * 2 + kcl) * 4 + nt) * 64 + li];
            }
        }
        __syncthreads();
        for (int kcl = 0; kcl < 2; ++kcl) {
            int kc = ph * 2 + kcl;
            short8v xh[2];
#pragma unroll
            for (int rt = 0; rt < 2; ++rt) {
                float4 v0 = nv[rt][0], v1 = nv[rt][1];
                float vv[8] = {v0.x, v0.y, v0.z, v0.w, v1.x, v1.y, v1.z, v1.w};
#pragma unroll
                for (int j = 0; j < 8; ++j) xh[rt][j] = (short)f2bf(vv[j]);
            }
            if (kc < 7) {
                nv[0][0] = *(const float4*)(xb0 + (kc + 1) * 32);
                nv[0][1] = *(const float4*)(xb0 + (kc + 1) * 32 + 4);
                nv[1][0] = *(const float4*)(xb1 + (kc + 1) * 32);
                nv[1][1] = *(const float4*)(xb1 + (kc + 1) * 32 + 4);
            }
#pragma unroll
            for (int nt = 0; nt < 4; ++nt) {
                short8v Bch = esv[((0 * 2 + kcl) * 4 + nt) * 64 + lane];
                short8v Bcl = esv[((1 * 2 + kcl) * 4 + nt) * 64 + lane];
                short8v Bsh = esv[((2 * 2 + kcl) * 4 + nt) * 64 + lane];
                short8v Bsl = esv[((3 * 2 + kcl) * 4 + nt) * 64 + lane];
#pragma unroll
                for (int rt = 0; rt < 2; ++rt) {
                    float4v r_ = accR[rt][nt];
                    r_ = __builtin_amdgcn_mfma_f32_16x16x32_bf16(xh[rt], Bch, r_, 0, 0, 0);
                    r_ = __builtin_amdgcn_mfma_f32_16x16x32_bf16(xh[rt], Bcl, r_, 0, 0, 0);
                    accR[rt][nt] = r_;
                    float4v i_ = accI[rt][nt];
                    i_ = __builtin_amdgcn_mfma_f32_16x16x32_bf16(xh[rt], Bsh, i_, 0, 0, 0);
                    i_ = __builtin_amdgcn_mfma_f32_16x16x32_bf16(xh[rt], Bsl, i_, 0, 0, 0);
                    accI[rt][nt] = i_;
                }
            }
        }
    }

    short* Yts = (short*)Yt;
    const size_t PLY = (size_t)32 * 32768 * 8;
#pragma unroll
    for (int rt = 0; rt < 2; ++rt) {
        size_t xrow0 = row0 + rt * 16 + rowq * 4;
        int h = (int)(xrow0 & 255), bc = (int)(xrow0 >> 8);
        size_t gbase = (size_t)(h >> 3) * 32768;
        int e0 = h & 7;
#pragma unroll
        for (int nt = 0; nt < 4; ++nt) {
            size_t p = (size_t)bc * 64 + nt * 16 + colp;
            size_t off = (gbase + p) * 8 + e0;
            float4v R = accR[rt][nt], I = accI[rt][nt];
            short rh[4], rl[4], ih[4], il[4];
#pragma unroll
            for (int q = 0; q < 4; ++q) {
                unsigned short h1 = f2bf(R[q]);
                rh[q] = (short)h1; rl[q] = (short)f2bf(R[q] - bf2f(h1));
                unsigned short h2 = f2bf(I[q]);
                ih[q] = (short)h2; il[q] = (short)f2bf(I[q] - bf2f(h2));
            }
            *(short4*)&Yts[0 * PLY + off] = make_short4(rh[0], rh[1], rh[2], rh[3]);
            *(short4*)&Yts[1 * PLY + off] = make_short4(rl[0], rl[1], rl[2], rl[3]);
            *(short4*)&Yts[2 * PLY + off] = make_short4(ih[0], ih[1], ih[2], ih[3]);
            *(short4*)&Yts[3 * PLY + off] = make_short4(il[0], il[1], il[2], il[3]);
        }
    }
}

// Split-bf16 complex MFMA GEMM (FH: Yt -> XF).
template<int S, int RT_W>
__global__ __launch_bounds__(256) void k_cmfma(const unsigned short* __restrict__ AF,
                                               const unsigned short* __restrict__ Bt,
                                               float2* __restrict__ Out) {
    constexpr int KC = S / 32;
    constexpr int SG = S / 8;
    constexpr int RTOT = RT_W * 4;
    __shared__ __align__(16) unsigned short bs[4 * SG * 16 * 8];
    int t = threadIdx.x;
    int wave = t >> 6, lane = t & 63;
    int rt0 = wave * RT_W;
    int colp = lane & 15, rowq = lane >> 4;
    const short8v* AFv = (const short8v*)AF;
    const short8v* bsv = (const short8v*)bs;
    const size_t PLA = (size_t)KC * RTOT * 64;

    for (int pt = 0; pt < 4; ++pt) {
        int p0 = blockIdx.x * 64 + pt * 16;
        __syncthreads();
        {
            const float4* src = (const float4*)Bt;
            float4* dst = (float4*)bs;
            for (int e = t; e < 4 * SG * 16; e += 256) {
                int pl = e / (SG * 16); int rem = e - pl * (SG * 16);
                int g = rem >> 4, li = rem & 15;
                dst[e] = src[((size_t)pl * SG + g) * 32768 + p0 + li];
            }
        }
        __syncthreads();
        float4v accR[RT_W], accI[RT_W];
#pragma unroll
        for (int rt = 0; rt < RT_W; ++rt) {
            accR[rt] = (float4v){0.f, 0.f, 0.f, 0.f};
            accI[rt] = (float4v){0.f, 0.f, 0.f, 0.f};
        }
#pragma unroll
        for (int kc = 0; kc < KC; ++kc) {
            int gi = kc * 4 + rowq;
            short8v Brh = bsv[((0 * SG + gi) << 4) + colp];
            short8v Brl = bsv[((1 * SG + gi) << 4) + colp];
            short8v Bih = bsv[((2 * SG + gi) << 4) + colp];
            short8v Bil = bsv[((3 * SG + gi) << 4) + colp];
#pragma unroll
            for (int rt = 0; rt < RT_W; ++rt) {
                size_t ab = ((size_t)kc * RTOT + rt0 + rt) * 64 + lane;
                short8v A0 = AFv[0 * PLA + ab];
                short8v A1 = AFv[1 * PLA + ab];
                short8v A2 = AFv[2 * PLA + ab];
                short8v A3 = AFv[3 * PLA + ab];
                short8v A4 = AFv[4 * PLA + ab];
                short8v A5 = AFv[5 * PLA + ab];
                float4v r_ = accR[rt];
                r_ = __builtin_amdgcn_mfma_f32_16x16x32_bf16(A0, Brh, r_, 0, 0, 0);
                r_ = __builtin_amdgcn_mfma_f32_16x16x32_bf16(A0, Brl, r_, 0, 0, 0);
                r_ = __builtin_amdgcn_mfma_f32_16x16x32_bf16(A1, Brh, r_, 0, 0, 0);
                r_ = __builtin_amdgcn_mfma_f32_16x16x32_bf16(A4, Bih, r_, 0, 0, 0);
                r_ = __builtin_amdgcn_mfma_f32_16x16x32_bf16(A4, Bil, r_, 0, 0, 0);
                r_ = __builtin_amdgcn_mfma_f32_16x16x32_bf16(A5, Bih, r_, 0, 0, 0);
                accR[rt] = r_;
                float4v i_ = accI[rt];
                i_ = __builtin_amdgcn_mfma_f32_16x16x32_bf16(A2, Brh, i_, 0, 0, 0);
                i_ = __builtin_amdgcn_mfma_f32_16x16x32_bf16(A2, Brl, i_, 0, 0, 0);
                i_ = __builtin_amdgcn_mfma_f32_16x16x32_bf16(A3, Brh, i_, 0, 0, 0);
                i_ = __builtin_amdgcn_mfma_f32_16x16x32_bf16(A0, Bih, i_, 0, 0, 0);
                i_ = __builtin_amdgcn_mfma_f32_16x16x32_bf16(A0, Bil, i_, 0, 0, 0);
                i_ = __builtin_amdgcn_mfma_f32_16x16x32_bf16(A1, Bih, i_, 0, 0, 0);
                accI[rt] = i_;
            }
        }
#pragma unroll
        for (int rt = 0; rt < RT_W; ++rt) {
            int rbase = (rt0 + rt) * 16 + rowq * 4;
#pragma unroll
            for (int q = 0; q < 4; ++q)
                Out[(size_t)(rbase + q) * P_ + p0 + colp] = make_float2(accR[rt][q], accI[rt][q]);
        }
    }
}

// MFMA contract, phase A -> tA bf16-HI only (2 planes).
// v2: XF tile (4 b x 128 c x 16 y = 64 KB) staged in LDS once per block — removes the
// 4x per-wave redundant global re-read (~1 GB -> 33.5 MB of L2/L3 traffic).
__global__ __launch_bounds__(256) void k_contractA(const float2* __restrict__ XF,
                                                   const unsigned short* __restrict__ bA,
                                                   const unsigned short* __restrict__ gB,
                                                   unsigned short* __restrict__ tA) {
    __shared__ __align__(16) float2 xfs[4][128][16];   // 64 KB
    int t = threadIdx.x;
    int k = blockIdx.x >> 2;
    int ytile = blockIdx.x & 3;
    int y0 = ytile << 4;
    int reg = (k >= 64) ? 1 : 0;
    int x = k & 63;
    int itile = t >> 6, lane = t & 63;
    int ylane = lane & 15, qg = lane >> 4;

    {   // stage XF tile: 4096 float4, 16 per thread
        const float4* src = (const float4*)XF;
        float4* dst = (float4*)xfs;
        size_t kbase = ((size_t)k * 32768 + y0) >> 1;   // float4 units
#pragma unroll
        for (int i = 0; i < 16; ++i) {
            int e = t + 256 * i;
            int f4w = e & 7;          // which float4 within the 16-f2 row
            int bc  = e >> 3;         // b*128 + c
            int b   = bc >> 7, c = bc & 127;
            dst[e] = src[kbase + (size_t)b * 4096 + (size_t)c * 32 + f4w];
        }
    }

    const short8v* gBv = (const short8v*)gB;
    short8v g_r  = gBv[(((size_t)(0 * 2 + reg) * 64 + x) * 4 + ytile) * 64 + lane];
    short8v g_i  = gBv[(((size_t)(1 * 2 + reg) * 64 + x) * 4 + ytile) * 64 + lane];
    short8v g_ni = gBv[(((size_t)(2 * 2 + reg) * 64 + x) * 4 + ytile) * 64 + lane];

    const short8v* bAv = (const short8v*)bA;
    size_t aR = (((size_t)(0 * 2 + reg) * 4 + itile) * 128) * 64 + lane;
    size_t aI = (((size_t)(1 * 2 + reg) * 4 + itile) * 128) * 64 + lane;

    float tr[4][4], ti[4][4];
#pragma unroll
    for (int q = 0; q < 4; ++q)
#pragma unroll
        for (int b = 0; b < 4; ++b) { tr[q][b] = 0.f; ti[q][b] = 0.f; }

    __syncthreads();     // XF tile ready

#pragma unroll 2
    for (int c = 0; c < 128; ++c) {
        short8v av = bAv[aR + (size_t)c * 64];
        short8v aw = bAv[aI + (size_t)c * 64];
        float4v z4 = {0.f, 0.f, 0.f, 0.f};
        float4v wr = __builtin_amdgcn_mfma_f32_16x16x32_bf16(av, g_r, z4, 0, 0, 0);
        wr = __builtin_amdgcn_mfma_f32_16x16x32_bf16(aw, g_ni, wr, 0, 0, 0);
        float4v wi = __builtin_amdgcn_mfma_f32_16x16x32_bf16(av, g_i, z4, 0, 0, 0);
        wi = __builtin_amdgcn_mfma_f32_16x16x32_bf16(aw, g_r, wi, 0, 0, 0);
#pragma unroll
        for (int b = 0; b < 4; ++b) {
            float2 xv = xfs[b][c][ylane];
#pragma unroll
            for (int q = 0; q < 4; ++q) {
                tr[q][b] = fmaf(wr[q], xv.x, fmaf(-wi[q], xv.y, tr[q][b]));
                ti[q][b] = fmaf(wr[q], xv.y, fmaf( wi[q], xv.x, ti[q][b]));
            }
        }
    }

    short* tAs = (short*)tA;
    const size_t PLT = (size_t)8 * 32768 * 8;     // plane stride (shorts)
    int gidx = itile * 2 + (qg >> 1);
    int e0 = (qg & 1) * 4;
#pragma unroll
    for (int b = 0; b < 4; ++b) {
        size_t col = (size_t)k * 256 + (size_t)b * 64 + y0 + ylane;
        size_t off = ((size_t)gidx * 32768 + col) * 8 + e0;
        short rh[4], ih[4];
#pragma unroll
        for (int q = 0; q < 4; ++q) {
            rh[q] = (short)f2bf(tr[q][b]);
            ih[q] = (short)f2bf(ti[q][b]);
        }
        *(short4*)&tAs[0 * PLT + off] = make_short4(rh[0], rh[1], rh[2], rh[3]);
        *(short4*)&tAs[1 * PLT + off] = make_short4(ih[0], ih[1], ih[2], ih[3]);
    }
}

// MFMA contract, phase B -> OF fp32. (a split-bf16, t bf16-hi: 8 MFMAs per (kc,rt))
__global__ __launch_bounds__(256) void k_amfma(const unsigned short* __restrict__ AFa,
                                               const unsigned short* __restrict__ tA,
                                               float2* __restrict__ OF) {
    constexpr int SG = 8;
    __shared__ __align__(16) unsigned short bs[2 * SG * 16 * 8];   // 4 KB
    int t = threadIdx.x;
    int wave = t >> 6, lane = t & 63;
    int rt0 = wave * 2;
    int colp = lane & 15, rowq = lane >> 4;
    int k = blockIdx.x >> 2, b = blockIdx.x & 3;
    int reg = (k >= 64) ? 1 : 0;
    const short8v* AFv = (const short8v*)(AFa + (size_t)reg * 6 * 2 * 8 * 512);
    const size_t PLA = 2 * 8 * 64;
    const short8v* bsv = (const short8v*)bs;
    size_t p0 = (size_t)blockIdx.x * 64;

    for (int pt = 0; pt < 4; ++pt) {
        __syncthreads();
        {   // stage 2 planes x 8 groups x 16 cols = 256 float4 (1/thread)
            const float4* src = (const float4*)tA;
            float4* dst = (float4*)bs;
            int e = t;
            int pl = e >> 7; int rem = e & 127;
            int g = rem >> 4, li = rem & 15;
            dst[e] = src[((size_t)pl * SG + g) * 32768 + p0 + pt * 16 + li];
        }
        __syncthreads();
        float4v accR[2], accI[2];
#pragma unroll
        for (int rt = 0; rt < 2; ++rt) {
            accR[rt] = (float4v){0.f, 0.f, 0.f, 0.f};
            accI[rt] = (float4v){0.f, 0.f, 0.f, 0.f};
        }
#pragma unroll
        for (int kc = 0; kc < 2; ++kc) {
            int gi = kc * 4 + rowq;
            short8v Brh = bsv[((0 * SG + gi) << 4) + colp];
            short8v Bih = bsv[((1 * SG + gi) << 4) + colp];
#pragma unroll
            for (int rt = 0; rt < 2; ++rt) {
                size_t ab = ((size_t)kc * 8 + rt0 + rt) * 64 + lane;
                short8v A0 = AFv[0 * PLA + ab];
                short8v A1 = AFv[1 * PLA + ab];
                short8v A2 = AFv[2 * PLA + ab];
                short8v A3 = AFv[3 * PLA + ab];
                short8v A4 = AFv[4 * PLA + ab];
                short8v A5 = AFv[5 * PLA + ab];
                float4v r_ = accR[rt];
                r_ = __builtin_amdgcn_mfma_f32_16x16x32_bf16(A0, Brh, r_, 0, 0, 0);
                r_ = __builtin_amdgcn_mfma_f32_16x16x32_bf16(A1, Brh, r_, 0, 0, 0);
                r_ = __builtin_amdgcn_mfma_f32_16x16x32_bf16(A4, Bih, r_, 0, 0, 0);
                r_ = __builtin_amdgcn_mfma_f32_16x16x32_bf16(A5, Bih, r_, 0, 0, 0);
                accR[rt] = r_;
                float4v i_ = accI[rt];
                i_ = __builtin_amdgcn_mfma_f32_16x16x32_bf16(A2, Brh, i_, 0, 0, 0);
                i_ = __builtin_amdgcn_mfma_f32_16x16x32_bf16(A3, Brh, i_, 0, 0, 0);
                i_ = __builtin_amdgcn_mfma_f32_16x16x32_bf16(A0, Bih, i_, 0, 0, 0);
                i_ = __builtin_amdgcn_mfma_f32_16x16x32_bf16(A1, Bih, i_, 0, 0, 0);
                accI[rt] = i_;
            }
        }
        int m = pt * 16 + colp;
#pragma unroll
        for (int rt = 0; rt < 2; ++rt) {
            int o0 = (rt0 + rt) * 16 + rowq * 4;
#pragma unroll
            for (int q = 0; q < 4; ++q)
                OF[(size_t)k * 32768 + (size_t)b * 8192 + (size_t)(o0 + q) * 64 + m] =
                    make_float2(accR[rt][q], accI[rt][q]);
        }
    }
}

// FUSED IH-GEMM + inverse-W MFMA. Block = one bo (b*128+o), 512 threads (8 waves).
__global__ __launch_bounds__(512) void k_ihinv(const unsigned short* __restrict__ AF2,
                                               const float2* __restrict__ OF,
                                               const unsigned short* __restrict__ EF,
                                               float* __restrict__ out) {
    constexpr int SG = 16, KC = 4, RTOT = 16;
    __shared__ __align__(16) unsigned short zs[2 * 256 * 64];     // 64 KB
    __shared__ __align__(16) unsigned short bs[4 * SG * 16 * 8];  // 16 KB
    int t = threadIdx.x;
    int wave = t >> 6, lane = t & 63;
    int colp = lane & 15, rowq = lane >> 4;
    int rt0 = wave * 2;
    int bo = blockIdx.x;
    size_t p0 = (size_t)bo * 64;
    const short8v* AFv = (const short8v*)AF2;
    const short8v* bsv = (const short8v*)bs;
    const size_t PLA = (size_t)KC * RTOT * 64;

    for (int pt = 0; pt < 4; ++pt) {
        __syncthreads();
        {   // stage B tile from OF fp32 (split hi/lo): 512 threads x 4 rows each
            int li = t & 15, g = (t >> 4) & 15, half = t >> 8;
            int e0 = half * 4;
            short rh[4], rl[4], ih[4], il[4];
#pragma unroll
            for (int j = 0; j < 4; ++j) {
                float2 v = OF[(size_t)(g * 8 + e0 + j) * P_ + p0 + pt * 16 + li];
                unsigned short h1 = f2bf(v.x);
                rh[j] = (short)h1; rl[j] = (short)f2bf(v.x - bf2f(h1));
                unsigned short h2 = f2bf(v.y);
                ih[j] = (short)h2; il[j] = (short)f2bf(v.y - bf2f(h2));
            }
            int base = (g * 16 + li) * 8 + e0;
            *(short4*)&bs[0 * 2048 + base] = make_short4(rh[0], rh[1], rh[2], rh[3]);
            *(short4*)&bs[1 * 2048 + base] = make_short4(rl[0], rl[1], rl[2], rl[3]);
            *(short4*)&bs[2 * 2048 + base] = make_short4(ih[0], ih[1], ih[2], ih[3]);
            *(short4*)&bs[3 * 2048 + base] = make_short4(il[0], il[1], il[2], il[3]);
        }
        __syncthreads();
        float4v accR[2], accI[2];
#pragma unroll
        for (int rt = 0; rt < 2; ++rt) {
            accR[rt] = (float4v){0.f, 0.f, 0.f, 0.f};
            accI[rt] = (float4v){0.f, 0.f, 0.f, 0.f};
        }
#pragma unroll
        for (int kc = 0; kc < KC; ++kc) {
            int gi = kc * 4 + rowq;
            short8v Brh = bsv[((0 * SG + gi) << 4) + colp];
            short8v Brl = bsv[((1 * SG + gi) << 4) + colp];
            short8v Bih = bsv[((2 * SG + gi) << 4) + colp];
            short8v Bil = bsv[((3 * SG + gi) << 4) + colp];
#pragma unroll
            for (int rt = 0; rt < 2; ++rt) {
                size_t ab = ((size_t)kc * RTOT + rt0 + rt) * 64 + lane;
                short8v A0 = AFv[0 * PLA + ab];
                short8v A1 = AFv[1 * PLA + ab];
                short8v A2 = AFv[2 * PLA + ab];
                short8v A3 = AFv[3 * PLA + ab];
                short8v A4 = AFv[4 * PLA + ab];
                short8v A5 = AFv[5 * PLA + ab];
                float4v r_ = accR[rt];
                r_ = __builtin_amdgcn_mfma_f32_16x16x32_bf16(A0, Brh, r_, 0, 0, 0);
                r_ = __builtin_amdgcn_mfma_f32_16x16x32_bf16(A0, Brl, r_, 0, 0, 0);
                r_ = __builtin_amdgcn_mfma_f32_16x16x32_bf16(A1, Brh, r_, 0, 0, 0);
                r_ = __builtin_amdgcn_mfma_f32_16x16x32_bf16(A4, Bih, r_, 0, 0, 0);
                r_ = __builtin_amdgcn_mfma_f32_16x16x32_bf16(A4, Bil, r_, 0, 0, 0);
                r_ = __builtin_amdgcn_mfma_f32_16x16x32_bf16(A5, Bih, r_, 0, 0, 0);
                accR[rt] = r_;
                float4v i_ = accI[rt];
                i_ = __builtin_amdgcn_mfma_f32_16x16x32_bf16(A2, Brh, i_, 0, 0, 0);
                i_ = __builtin_amdgcn_mfma_f32_16x16x32_bf16(A2, Brl, i_, 0, 0, 0);
                i_ = __builtin_amdgcn_mfma_f32_16x16x32_bf16(A3, Brh, i_, 0, 0, 0);
                i_ = __builtin_amdgcn_mfma_f32_16x16x32_bf16(A0, Bih, i_, 0, 0, 0);
                i_ = __builtin_amdgcn_mfma_f32_16x16x32_bf16(A0, Bil, i_, 0, 0, 0);
                i_ = __builtin_amdgcn_mfma_f32_16x16x32_bf16(A1, Bih, i_, 0, 0, 0);
                accI[rt] = i_;
            }
        }
#pragma unroll
        for (int rt = 0; rt < 2; ++rt)
#pragma unroll
            for (int q = 0; q < 4; ++q) {
                int h = (rt0 + rt) * 16 + rowq * 4 + q;
                int kwsw = (pt * 16 + colp) ^ ((h & 7) << 3);
                zs[h * 64 + kwsw] = (unsigned short)f2bf(accR[rt][q]);
                zs[16384 + h * 64 + kwsw] = (unsigned short)f2bf(accI[rt][q]);
            }
    }
    __syncthreads();

    const short8v* EFv = (const short8v*)EF;
    for (int nt = 0; nt < 16; ++nt) {
        short8v Er0  = EFv[((0 * 2 + 0) * 16 + nt) * 64 + lane];
        short8v Er1  = EFv[((0 * 2 + 1) * 16 + nt) * 64 + lane];
        short8v nEi0 = EFv[((1 * 2 + 0) * 16 + nt) * 64 + lane];
        short8v nEi1 = EFv[((1 * 2 + 1) * 16 + nt) * 64 + lane];
#pragma unroll
        for (int mtl = 0; mtl < 2; ++mtl) {
            int h0 = (wave * 2 + mtl) * 16;
            int hA = h0 + colp;
            int sw = (hA & 7) << 3;
            short8v Zr0 = *(const short8v*)&zs[hA * 64 + ((8 * rowq) ^ sw)];
            short8v Zr1 = *(const short8v*)&zs[hA * 64 + ((32 + 8 * rowq) ^ sw)];
            short8v Zi0 = *(const short8v*)&zs[16384 + hA * 64 + ((8 * rowq) ^ sw)];
            short8v Zi1 = *(const short8v*)&zs[16384 + hA * 64 + ((32 + 8 * rowq) ^ sw)];
            float4v acc = {0.f, 0.f, 0.f, 0.f};
            acc = __builtin_amdgcn_mfma_f32_16x16x32_bf16(Zr0, Er0,  acc, 0, 0, 0);
            acc = __builtin_amdgcn_mfma_f32_16x16x32_bf16(Zi0, nEi0, acc, 0, 0, 0);
            acc = __builtin_amdgcn_mfma_f32_16x16x32_bf16(Zr1, Er1,  acc, 0, 0, 0);
            acc = __builtin_amdgcn_mfma_f32_16x16x32_bf16(Zi1, nEi1, acc, 0, 0, 0);
            size_t ob = ((size_t)bo * 256 + h0 + rowq * 4) * 256 + nt * 16 + colp;
#pragma unroll
            for (int q = 0; q < 4; ++q)
                out[ob + (size_t)q * 256] = acc[q];
        }
    }
}

extern "C" void kernel_launch(void* const* d_in, const int* in_sizes, int n_in,
                              void* d_out, int out_size, void* d_ws, size_t ws_size,
                              hipStream_t stream) {
    const float* x  = (const float*)d_in[0];
    const float* a1 = (const float*)d_in[1];
    const float* b1 = (const float*)d_in[2];
    const float* c1 = (const float*)d_in[3];
    const float* d1 = (const float*)d_in[4];
    const float* a2 = (const float*)d_in[5];
    const float* b2 = (const float*)d_in[6];
    const float* c2 = (const float*)d_in[7];
    const float* d2 = (const float*)d_in[8];
    float* out = (float*)d_out;
    float* wsf = (float*)d_ws;

    if (ws_size < WS_FLOATS * sizeof(float)) return;

    unsigned short* Yt  = (unsigned short*)(wsf + oYT);
    float2*         XF  = (float2*)(wsf + oXF);
    float2*         OF  = (float2*)(wsf + oOF);
    float2*         G   = (float2*)(wsf + oOF);          // G lives in OF region until prepBG
    unsigned short* BF  = (unsigned short*)(wsf + oBF);
    unsigned short* AF1 = (unsigned short*)(wsf + oAF1);
    unsigned short* AF2 = (unsigned short*)(wsf + oAF2);
    unsigned short* bA  = (unsigned short*)(wsf + oYT);  // after cmfma1, Yt region is dead
    unsigned short* gB  = bA + 1048576;
    unsigned short* tA  = (unsigned short*)(wsf + oTA);
    unsigned short* AFa = (unsigned short*)(wsf + oG);
    unsigned short* EF  = (unsigned short*)(wsf + oEF);

    k_prepTables<<<2304, 256, 0, stream>>>(a1, a2, AF1, AF2, BF, EF, AFa);
    k_g<<<1024, 256, 0, stream>>>(c1, d1, c2, d2, G);
    k_stage1m<<<1024, 256, 0, stream>>>(x, BF, Yt);
    k_cmfma<256, 2><<<512, 256, 0, stream>>>(AF1, Yt, XF);
    k_prepBG<<<7168, 256, 0, stream>>>(b1, b2, G, bA, gB);
    k_contractA<<<512, 256, 0, stream>>>(XF, bA, gB, tA);
    k_amfma<<<512, 256, 0, stream>>>(AFa, tA, OF);       // overwrites G (dead after prepBG)
    k_ihinv<<<512, 512, 0, stream>>>(AF2, OF, EF, out);

    (void)in_sizes; (void)n_in; (void)out_size;
}

// Round 17
// 235.059 us; speedup vs baseline: 1.0324x; 1.0324x over previous
//
#include <hip/hip_runtime.h>
#include <math.h>

// FactorizedSpectralConv2d: pruned-DFT + TT contraction, MFMA everywhere matmul-shaped.
//
//   k_prepTables: split-bf16 A-frag tables FH/IH + FW B-frags + invW E B-frags + a A-frags
//   k_g         : g[r][j][x][y] = sum_k cc[j,x,k]*dc[k,y]  (G in then-dead OF region)
//   k_prepBG    : bf16 frag tables for b (A) and g (B) from G
//   k_stage1m   : W-DFT of x via MFMA -> Yt 4 bf16 planes [h/8][p][8] (LDS-staged twiddles)
//   k_cmfma     : XFh[k][p] = sum_h FH[k][h] Yt[h][p], packed bf16-hi (re|im<<16) in u32
//   k_contractA : MFMA w-GEMM + fp32 t-update; packed XFh tile staged in 32KB LDS;
//                 t written as bf16-HI frag planes tA (2 planes)
//   k_amfma     : OF[o,(k,b,m)] = sum_i a[o,i] tA[i,(k,b,m)]  (a split, t hi-only; 8 MFMAs)
//   k_ihinv     : FUSED per-bo block: phase1 Z = IH·OF (OF split on the fly, Z -> LDS bf16-hi
//                 XOR-swizzled); phase2 out = Re(Z . E) via MFMA from LDS.

#define TWO_PI 6.28318530717958647692f

typedef __attribute__((ext_vector_type(8))) short short8v;   // 8 bf16 (4 VGPRs)
typedef __attribute__((ext_vector_type(4))) float float4v;   // MFMA C/D

namespace {
constexpr size_t P_ = 32768;            // B*C*KW pixel batch width

// workspace float offsets
constexpr size_t oYT = 0;                     // Yt: 4 planes [32][32768][8] bf16 = 16.77M floats
                                              //   then bA/gB + tA (contract)
constexpr size_t oTA = 1048576;               // tA: 2 planes [8][32768][8] bf16
constexpr size_t oXF = 16777216;              // XFh u32 16.7MB (packed bf16-hi re|im)
constexpr size_t oOF = 25165824;              // G f2 (2MB, until prepBG) then OF f2 33.5MB
constexpr size_t oBF = 33554432;              // FW B-frag table: 65536 shorts
constexpr size_t oAF1 = 33587200;             // FH frags: 196608 shorts
constexpr size_t oAF2 = 33685504;             // IH frags: 196608 shorts
constexpr size_t oG  = 33792000;              // AFa (98304 shorts) then EF (32768 shorts)
constexpr size_t oEF = oG + 262144;
constexpr size_t WS_FLOATS = oG + 524288;     // ~137.3 MB
}

__device__ __forceinline__ unsigned short f2bf(float f) {   // RNE float->bf16 bits
    unsigned int u = __float_as_uint(f);
    unsigned int r = (u + 0x7FFFu + ((u >> 16) & 1u)) >> 16;
    return (unsigned short)r;
}
__device__ __forceinline__ float bf2f(unsigned short b) {
    return __uint_as_float(((unsigned int)b) << 16);
}

// All static fragment tables in one launch.
__global__ __launch_bounds__(256) void k_prepTables(const float* __restrict__ a1,
                                                    const float* __restrict__ a2,
                                                    unsigned short* __restrict__ AF1,
                                                    unsigned short* __restrict__ AF2,
                                                    unsigned short* __restrict__ BF,
                                                    unsigned short* __restrict__ EF,
                                                    unsigned short* __restrict__ AFa) {
    int idx = blockIdx.x * 256 + threadIdx.x;      // < 589824
    if (idx < 393216) {
        int tbl = (idx >= 196608);
        int id = tbl ? (idx - 196608) : idx;
        int e = id & 7, lane = (id >> 3) & 63;
        int pl = id >> 15;
        float ang;
        if (!tbl) {
            int rt = (id >> 9) & 7, kc = (id >> 12) & 7;
            int r = rt * 16 + (lane & 15);             // k-row (128)
            int s = kc * 32 + 8 * (lane >> 4) + e;     // h (256)
            int kh = r + ((r >= 64) ? 128 : 0);
            int ph = (kh * s) & 255;
            ang = -TWO_PI * (float)ph / 256.0f;
        } else {
            int rt = (id >> 9) & 15, kc = (id >> 13) & 3;
            int r = rt * 16 + (lane & 15);             // h (256)
            int s = kc * 32 + 8 * (lane >> 4) + e;     // k (128)
            int kh = s + ((s >= 64) ? 128 : 0);
            int ph = (kh * r) & 255;
            ang = TWO_PI * (float)ph / 256.0f;
        }
        float sn, cs; sincosf(ang, &sn, &cs);
        float base = (pl < 2) ? cs : ((pl < 4) ? sn : -sn);
        unsigned short hi = f2bf(base);
        unsigned short out = (pl & 1) ? f2bf(base - bf2f(hi)) : hi;
        (tbl ? AF2 : AF1)[id] = out;
    } else if (idx < 458752) {
        int id = idx - 393216;                          // < 65536
        int e = id & 7, lane = (id >> 3) & 63;
        int nt = (id >> 9) & 3, kc = (id >> 11) & 7;
        int pl = id >> 14;                              // 0..3
        int kw = nt * 16 + (lane & 15);
        int w = kc * 32 + 8 * (lane >> 4) + e;
        int ph = (w * kw) & 255;
        float ang = -TWO_PI * (float)ph / 256.0f;
        float sn, cs; sincosf(ang, &sn, &cs);
        float base = (pl < 2) ? cs : sn;
        unsigned short hi = f2bf(base);
        unsigned short out = (pl & 1) ? f2bf(base - bf2f(hi)) : hi;
        BF[id] = out;
    } else if (idx < 491520) {
        int id = idx - 458752;                          // < 32768
        int e = id & 7, lane = (id >> 3) & 63;
        int nt = (id >> 9) & 15, kc = (id >> 13) & 1, pl = id >> 14;
        int w = nt * 16 + (lane & 15);
        int kw = kc * 32 + 8 * (lane >> 4) + e;
        int ph = (kw * w) & 255;
        float ang = TWO_PI * (float)ph / 256.0f;
        float sn, cs; sincosf(ang, &sn, &cs);
        float sc = ((kw == 0) ? 1.0f : 2.0f) / 65536.0f;
        float v = (pl == 0) ? (sc * cs) : (-sc * sn);
        EF[id] = f2bf(v);
    } else {
        int id = idx - 491520;                          // < 98304
        int e = id & 7, lane = (id >> 3) & 63;
        int rt = (id >> 9) & 7, kc = (id >> 12) & 1;
        int plreg = id >> 13;                           // 0..11
        int reg = plreg / 6, pl = plreg % 6;
        int o = rt * 16 + (lane & 15);
        int i = kc * 32 + 8 * (lane >> 4) + e;
        const float* ap = reg ? a2 : a1;
        float ar = ap[(o * 64 + i) * 2 + 0];
        float ai = ap[(o * 64 + i) * 2 + 1];
        float base = (pl < 2) ? ar : ((pl < 4) ? ai : -ai);
        unsigned short hi = f2bf(base);
        unsigned short out = (pl & 1) ? f2bf(base - bf2f(hi)) : hi;
        AFa[id] = out;
    }
}

// g[r][j][x][y] = sum_k cc[j,x,k] * dc[k,y]
__global__ __launch_bounds__(256) void k_g(const float* __restrict__ c1, const float* __restrict__ d1,
                                           const float* __restrict__ c2, const float* __restrict__ d2,
                                           float2* __restrict__ G) {
    int idx = blockIdx.x * 256 + threadIdx.x;      // < 262144
    int r = idx >> 17;
    int rem = idx & 131071;
    int j = rem >> 12;
    int xy = rem & 4095;
    int xm = xy >> 6, ym = xy & 63;
    const float* cp = r ? c2 : c1;
    const float* dp = r ? d2 : d1;
    float sr = 0.f, si = 0.f;
    for (int kk = 0; kk < 32; ++kk) {
        float cr = cp[((j * 64 + xm) * 32 + kk) * 2 + 0];
        float ci = cp[((j * 64 + xm) * 32 + kk) * 2 + 1];
        float dr = dp[(kk * 64 + ym) * 2 + 0];
        float di = dp[(kk * 64 + ym) * 2 + 1];
        sr = fmaf(cr, dr, fmaf(-ci, di, sr));
        si = fmaf(cr, di, fmaf( ci, dr, si));
    }
    G[(size_t)(r * 32 + j) * 4096 + xy] = make_float2(sr, si);
}

// bf16 fragment tables for the contraction (reads G).
__global__ __launch_bounds__(256) void k_prepBG(const float* __restrict__ b1, const float* __restrict__ b2,
                                                const float2* __restrict__ G,
                                                unsigned short* __restrict__ bA,
                                                unsigned short* __restrict__ gB) {
    size_t idx = (size_t)blockIdx.x * 256 + threadIdx.x;
    if (idx < 1048576) {
        int e     = idx & 7;
        int lane  = (idx >> 3) & 63;
        int c     = (idx >> 9) & 127;
        int itile = (idx >> 16) & 3;
        int reg   = (idx >> 18) & 1;
        int plane = (idx >> 19) & 1;
        int i = itile * 16 + (lane & 15);
        int j = 8 * (lane >> 4) + e;
        const float* bp = reg ? b2 : b1;
        float v = bp[((size_t)(i * 128 + c) * 32 + j) * 2 + plane];
        bA[idx] = f2bf(v);
    } else if (idx < 1048576 + 786432) {
        size_t i2 = idx - 1048576;
        int e     = i2 & 7;
        int lane  = (i2 >> 3) & 63;
        int ytile = (i2 >> 9) & 3;
        int x     = (i2 >> 11) & 63;
        int reg   = (i2 >> 17) & 1;
        int plane = (int)(i2 >> 18);           // 0,1,2
        int y = ytile * 16 + (lane & 15);
        int j = 8 * (lane >> 4) + e;
        float2 gv = G[(size_t)(reg * 32 + j) * 4096 + x * 64 + y];
        float v = (plane == 0) ? gv.x : ((plane == 1) ? gv.y : -gv.y);
        gB[i2] = f2bf(v);
    }
}

// MFMA W-DFT v4: BF staged via LDS in 32KB barrier-synced phases (2 kc each).
__global__ __launch_bounds__(256) void k_stage1m(const float* __restrict__ x,
                                                 const unsigned short* __restrict__ BF,
                                                 unsigned short* __restrict__ Yt) {
    __shared__ __align__(16) unsigned short es[16384];   // 32 KB
    int t = threadIdx.x;
    int wave = t >> 6, lane = t & 63;
    size_t row0 = (size_t)blockIdx.x * 128 + (size_t)wave * 32;
    int colp = lane & 15, rowq = lane >> 4;
    const short8v* esv = (const short8v*)es;

    float4v accR[2][4], accI[2][4];
#pragma unroll
    for (int rt = 0; rt < 2; ++rt)
#pragma unroll
        for (int nt = 0; nt < 4; ++nt) {
            accR[rt][nt] = (float4v){0.f, 0.f, 0.f, 0.f};
            accI[rt][nt] = (float4v){0.f, 0.f, 0.f, 0.f};
        }

    const float* xb0 = x + (row0 + colp) * 256 + 8 * rowq;
    const float* xb1 = xb0 + 16 * 256;
    float4 nv[2][2];
    nv[0][0] = *(const float4*)(xb0);  nv[0][1] = *(const float4*)(xb0 + 4);
    nv[1][0] = *(const float4*)(xb1);  nv[1][1] = *(const float4*)(xb1 + 4);

    const float4* bf4 = (const float4*)BF;
    for (int ph = 0; ph < 4; ++ph) {
        __syncthreads();
        {
#pragma unroll
            for (int i = 0; i < 8; ++i) {
                int idx = t + 256 * i;
                int li  = idx & 63;
                int nt  = (idx >> 6) & 3;
                int kcl = (idx >> 8) & 1;
                int pl  = idx >> 9;
                ((float4*)es)[idx] = bf4[((size_t)(pl * 8 + ph * 2 + kcl) * 4 + nt) * 64 + li];
            }
        }
        __syncthreads();
        for (int kcl = 0; kcl < 2; ++kcl) {
            int kc = ph * 2 + kcl;
            short8v xh[2];
#pragma unroll
            for (int rt = 0; rt < 2; ++rt) {
                float4 v0 = nv[rt][0], v1 = nv[rt][1];
                float vv[8] = {v0.x, v0.y, v0.z, v0.w, v1.x, v1.y, v1.z, v1.w};
#pragma unroll
                for (int j = 0; j < 8; ++j) xh[rt][j] = (short)f2bf(vv[j]);
            }
            if (kc < 7) {
                nv[0][0] = *(const float4*)(xb0 + (kc + 1) * 32);
                nv[0][1] = *(const float4*)(xb0 + (kc + 1) * 32 + 4);
                nv[1][0] = *(const float4*)(xb1 + (kc + 1) * 32);
                nv[1][1] = *(const float4*)(xb1 + (kc + 1) * 32 + 4);
            }
#pragma unroll
            for (int nt = 0; nt < 4; ++nt) {
                short8v Bch = esv[((0 * 2 + kcl) * 4 + nt) * 64 + lane];
                short8v Bcl = esv[((1 * 2 + kcl) * 4 + nt) * 64 + lane];
                short8v Bsh = esv[((2 * 2 + kcl) * 4 + nt) * 64 + lane];
                short8v Bsl = esv[((3 * 2 + kcl) * 4 + nt) * 64 + lane];
#pragma unroll
                for (int rt = 0; rt < 2; ++rt) {
                    float4v r_ = accR[rt][nt];
                    r_ = __builtin_amdgcn_mfma_f32_16x16x32_bf16(xh[rt], Bch, r_, 0, 0, 0);
                    r_ = __builtin_amdgcn_mfma_f32_16x16x32_bf16(xh[rt], Bcl, r_, 0, 0, 0);
                    accR[rt][nt] = r_;
                    float4v i_ = accI[rt][nt];
                    i_ = __builtin_amdgcn_mfma_f32_16x16x32_bf16(xh[rt], Bsh, i_, 0, 0, 0);
                    i_ = __builtin_amdgcn_mfma_f32_16x16x32_bf16(xh[rt], Bsl, i_, 0, 0, 0);
                    accI[rt][nt] = i_;
                }
            }
        }
    }

    short* Yts = (short*)Yt;
    const size_t PLY = (size_t)32 * 32768 * 8;
#pragma unroll
    for (int rt = 0; rt < 2; ++rt) {
        size_t xrow0 = row0 + rt * 16 + rowq * 4;
        int h = (int)(xrow0 & 255), bc = (int)(xrow0 >> 8);
        size_t gbase = (size_t)(h >> 3) * 32768;
        int e0 = h & 7;
#pragma unroll
        for (int nt = 0; nt < 4; ++nt) {
            size_t p = (size_t)bc * 64 + nt * 16 + colp;
            size_t off = (gbase + p) * 8 + e0;
            float4v R = accR[rt][nt], I = accI[rt][nt];
            short rh[4], rl[4], ih[4], il[4];
#pragma unroll
            for (int q = 0; q < 4; ++q) {
                unsigned short h1 = f2bf(R[q]);
                rh[q] = (short)h1; rl[q] = (short)f2bf(R[q] - bf2f(h1));
                unsigned short h2 = f2bf(I[q]);
                ih[q] = (short)h2; il[q] = (short)f2bf(I[q] - bf2f(h2));
            }
            *(short4*)&Yts[0 * PLY + off] = make_short4(rh[0], rh[1], rh[2], rh[3]);
            *(short4*)&Yts[1 * PLY + off] = make_short4(rl[0], rl[1], rl[2], rl[3]);
            *(short4*)&Yts[2 * PLY + off] = make_short4(ih[0], ih[1], ih[2], ih[3]);
            *(short4*)&Yts[3 * PLY + off] = make_short4(il[0], il[1], il[2], il[3]);
        }
    }
}

// Split-bf16 complex MFMA GEMM (FH: Yt -> XFh packed bf16-hi u32).
template<int S, int RT_W>
__global__ __launch_bounds__(256) void k_cmfma(const unsigned short* __restrict__ AF,
                                               const unsigned short* __restrict__ Bt,
                                               unsigned int* __restrict__ XFh) {
    constexpr int KC = S / 32;
    constexpr int SG = S / 8;
    constexpr int RTOT = RT_W * 4;
    __shared__ __align__(16) unsigned short bs[4 * SG * 16 * 8];
    int t = threadIdx.x;
    int wave = t >> 6, lane = t & 63;
    int rt0 = wave * RT_W;
    int colp = lane & 15, rowq = lane >> 4;
    const short8v* AFv = (const short8v*)AF;
    const short8v* bsv = (const short8v*)bs;
    const size_t PLA = (size_t)KC * RTOT * 64;

    for (int pt = 0; pt < 4; ++pt) {
        int p0 = blockIdx.x * 64 + pt * 16;
        __syncthreads();
        {
            const float4* src = (const float4*)Bt;
            float4* dst = (float4*)bs;
            for (int e = t; e < 4 * SG * 16; e += 256) {
                int pl = e / (SG * 16); int rem = e - pl * (SG * 16);
                int g = rem >> 4, li = rem & 15;
                dst[e] = src[((size_t)pl * SG + g) * 32768 + p0 + li];
            }
        }
        __syncthreads();
        float4v accR[RT_W], accI[RT_W];
#pragma unroll
        for (int rt = 0; rt < RT_W; ++rt) {
            accR[rt] = (float4v){0.f, 0.f, 0.f, 0.f};
            accI[rt] = (float4v){0.f, 0.f, 0.f, 0.f};
        }
#pragma unroll
        for (int kc = 0; kc < KC; ++kc) {
            int gi = kc * 4 + rowq;
            short8v Brh = bsv[((0 * SG + gi) << 4) + colp];
            short8v Brl = bsv[((1 * SG + gi) << 4) + colp];
            short8v Bih = bsv[((2 * SG + gi) << 4) + colp];
            short8v Bil = bsv[((3 * SG + gi) << 4) + colp];
#pragma unroll
            for (int rt = 0; rt < RT_W; ++rt) {
                size_t ab = ((size_t)kc * RTOT + rt0 + rt) * 64 + lane;
                short8v A0 = AFv[0 * PLA + ab];
                short8v A1 = AFv[1 * PLA + ab];
                short8v A2 = AFv[2 * PLA + ab];
                short8v A3 = AFv[3 * PLA + ab];
                short8v A4 = AFv[4 * PLA + ab];
                short8v A5 = AFv[5 * PLA + ab];
                float4v r_ = accR[rt];
                r_ = __builtin_amdgcn_mfma_f32_16x16x32_bf16(A0, Brh, r_, 0, 0, 0);
                r_ = __builtin_amdgcn_mfma_f32_16x16x32_bf16(A0, Brl, r_, 0, 0, 0);
                r_ = __builtin_amdgcn_mfma_f32_16x16x32_bf16(A1, Brh, r_, 0, 0, 0);
                r_ = __builtin_amdgcn_mfma_f32_16x16x32_bf16(A4, Bih, r_, 0, 0, 0);
                r_ = __builtin_amdgcn_mfma_f32_16x16x32_bf16(A4, Bil, r_, 0, 0, 0);
                r_ = __builtin_amdgcn_mfma_f32_16x16x32_bf16(A5, Bih, r_, 0, 0, 0);
                accR[rt] = r_;
                float4v i_ = accI[rt];
                i_ = __builtin_amdgcn_mfma_f32_16x16x32_bf16(A2, Brh, i_, 0, 0, 0);
                i_ = __builtin_amdgcn_mfma_f32_16x16x32_bf16(A2, Brl, i_, 0, 0, 0);
                i_ = __builtin_amdgcn_mfma_f32_16x16x32_bf16(A3, Brh, i_, 0, 0, 0);
                i_ = __builtin_amdgcn_mfma_f32_16x16x32_bf16(A0, Bih, i_, 0, 0, 0);
                i_ = __builtin_amdgcn_mfma_f32_16x16x32_bf16(A0, Bil, i_, 0, 0, 0);
                i_ = __builtin_amdgcn_mfma_f32_16x16x32_bf16(A1, Bih, i_, 0, 0, 0);
                accI[rt] = i_;
            }
        }
#pragma unroll
        for (int rt = 0; rt < RT_W; ++rt) {
            int rbase = (rt0 + rt) * 16 + rowq * 4;
#pragma unroll
            for (int q = 0; q < 4; ++q) {
                unsigned int pw = (unsigned int)f2bf(accR[rt][q])
                                | ((unsigned int)f2bf(accI[rt][q]) << 16);
                XFh[(size_t)(rbase + q) * P_ + p0 + colp] = pw;
            }
        }
    }
}

// MFMA contract, phase A -> tA bf16-HI only (2 planes).
// v3: packed XFh tile (4 b x 128 c x 16 y u32 = 32 KB) staged in LDS.
__global__ __launch_bounds__(256) void k_contractA(const unsigned int* __restrict__ XFh,
                                                   const unsigned short* __restrict__ bA,
                                                   const unsigned short* __restrict__ gB,
                                                   unsigned short* __restrict__ tA) {
    __shared__ __align__(16) unsigned int xfs[4][128][16];   // 32 KB
    int t = threadIdx.x;
    int k = blockIdx.x >> 2;
    int ytile = blockIdx.x & 3;
    int y0 = ytile << 4;
    int reg = (k >= 64) ? 1 : 0;
    int x = k & 63;
    int itile = t >> 6, lane = t & 63;
    int ylane = lane & 15, qg = lane >> 4;

    {   // stage XFh tile: 2048 uint4, 8 per thread
        const uint4* src = (const uint4*)XFh;
        uint4* dst = (uint4*)xfs;
        size_t kbase = ((size_t)k * 32768 + y0) >> 2;   // uint4 units
#pragma unroll
        for (int i = 0; i < 8; ++i) {
            int e = t + 256 * i;
            int f4w = e & 3;          // which uint4 within the 16-u32 row
            int bc  = e >> 2;         // b*128 + c
            int b   = bc >> 7, c = bc & 127;
            dst[e] = src[kbase + (size_t)b * 2048 + (size_t)c * 16 + f4w];
        }
    }

    const short8v* gBv = (const short8v*)gB;
    short8v g_r  = gBv[(((size_t)(0 * 2 + reg) * 64 + x) * 4 + ytile) * 64 + lane];
    short8v g_i  = gBv[(((size_t)(1 * 2 + reg) * 64 + x) * 4 + ytile) * 64 + lane];
    short8v g_ni = gBv[(((size_t)(2 * 2 + reg) * 64 + x) * 4 + ytile) * 64 + lane];

    const short8v* bAv = (const short8v*)bA;
    size_t aR = (((size_t)(0 * 2 + reg) * 4 + itile) * 128) * 64 + lane;
    size_t aI = (((size_t)(1 * 2 + reg) * 4 + itile) * 128) * 64 + lane;

    float tr[4][4], ti[4][4];
#pragma unroll
    for (int q = 0; q < 4; ++q)
#pragma unroll
        for (int b = 0; b < 4; ++b) { tr[q][b] = 0.f; ti[q][b] = 0.f; }

    __syncthreads();     // XFh tile ready

#pragma unroll 2
    for (int c = 0; c < 128; ++c) {
        short8v av = bAv[aR + (size_t)c * 64];
        short8v aw = bAv[aI + (size_t)c * 64];
        float4v z4 = {0.f, 0.f, 0.f, 0.f};
        float4v wr = __builtin_amdgcn_mfma_f32_16x16x32_bf16(av, g_r, z4, 0, 0, 0);
        wr = __builtin_amdgcn_mfma_f32_16x16x32_bf16(aw, g_ni, wr, 0, 0, 0);
        float4v wi = __builtin_amdgcn_mfma_f32_16x16x32_bf16(av, g_i, z4, 0, 0, 0);
        wi = __builtin_amdgcn_mfma_f32_16x16x32_bf16(aw, g_r, wi, 0, 0, 0);
#pragma unroll
        for (int b = 0; b < 4; ++b) {
            unsigned int xw = xfs[b][c][ylane];
            float xr = bf2f((unsigned short)(xw & 0xFFFFu));
            float xi = bf2f((unsigned short)(xw >> 16));
#pragma unroll
            for (int q = 0; q < 4; ++q) {
                tr[q][b] = fmaf(wr[q], xr, fmaf(-wi[q], xi, tr[q][b]));
                ti[q][b] = fmaf(wr[q], xi, fmaf( wi[q], xr, ti[q][b]));
            }
        }
    }

    short* tAs = (short*)tA;
    const size_t PLT = (size_t)8 * 32768 * 8;     // plane stride (shorts)
    int gidx = itile * 2 + (qg >> 1);
    int e0 = (qg & 1) * 4;
#pragma unroll
    for (int b = 0; b < 4; ++b) {
        size_t col = (size_t)k * 256 + (size_t)b * 64 + y0 + ylane;
        size_t off = ((size_t)gidx * 32768 + col) * 8 + e0;
        short rh[4], ih[4];
#pragma unroll
        for (int q = 0; q < 4; ++q) {
            rh[q] = (short)f2bf(tr[q][b]);
            ih[q] = (short)f2bf(ti[q][b]);
        }
        *(short4*)&tAs[0 * PLT + off] = make_short4(rh[0], rh[1], rh[2], rh[3]);
        *(short4*)&tAs[1 * PLT + off] = make_short4(ih[0], ih[1], ih[2], ih[3]);
    }
}

// MFMA contract, phase B -> OF fp32. (a split-bf16, t bf16-hi: 8 MFMAs per (kc,rt))
__global__ __launch_bounds__(256) void k_amfma(const unsigned short* __restrict__ AFa,
                                               const unsigned short* __restrict__ tA,
                                               float2* __restrict__ OF) {
    constexpr int SG = 8;
    __shared__ __align__(16) unsigned short bs[2 * SG * 16 * 8];   // 4 KB
    int t = threadIdx.x;
    int wave = t >> 6, lane = t & 63;
    int rt0 = wave * 2;
    int colp = lane & 15, rowq = lane >> 4;
    int k = blockIdx.x >> 2, b = blockIdx.x & 3;
    int reg = (k >= 64) ? 1 : 0;
    const short8v* AFv = (const short8v*)(AFa + (size_t)reg * 6 * 2 * 8 * 512);
    const size_t PLA = 2 * 8 * 64;
    const short8v* bsv = (const short8v*)bs;
    size_t p0 = (size_t)blockIdx.x * 64;

    for (int pt = 0; pt < 4; ++pt) {
        __syncthreads();
        {
            const float4* src = (const float4*)tA;
            float4* dst = (float4*)bs;
            int e = t;
            int pl = e >> 7; int rem = e & 127;
            int g = rem >> 4, li = rem & 15;
            dst[e] = src[((size_t)pl * SG + g) * 32768 + p0 + pt * 16 + li];
        }
        __syncthreads();
        float4v accR[2], accI[2];
#pragma unroll
        for (int rt = 0; rt < 2; ++rt) {
            accR[rt] = (float4v){0.f, 0.f, 0.f, 0.f};
            accI[rt] = (float4v){0.f, 0.f, 0.f, 0.f};
        }
#pragma unroll
        for (int kc = 0; kc < 2; ++kc) {
            int gi = kc * 4 + rowq;
            short8v Brh = bsv[((0 * SG + gi) << 4) + colp];
            short8v Bih = bsv[((1 * SG + gi) << 4) + colp];
#pragma unroll
            for (int rt = 0; rt < 2; ++rt) {
                size_t ab = ((size_t)kc * 8 + rt0 + rt) * 64 + lane;
                short8v A0 = AFv[0 * PLA + ab];
                short8v A1 = AFv[1 * PLA + ab];
                short8v A2 = AFv[2 * PLA + ab];
                short8v A3 = AFv[3 * PLA + ab];
                short8v A4 = AFv[4 * PLA + ab];
                short8v A5 = AFv[5 * PLA + ab];
                float4v r_ = accR[rt];
                r_ = __builtin_amdgcn_mfma_f32_16x16x32_bf16(A0, Brh, r_, 0, 0, 0);
                r_ = __builtin_amdgcn_mfma_f32_16x16x32_bf16(A1, Brh, r_, 0, 0, 0);
                r_ = __builtin_amdgcn_mfma_f32_16x16x32_bf16(A4, Bih, r_, 0, 0, 0);
                r_ = __builtin_amdgcn_mfma_f32_16x16x32_bf16(A5, Bih, r_, 0, 0, 0);
                accR[rt] = r_;
                float4v i_ = accI[rt];
                i_ = __builtin_amdgcn_mfma_f32_16x16x32_bf16(A2, Brh, i_, 0, 0, 0);
                i_ = __builtin_amdgcn_mfma_f32_16x16x32_bf16(A3, Brh, i_, 0, 0, 0);
                i_ = __builtin_amdgcn_mfma_f32_16x16x32_bf16(A0, Bih, i_, 0, 0, 0);
                i_ = __builtin_amdgcn_mfma_f32_16x16x32_bf16(A1, Bih, i_, 0, 0, 0);
                accI[rt] = i_;
            }
        }
        int m = pt * 16 + colp;
#pragma unroll
        for (int rt = 0; rt < 2; ++rt) {
            int o0 = (rt0 + rt) * 16 + rowq * 4;
#pragma unroll
            for (int q = 0; q < 4; ++q)
                OF[(size_t)k * 32768 + (size_t)b * 8192 + (size_t)(o0 + q) * 64 + m] =
                    make_float2(accR[rt][q], accI[rt][q]);
        }
    }
}

// FUSED IH-GEMM + inverse-W MFMA. Block = one bo (b*128+o), 512 threads (8 waves).
__global__ __launch_bounds__(512) void k_ihinv(const unsigned short* __restrict__ AF2,
                                               const float2* __restrict__ OF,
                                               const unsigned short* __restrict__ EF,
                                               float* __restrict__ out) {
    constexpr int SG = 16, KC = 4, RTOT = 16;
    __shared__ __align__(16) unsigned short zs[2 * 256 * 64];     // 64 KB
    __shared__ __align__(16) unsigned short bs[4 * SG * 16 * 8];  // 16 KB
    int t = threadIdx.x;
    int wave = t >> 6, lane = t & 63;
    int colp = lane & 15, rowq = lane >> 4;
    int rt0 = wave * 2;
    int bo = blockIdx.x;
    size_t p0 = (size_t)bo * 64;
    const short8v* AFv = (const short8v*)AF2;
    const short8v* bsv = (const short8v*)bs;
    const size_t PLA = (size_t)KC * RTOT * 64;

    for (int pt = 0; pt < 4; ++pt) {
        __syncthreads();
        {   // stage B tile from OF fp32 (split hi/lo): 512 threads x 4 rows each
            int li = t & 15, g = (t >> 4) & 15, half = t >> 8;
            int e0 = half * 4;
            short rh[4], rl[4], ih[4], il[4];
#pragma unroll
            for (int j = 0; j < 4; ++j) {
                float2 v = OF[(size_t)(g * 8 + e0 + j) * P_ + p0 + pt * 16 + li];
                unsigned short h1 = f2bf(v.x);
                rh[j] = (short)h1; rl[j] = (short)f2bf(v.x - bf2f(h1));
                unsigned short h2 = f2bf(v.y);
                ih[j] = (short)h2; il[j] = (short)f2bf(v.y - bf2f(h2));
            }
            int base = (g * 16 + li) * 8 + e0;
            *(short4*)&bs[0 * 2048 + base] = make_short4(rh[0], rh[1], rh[2], rh[3]);
            *(short4*)&bs[1 * 2048 + base] = make_short4(rl[0], rl[1], rl[2], rl[3]);
            *(short4*)&bs[2 * 2048 + base] = make_short4(ih[0], ih[1], ih[2], ih[3]);
            *(short4*)&bs[3 * 2048 + base] = make_short4(il[0], il[1], il[2], il[3]);
        }
        __syncthreads();
        float4v accR[2], accI[2];
#pragma unroll
        for (int rt = 0; rt < 2; ++rt) {
            accR[rt] = (float4v){0.f, 0.f, 0.f, 0.f};
            accI[rt] = (float4v){0.f, 0.f, 0.f, 0.f};
        }
#pragma unroll
        for (int kc = 0; kc < KC; ++kc) {
            int gi = kc * 4 + rowq;
            short8v Brh = bsv[((0 * SG + gi) << 4) + colp];
            short8v Brl = bsv[((1 * SG + gi) << 4) + colp];
            short8v Bih = bsv[((2 * SG + gi) << 4) + colp];
            short8v Bil = bsv[((3 * SG + gi) << 4) + colp];
#pragma unroll
            for (int rt = 0; rt < 2; ++rt) {
                size_t ab = ((size_t)kc * RTOT + rt0 + rt) * 64 + lane;
                short8v A0 = AFv[0 * PLA + ab];
                short8v A1 = AFv[1 * PLA + ab];
                short8v A2 = AFv[2 * PLA + ab];
                short8v A3 = AFv[3 * PLA + ab];
                short8v A4 = AFv[4 * PLA + ab];
                short8v A5 = AFv[5 * PLA + ab];
                float4v r_ = accR[rt];
                r_ = __builtin_amdgcn_mfma_f32_16x16x32_bf16(A0, Brh, r_, 0, 0, 0);
                r_ = __builtin_amdgcn_mfma_f32_16x16x32_bf16(A0, Brl, r_, 0, 0, 0);
                r_ = __builtin_amdgcn_mfma_f32_16x16x32_bf16(A1, Brh, r_, 0, 0, 0);
                r_ = __builtin_amdgcn_mfma_f32_16x16x32_bf16(A4, Bih, r_, 0, 0, 0);
                r_ = __builtin_amdgcn_mfma_f32_16x16x32_bf16(A4, Bil, r_, 0, 0, 0);
                r_ = __builtin_amdgcn_mfma_f32_16x16x32_bf16(A5, Bih, r_, 0, 0, 0);
                accR[rt] = r_;
                float4v i_ = accI[rt];
                i_ = __builtin_amdgcn_mfma_f32_16x16x32_bf16(A2, Brh, i_, 0, 0, 0);
                i_ = __builtin_amdgcn_mfma_f32_16x16x32_bf16(A2, Brl, i_, 0, 0, 0);
                i_ = __builtin_amdgcn_mfma_f32_16x16x32_bf16(A3, Brh, i_, 0, 0, 0);
                i_ = __builtin_amdgcn_mfma_f32_16x16x32_bf16(A0, Bih, i_, 0, 0, 0);
                i_ = __builtin_amdgcn_mfma_f32_16x16x32_bf16(A0, Bil, i_, 0, 0, 0);
                i_ = __builtin_amdgcn_mfma_f32_16x16x32_bf16(A1, Bih, i_, 0, 0, 0);
                accI[rt] = i_;
            }
        }
#pragma unroll
        for (int rt = 0; rt < 2; ++rt)
#pragma unroll
            for (int q = 0; q < 4; ++q) {
                int h = (rt0 + rt) * 16 + rowq * 4 + q;
                int kwsw = (pt * 16 + colp) ^ ((h & 7) << 3);
                zs[h * 64 + kwsw] = (unsigned short)f2bf(accR[rt][q]);
                zs[16384 + h * 64 + kwsw] = (unsigned short)f2bf(accI[rt][q]);
            }
    }
    __syncthreads();

    const short8v* EFv = (const short8v*)EF;
    for (int nt = 0; nt < 16; ++nt) {
        short8v Er0  = EFv[((0 * 2 + 0) * 16 + nt) * 64 + lane];
        short8v Er1  = EFv[((0 * 2 + 1) * 16 + nt) * 64 + lane];
        short8v nEi0 = EFv[((1 * 2 + 0) * 16 + nt) * 64 + lane];
        short8v nEi1 = EFv[((1 * 2 + 1) * 16 + nt) * 64 + lane];
#pragma unroll
        for (int mtl = 0; mtl < 2; ++mtl) {
            int h0 = (wave * 2 + mtl) * 16;
            int hA = h0 + colp;
            int sw = (hA & 7) << 3;
            short8v Zr0 = *(const short8v*)&zs[hA * 64 + ((8 * rowq) ^ sw)];
            short8v Zr1 = *(const short8v*)&zs[hA * 64 + ((32 + 8 * rowq) ^ sw)];
            short8v Zi0 = *(const short8v*)&zs[16384 + hA * 64 + ((8 * rowq) ^ sw)];
            short8v Zi1 = *(const short8v*)&zs[16384 + hA * 64 + ((32 + 8 * rowq) ^ sw)];
            float4v acc = {0.f, 0.f, 0.f, 0.f};
            acc = __builtin_amdgcn_mfma_f32_16x16x32_bf16(Zr0, Er0,  acc, 0, 0, 0);
            acc = __builtin_amdgcn_mfma_f32_16x16x32_bf16(Zi0, nEi0, acc, 0, 0, 0);
            acc = __builtin_amdgcn_mfma_f32_16x16x32_bf16(Zr1, Er1,  acc, 0, 0, 0);
            acc = __builtin_amdgcn_mfma_f32_16x16x32_bf16(Zi1, nEi1, acc, 0, 0, 0);
            size_t ob = ((size_t)bo * 256 + h0 + rowq * 4) * 256 + nt * 16 + colp;
#pragma unroll
            for (int q = 0; q < 4; ++q)
                out[ob + (size_t)q * 256] = acc[q];
        }
    }
}

extern "C" void kernel_launch(void* const* d_in, const int* in_sizes, int n_in,
                              void* d_out, int out_size, void* d_ws, size_t ws_size,
                              hipStream_t stream) {
    const float* x  = (const float*)d_in[0];
    const float* a1 = (const float*)d_in[1];
    const float* b1 = (const float*)d_in[2];
    const float* c1 = (const float*)d_in[3];
    const float* d1 = (const float*)d_in[4];
    const float* a2 = (const float*)d_in[5];
    const float* b2 = (const float*)d_in[6];
    const float* c2 = (const float*)d_in[7];
    const float* d2 = (const float*)d_in[8];
    float* out = (float*)d_out;
    float* wsf = (float*)d_ws;

    if (ws_size < WS_FLOATS * sizeof(float)) return;

    unsigned short* Yt  = (unsigned short*)(wsf + oYT);
    unsigned int*   XFh = (unsigned int*)(wsf + oXF);
    float2*         OF  = (float2*)(wsf + oOF);
    float2*         G   = (float2*)(wsf + oOF);          // G lives in OF region until prepBG
    unsigned short* BF  = (unsigned short*)(wsf + oBF);
    unsigned short* AF1 = (unsigned short*)(wsf + oAF1);
    unsigned short* AF2 = (unsigned short*)(wsf + oAF2);
    unsigned short* bA  = (unsigned short*)(wsf + oYT);  // after cmfma1, Yt region is dead
    unsigned short* gB  = bA + 1048576;
    unsigned short* tA  = (unsigned short*)(wsf + oTA);
    unsigned short* AFa = (unsigned short*)(wsf + oG);
    unsigned short* EF  = (unsigned short*)(wsf + oEF);

    k_prepTables<<<2304, 256, 0, stream>>>(a1, a2, AF1, AF2, BF, EF, AFa);
    k_g<<<1024, 256, 0, stream>>>(c1, d1, c2, d2, G);
    k_stage1m<<<1024, 256, 0, stream>>>(x, BF, Yt);
    k_cmfma<256, 2><<<512, 256, 0, stream>>>(AF1, Yt, XFh);
    k_prepBG<<<7168, 256, 0, stream>>>(b1, b2, G, bA, gB);
    k_contractA<<<512, 256, 0, stream>>>(XFh, bA, gB, tA);
    k_amfma<<<512, 256, 0, stream>>>(AFa, tA, OF);       // overwrites G (dead after prepBG)
    k_ihinv<<<512, 512, 0, stream>>>(AF2, OF, EF, out);

    (void)in_sizes; (void)n_in; (void)out_size;
}

// Round 18
// 227.852 us; speedup vs baseline: 1.0650x; 1.0316x over previous
//
#include <hip/hip_runtime.h>
#include <math.h>

// FactorizedSpectralConv2d: pruned-DFT + TT contraction, MFMA everywhere matmul-shaped.
//
//   k_prepTables: split-bf16 A-frag tables FH/IH + FW B-frags + invW E B-frags + a A-frags
//   k_g         : g[r][j][x][y] = sum_k cc[j,x,k]*dc[k,y]  (G in then-dead OF region)
//   k_prepBG    : bf16 frag tables for b (A) and g (B) from G
//   k_stage1m   : W-DFT of x via MFMA -> Yt 4 bf16 planes [h/8][p][8] (LDS-staged twiddles)
//   k_cmfma     : XFh[k][p] = sum_h FH[k][h] Yt[h][p], packed bf16-hi (re|im<<16) in u32
//   k_contractA : MFMA w-GEMM + fp32 t-update; packed XFh tile staged in 32KB LDS;
//                 t written as bf16-HI frag planes tA (2 planes)
//   k_amfma     : OFh[o,(k,b,m)] = sum_i a[o,i] tA[i,(k,b,m)], packed bf16-hi u32
//   k_ihinv     : FUSED per-bo block: phase1 Z = IH·OFh (2 B-planes, 8 MFMAs/(kc,rt),
//                 Z -> LDS bf16-hi XOR-swizzled); phase2 out = Re(Z . E) via MFMA from LDS.

#define TWO_PI 6.28318530717958647692f

typedef __attribute__((ext_vector_type(8))) short short8v;   // 8 bf16 (4 VGPRs)
typedef __attribute__((ext_vector_type(4))) float float4v;   // MFMA C/D

namespace {
constexpr size_t P_ = 32768;            // B*C*KW pixel batch width

// workspace float offsets
constexpr size_t oYT = 0;                     // Yt: 4 planes [32][32768][8] bf16 = 16.77M floats
                                              //   then bA/gB + tA (contract)
constexpr size_t oTA = 1048576;               // tA: 2 planes [8][32768][8] bf16
constexpr size_t oXF = 16777216;              // XFh u32 16.7MB (packed bf16-hi re|im)
constexpr size_t oOF = 25165824;              // G f2 (2MB, until prepBG) then OFh u32 16.7MB
constexpr size_t oBF = 33554432;              // FW B-frag table: 65536 shorts
constexpr size_t oAF1 = 33587200;             // FH frags: 196608 shorts
constexpr size_t oAF2 = 33685504;             // IH frags: 196608 shorts
constexpr size_t oG  = 33792000;              // AFa (98304 shorts) then EF (32768 shorts)
constexpr size_t oEF = oG + 262144;
constexpr size_t WS_FLOATS = oG + 524288;     // ~137.3 MB
}

__device__ __forceinline__ unsigned short f2bf(float f) {   // RNE float->bf16 bits
    unsigned int u = __float_as_uint(f);
    unsigned int r = (u + 0x7FFFu + ((u >> 16) & 1u)) >> 16;
    return (unsigned short)r;
}
__device__ __forceinline__ float bf2f(unsigned short b) {
    return __uint_as_float(((unsigned int)b) << 16);
}

// All static fragment tables in one launch.
__global__ __launch_bounds__(256) void k_prepTables(const float* __restrict__ a1,
                                                    const float* __restrict__ a2,
                                                    unsigned short* __restrict__ AF1,
                                                    unsigned short* __restrict__ AF2,
                                                    unsigned short* __restrict__ BF,
                                                    unsigned short* __restrict__ EF,
                                                    unsigned short* __restrict__ AFa) {
    int idx = blockIdx.x * 256 + threadIdx.x;      // < 589824
    if (idx < 393216) {
        int tbl = (idx >= 196608);
        int id = tbl ? (idx - 196608) : idx;
        int e = id & 7, lane = (id >> 3) & 63;
        int pl = id >> 15;
        float ang;
        if (!tbl) {
            int rt = (id >> 9) & 7, kc = (id >> 12) & 7;
            int r = rt * 16 + (lane & 15);             // k-row (128)
            int s = kc * 32 + 8 * (lane >> 4) + e;     // h (256)
            int kh = r + ((r >= 64) ? 128 : 0);
            int ph = (kh * s) & 255;
            ang = -TWO_PI * (float)ph / 256.0f;
        } else {
            int rt = (id >> 9) & 15, kc = (id >> 13) & 3;
            int r = rt * 16 + (lane & 15);             // h (256)
            int s = kc * 32 + 8 * (lane >> 4) + e;     // k (128)
            int kh = s + ((s >= 64) ? 128 : 0);
            int ph = (kh * r) & 255;
            ang = TWO_PI * (float)ph / 256.0f;
        }
        float sn, cs; sincosf(ang, &sn, &cs);
        float base = (pl < 2) ? cs : ((pl < 4) ? sn : -sn);
        unsigned short hi = f2bf(base);
        unsigned short out = (pl & 1) ? f2bf(base - bf2f(hi)) : hi;
        (tbl ? AF2 : AF1)[id] = out;
    } else if (idx < 458752) {
        int id = idx - 393216;                          // < 65536
        int e = id & 7, lane = (id >> 3) & 63;
        int nt = (id >> 9) & 3, kc = (id >> 11) & 7;
        int pl = id >> 14;                              // 0..3
        int kw = nt * 16 + (lane & 15);
        int w = kc * 32 + 8 * (lane >> 4) + e;
        int ph = (w * kw) & 255;
        float ang = -TWO_PI * (float)ph / 256.0f;
        float sn, cs; sincosf(ang, &sn, &cs);
        float base = (pl < 2) ? cs : sn;
        unsigned short hi = f2bf(base);
        unsigned short out = (pl & 1) ? f2bf(base - bf2f(hi)) : hi;
        BF[id] = out;
    } else if (idx < 491520) {
        int id = idx - 458752;                          // < 32768
        int e = id & 7, lane = (id >> 3) & 63;
        int nt = (id >> 9) & 15, kc = (id >> 13) & 1, pl = id >> 14;
        int w = nt * 16 + (lane & 15);
        int kw = kc * 32 + 8 * (lane >> 4) + e;
        int ph = (kw * w) & 255;
        float ang = TWO_PI * (float)ph / 256.0f;
        float sn, cs; sincosf(ang, &sn, &cs);
        float sc = ((kw == 0) ? 1.0f : 2.0f) / 65536.0f;
        float v = (pl == 0) ? (sc * cs) : (-sc * sn);
        EF[id] = f2bf(v);
    } else {
        int id = idx - 491520;                          // < 98304
        int e = id & 7, lane = (id >> 3) & 63;
        int rt = (id >> 9) & 7, kc = (id >> 12) & 1;
        int plreg = id >> 13;                           // 0..11
        int reg = plreg / 6, pl = plreg % 6;
        int o = rt * 16 + (lane & 15);
        int i = kc * 32 + 8 * (lane >> 4) + e;
        const float* ap = reg ? a2 : a1;
        float ar = ap[(o * 64 + i) * 2 + 0];
        float ai = ap[(o * 64 + i) * 2 + 1];
        float base = (pl < 2) ? ar : ((pl < 4) ? ai : -ai);
        unsigned short hi = f2bf(base);
        unsigned short out = (pl & 1) ? f2bf(base - bf2f(hi)) : hi;
        AFa[id] = out;
    }
}

// g[r][j][x][y] = sum_k cc[j,x,k] * dc[k,y]
__global__ __launch_bounds__(256) void k_g(const float* __restrict__ c1, const float* __restrict__ d1,
                                           const float* __restrict__ c2, const float* __restrict__ d2,
                                           float2* __restrict__ G) {
    int idx = blockIdx.x * 256 + threadIdx.x;      // < 262144
    int r = idx >> 17;
    int rem = idx & 131071;
    int j = rem >> 12;
    int xy = rem & 4095;
    int xm = xy >> 6, ym = xy & 63;
    const float* cp = r ? c2 : c1;
    const float* dp = r ? d2 : d1;
    float sr = 0.f, si = 0.f;
    for (int kk = 0; kk < 32; ++kk) {
        float cr = cp[((j * 64 + xm) * 32 + kk) * 2 + 0];
        float ci = cp[((j * 64 + xm) * 32 + kk) * 2 + 1];
        float dr = dp[(kk * 64 + ym) * 2 + 0];
        float di = dp[(kk * 64 + ym) * 2 + 1];
        sr = fmaf(cr, dr, fmaf(-ci, di, sr));
        si = fmaf(cr, di, fmaf( ci, dr, si));
    }
    G[(size_t)(r * 32 + j) * 4096 + xy] = make_float2(sr, si);
}

// bf16 fragment tables for the contraction (reads G).
__global__ __launch_bounds__(256) void k_prepBG(const float* __restrict__ b1, const float* __restrict__ b2,
                                                const float2* __restrict__ G,
                                                unsigned short* __restrict__ bA,
                                                unsigned short* __restrict__ gB) {
    size_t idx = (size_t)blockIdx.x * 256 + threadIdx.x;
    if (idx < 1048576) {
        int e     = idx & 7;
        int lane  = (idx >> 3) & 63;
        int c     = (idx >> 9) & 127;
        int itile = (idx >> 16) & 3;
        int reg   = (idx >> 18) & 1;
        int plane = (idx >> 19) & 1;
        int i = itile * 16 + (lane & 15);
        int j = 8 * (lane >> 4) + e;
        const float* bp = reg ? b2 : b1;
        float v = bp[((size_t)(i * 128 + c) * 32 + j) * 2 + plane];
        bA[idx] = f2bf(v);
    } else if (idx < 1048576 + 786432) {
        size_t i2 = idx - 1048576;
        int e     = i2 & 7;
        int lane  = (i2 >> 3) & 63;
        int ytile = (i2 >> 9) & 3;
        int x     = (i2 >> 11) & 63;
        int reg   = (i2 >> 17) & 1;
        int plane = (int)(i2 >> 18);           // 0,1,2
        int y = ytile * 16 + (lane & 15);
        int j = 8 * (lane >> 4) + e;
        float2 gv = G[(size_t)(reg * 32 + j) * 4096 + x * 64 + y];
        float v = (plane == 0) ? gv.x : ((plane == 1) ? gv.y : -gv.y);
        gB[i2] = f2bf(v);
    }
}

// MFMA W-DFT v4: BF staged via LDS in 32KB barrier-synced phases (2 kc each).
__global__ __launch_bounds__(256) void k_stage1m(const float* __restrict__ x,
                                                 const unsigned short* __restrict__ BF,
                                                 unsigned short* __restrict__ Yt) {
    __shared__ __align__(16) unsigned short es[16384];   // 32 KB
    int t = threadIdx.x;
    int wave = t >> 6, lane = t & 63;
    size_t row0 = (size_t)blockIdx.x * 128 + (size_t)wave * 32;
    int colp = lane & 15, rowq = lane >> 4;
    const short8v* esv = (const short8v*)es;

    float4v accR[2][4], accI[2][4];
#pragma unroll
    for (int rt = 0; rt < 2; ++rt)
#pragma unroll
        for (int nt = 0; nt < 4; ++nt) {
            accR[rt][nt] = (float4v){0.f, 0.f, 0.f, 0.f};
            accI[rt][nt] = (float4v){0.f, 0.f, 0.f, 0.f};
        }

    const float* xb0 = x + (row0 + colp) * 256 + 8 * rowq;
    const float* xb1 = xb0 + 16 * 256;
    float4 nv[2][2];
    nv[0][0] = *(const float4*)(xb0);  nv[0][1] = *(const float4*)(xb0 + 4);
    nv[1][0] = *(const float4*)(xb1);  nv[1][1] = *(const float4*)(xb1 + 4);

    const float4* bf4 = (const float4*)BF;
    for (int ph = 0; ph < 4; ++ph) {
        __syncthreads();
        {
#pragma unroll
            for (int i = 0; i < 8; ++i) {
                int idx = t + 256 * i;
                int li  = idx & 63;
                int nt  = (idx >> 6) & 3;
                int kcl = (idx >> 8) & 1;
                int pl  = idx >> 9;
                ((float4*)es)[idx] = bf4[((size_t)(pl * 8 + ph * 2 + kcl) * 4 + nt) * 64 + li];
            }
        }
        __syncthreads();
        for (int kcl = 0; kcl < 2; ++kcl) {
            int kc = ph * 2 + kcl;
            short8v xh[2];
#pragma unroll
            for (int rt = 0; rt < 2; ++rt) {
                float4 v0 = nv[rt][0], v1 = nv[rt][1];
                float vv[8] = {v0.x, v0.y, v0.z, v0.w, v1.x, v1.y, v1.z, v1.w};
#pragma unroll
                for (int j = 0; j < 8; ++j) xh[rt][j] = (short)f2bf(vv[j]);
            }
            if (kc < 7) {
                nv[0][0] = *(const float4*)(xb0 + (kc + 1) * 32);
                nv[0][1] = *(const float4*)(xb0 + (kc + 1) * 32 + 4);
                nv[1][0] = *(const float4*)(xb1 + (kc + 1) * 32);
                nv[1][1] = *(const float4*)(xb1 + (kc + 1) * 32 + 4);
            }
#pragma unroll
            for (int nt = 0; nt < 4; ++nt) {
                short8v Bch = esv[((0 * 2 + kcl) * 4 + nt) * 64 + lane];
                short8v Bcl = esv[((1 * 2 + kcl) * 4 + nt) * 64 + lane];
                short8v Bsh = esv[((2 * 2 + kcl) * 4 + nt) * 64 + lane];
                short8v Bsl = esv[((3 * 2 + kcl) * 4 + nt) * 64 + lane];
#pragma unroll
                for (int rt = 0; rt < 2; ++rt) {
                    float4v r_ = accR[rt][nt];
                    r_ = __builtin_amdgcn_mfma_f32_16x16x32_bf16(xh[rt], Bch, r_, 0, 0, 0);
                    r_ = __builtin_amdgcn_mfma_f32_16x16x32_bf16(xh[rt], Bcl, r_, 0, 0, 0);
                    accR[rt][nt] = r_;
                    float4v i_ = accI[rt][nt];
                    i_ = __builtin_amdgcn_mfma_f32_16x16x32_bf16(xh[rt], Bsh, i_, 0, 0, 0);
                    i_ = __builtin_amdgcn_mfma_f32_16x16x32_bf16(xh[rt], Bsl, i_, 0, 0, 0);
                    accI[rt][nt] = i_;
                }
            }
        }
    }

    short* Yts = (short*)Yt;
    const size_t PLY = (size_t)32 * 32768 * 8;
#pragma unroll
    for (int rt = 0; rt < 2; ++rt) {
        size_t xrow0 = row0 + rt * 16 + rowq * 4;
        int h = (int)(xrow0 & 255), bc = (int)(xrow0 >> 8);
        size_t gbase = (size_t)(h >> 3) * 32768;
        int e0 = h & 7;
#pragma unroll
        for (int nt = 0; nt < 4; ++nt) {
            size_t p = (size_t)bc * 64 + nt * 16 + colp;
            size_t off = (gbase + p) * 8 + e0;
            float4v R = accR[rt][nt], I = accI[rt][nt];
            short rh[4], rl[4], ih[4], il[4];
#pragma unroll
            for (int q = 0; q < 4; ++q) {
                unsigned short h1 = f2bf(R[q]);
                rh[q] = (short)h1; rl[q] = (short)f2bf(R[q] - bf2f(h1));
                unsigned short h2 = f2bf(I[q]);
                ih[q] = (short)h2; il[q] = (short)f2bf(I[q] - bf2f(h2));
            }
            *(short4*)&Yts[0 * PLY + off] = make_short4(rh[0], rh[1], rh[2], rh[3]);
            *(short4*)&Yts[1 * PLY + off] = make_short4(rl[0], rl[1], rl[2], rl[3]);
            *(short4*)&Yts[2 * PLY + off] = make_short4(ih[0], ih[1], ih[2], ih[3]);
            *(short4*)&Yts[3 * PLY + off] = make_short4(il[0], il[1], il[2], il[3]);
        }
    }
}

// Split-bf16 complex MFMA GEMM (FH: Yt -> XFh packed bf16-hi u32).
template<int S, int RT_W>
__global__ __launch_bounds__(256) void k_cmfma(const unsigned short* __restrict__ AF,
                                               const unsigned short* __restrict__ Bt,
                                               unsigned int* __restrict__ XFh) {
    constexpr int KC = S / 32;
    constexpr int SG = S / 8;
    constexpr int RTOT = RT_W * 4;
    __shared__ __align__(16) unsigned short bs[4 * SG * 16 * 8];
    int t = threadIdx.x;
    int wave = t >> 6, lane = t & 63;
    int rt0 = wave * RT_W;
    int colp = lane & 15, rowq = lane >> 4;
    const short8v* AFv = (const short8v*)AF;
    const short8v* bsv = (const short8v*)bs;
    const size_t PLA = (size_t)KC * RTOT * 64;

    for (int pt = 0; pt < 4; ++pt) {
        int p0 = blockIdx.x * 64 + pt * 16;
        __syncthreads();
        {
            const float4* src = (const float4*)Bt;
            float4* dst = (float4*)bs;
            for (int e = t; e < 4 * SG * 16; e += 256) {
                int pl = e / (SG * 16); int rem = e - pl * (SG * 16);
                int g = rem >> 4, li = rem & 15;
                dst[e] = src[((size_t)pl * SG + g) * 32768 + p0 + li];
            }
        }
        __syncthreads();
        float4v accR[RT_W], accI[RT_W];
#pragma unroll
        for (int rt = 0; rt < RT_W; ++rt) {
            accR[rt] = (float4v){0.f, 0.f, 0.f, 0.f};
            accI[rt] = (float4v){0.f, 0.f, 0.f, 0.f};
        }
#pragma unroll
        for (int kc = 0; kc < KC; ++kc) {
            int gi = kc * 4 + rowq;
            short8v Brh = bsv[((0 * SG + gi) << 4) + colp];
            short8v Brl = bsv[((1 * SG + gi) << 4) + colp];
            short8v Bih = bsv[((2 * SG + gi) << 4) + colp];
            short8v Bil = bsv[((3 * SG + gi) << 4) + colp];
#pragma unroll
            for (int rt = 0; rt < RT_W; ++rt) {
                size_t ab = ((size_t)kc * RTOT + rt0 + rt) * 64 + lane;
                short8v A0 = AFv[0 * PLA + ab];
                short8v A1 = AFv[1 * PLA + ab];
                short8v A2 = AFv[2 * PLA + ab];
                short8v A3 = AFv[3 * PLA + ab];
                short8v A4 = AFv[4 * PLA + ab];
                short8v A5 = AFv[5 * PLA + ab];
                float4v r_ = accR[rt];
                r_ = __builtin_amdgcn_mfma_f32_16x16x32_bf16(A0, Brh, r_, 0, 0, 0);
                r_ = __builtin_amdgcn_mfma_f32_16x16x32_bf16(A0, Brl, r_, 0, 0, 0);
                r_ = __builtin_amdgcn_mfma_f32_16x16x32_bf16(A1, Brh, r_, 0, 0, 0);
                r_ = __builtin_amdgcn_mfma_f32_16x16x32_bf16(A4, Bih, r_, 0, 0, 0);
                r_ = __builtin_amdgcn_mfma_f32_16x16x32_bf16(A4, Bil, r_, 0, 0, 0);
                r_ = __builtin_amdgcn_mfma_f32_16x16x32_bf16(A5, Bih, r_, 0, 0, 0);
                accR[rt] = r_;
                float4v i_ = accI[rt];
                i_ = __builtin_amdgcn_mfma_f32_16x16x32_bf16(A2, Brh, i_, 0, 0, 0);
                i_ = __builtin_amdgcn_mfma_f32_16x16x32_bf16(A2, Brl, i_, 0, 0, 0);
                i_ = __builtin_amdgcn_mfma_f32_16x16x32_bf16(A3, Brh, i_, 0, 0, 0);
                i_ = __builtin_amdgcn_mfma_f32_16x16x32_bf16(A0, Bih, i_, 0, 0, 0);
                i_ = __builtin_amdgcn_mfma_f32_16x16x32_bf16(A0, Bil, i_, 0, 0, 0);
                i_ = __builtin_amdgcn_mfma_f32_16x16x32_bf16(A1, Bih, i_, 0, 0, 0);
                accI[rt] = i_;
            }
        }
#pragma unroll
        for (int rt = 0; rt < RT_W; ++rt) {
            int rbase = (rt0 + rt) * 16 + rowq * 4;
#pragma unroll
            for (int q = 0; q < 4; ++q) {
                unsigned int pw = (unsigned int)f2bf(accR[rt][q])
                                | ((unsigned int)f2bf(accI[rt][q]) << 16);
                XFh[(size_t)(rbase + q) * P_ + p0 + colp] = pw;
            }
        }
    }
}

// MFMA contract, phase A -> tA bf16-HI only (2 planes).
// Packed XFh tile (4 b x 128 c x 16 y u32 = 32 KB) staged in LDS.
__global__ __launch_bounds__(256) void k_contractA(const unsigned int* __restrict__ XFh,
                                                   const unsigned short* __restrict__ bA,
                                                   const unsigned short* __restrict__ gB,
                                                   unsigned short* __restrict__ tA) {
    __shared__ __align__(16) unsigned int xfs[4][128][16];   // 32 KB
    int t = threadIdx.x;
    int k = blockIdx.x >> 2;
    int ytile = blockIdx.x & 3;
    int y0 = ytile << 4;
    int reg = (k >= 64) ? 1 : 0;
    int x = k & 63;
    int itile = t >> 6, lane = t & 63;
    int ylane = lane & 15, qg = lane >> 4;

    {   // stage XFh tile: 2048 uint4, 8 per thread
        const uint4* src = (const uint4*)XFh;
        uint4* dst = (uint4*)xfs;
        size_t kbase = ((size_t)k * 32768 + y0) >> 2;   // uint4 units
#pragma unroll
        for (int i = 0; i < 8; ++i) {
            int e = t + 256 * i;
            int f4w = e & 3;          // which uint4 within the 16-u32 row
            int bc  = e >> 2;         // b*128 + c
            int b   = bc >> 7, c = bc & 127;
            dst[e] = src[kbase + (size_t)b * 2048 + (size_t)c * 16 + f4w];
        }
    }

    const short8v* gBv = (const short8v*)gB;
    short8v g_r  = gBv[(((size_t)(0 * 2 + reg) * 64 + x) * 4 + ytile) * 64 + lane];
    short8v g_i  = gBv[(((size_t)(1 * 2 + reg) * 64 + x) * 4 + ytile) * 64 + lane];
    short8v g_ni = gBv[(((size_t)(2 * 2 + reg) * 64 + x) * 4 + ytile) * 64 + lane];

    const short8v* bAv = (const short8v*)bA;
    size_t aR = (((size_t)(0 * 2 + reg) * 4 + itile) * 128) * 64 + lane;
    size_t aI = (((size_t)(1 * 2 + reg) * 4 + itile) * 128) * 64 + lane;

    float tr[4][4], ti[4][4];
#pragma unroll
    for (int q = 0; q < 4; ++q)
#pragma unroll
        for (int b = 0; b < 4; ++b) { tr[q][b] = 0.f; ti[q][b] = 0.f; }

    __syncthreads();     // XFh tile ready

#pragma unroll 2
    for (int c = 0; c < 128; ++c) {
        short8v av = bAv[aR + (size_t)c * 64];
        short8v aw = bAv[aI + (size_t)c * 64];
        float4v z4 = {0.f, 0.f, 0.f, 0.f};
        float4v wr = __builtin_amdgcn_mfma_f32_16x16x32_bf16(av, g_r, z4, 0, 0, 0);
        wr = __builtin_amdgcn_mfma_f32_16x16x32_bf16(aw, g_ni, wr, 0, 0, 0);
        float4v wi = __builtin_amdgcn_mfma_f32_16x16x32_bf16(av, g_i, z4, 0, 0, 0);
        wi = __builtin_amdgcn_mfma_f32_16x16x32_bf16(aw, g_r, wi, 0, 0, 0);
#pragma unroll
        for (int b = 0; b < 4; ++b) {
            unsigned int xw = xfs[b][c][ylane];
            float xr = bf2f((unsigned short)(xw & 0xFFFFu));
            float xi = bf2f((unsigned short)(xw >> 16));
#pragma unroll
            for (int q = 0; q < 4; ++q) {
                tr[q][b] = fmaf(wr[q], xr, fmaf(-wi[q], xi, tr[q][b]));
                ti[q][b] = fmaf(wr[q], xi, fmaf( wi[q], xr, ti[q][b]));
            }
        }
    }

    short* tAs = (short*)tA;
    const size_t PLT = (size_t)8 * 32768 * 8;     // plane stride (shorts)
    int gidx = itile * 2 + (qg >> 1);
    int e0 = (qg & 1) * 4;
#pragma unroll
    for (int b = 0; b < 4; ++b) {
        size_t col = (size_t)k * 256 + (size_t)b * 64 + y0 + ylane;
        size_t off = ((size_t)gidx * 32768 + col) * 8 + e0;
        short rh[4], ih[4];
#pragma unroll
        for (int q = 0; q < 4; ++q) {
            rh[q] = (short)f2bf(tr[q][b]);
            ih[q] = (short)f2bf(ti[q][b]);
        }
        *(short4*)&tAs[0 * PLT + off] = make_short4(rh[0], rh[1], rh[2], rh[3]);
        *(short4*)&tAs[1 * PLT + off] = make_short4(ih[0], ih[1], ih[2], ih[3]);
    }
}

// MFMA contract, phase B -> OFh packed bf16-hi u32.
__global__ __launch_bounds__(256) void k_amfma(const unsigned short* __restrict__ AFa,
                                               const unsigned short* __restrict__ tA,
                                               unsigned int* __restrict__ OFh) {
    constexpr int SG = 8;
    __shared__ __align__(16) unsigned short bs[2 * SG * 16 * 8];   // 4 KB
    int t = threadIdx.x;
    int wave = t >> 6, lane = t & 63;
    int rt0 = wave * 2;
    int colp = lane & 15, rowq = lane >> 4;
    int k = blockIdx.x >> 2, b = blockIdx.x & 3;
    int reg = (k >= 64) ? 1 : 0;
    const short8v* AFv = (const short8v*)(AFa + (size_t)reg * 6 * 2 * 8 * 512);
    const size_t PLA = 2 * 8 * 64;
    const short8v* bsv = (const short8v*)bs;
    size_t p0 = (size_t)blockIdx.x * 64;

    for (int pt = 0; pt < 4; ++pt) {
        __syncthreads();
        {
            const float4* src = (const float4*)tA;
            float4* dst = (float4*)bs;
            int e = t;
            int pl = e >> 7; int rem = e & 127;
            int g = rem >> 4, li = rem & 15;
            dst[e] = src[((size_t)pl * SG + g) * 32768 + p0 + pt * 16 + li];
        }
        __syncthreads();
        float4v accR[2], accI[2];
#pragma unroll
        for (int rt = 0; rt < 2; ++rt) {
            accR[rt] = (float4v){0.f, 0.f, 0.f, 0.f};
            accI[rt] = (float4v){0.f, 0.f, 0.f, 0.f};
        }
#pragma unroll
        for (int kc = 0; kc < 2; ++kc) {
            int gi = kc * 4 + rowq;
            short8v Brh = bsv[((0 * SG + gi) << 4) + colp];
            short8v Bih = bsv[((1 * SG + gi) << 4) + colp];
#pragma unroll
            for (int rt = 0; rt < 2; ++rt) {
                size_t ab = ((size_t)kc * 8 + rt0 + rt) * 64 + lane;
                short8v A0 = AFv[0 * PLA + ab];
                short8v A1 = AFv[1 * PLA + ab];
                short8v A2 = AFv[2 * PLA + ab];
                short8v A3 = AFv[3 * PLA + ab];
                short8v A4 = AFv[4 * PLA + ab];
                short8v A5 = AFv[5 * PLA + ab];
                float4v r_ = accR[rt];
                r_ = __builtin_amdgcn_mfma_f32_16x16x32_bf16(A0, Brh, r_, 0, 0, 0);
                r_ = __builtin_amdgcn_mfma_f32_16x16x32_bf16(A1, Brh, r_, 0, 0, 0);
                r_ = __builtin_amdgcn_mfma_f32_16x16x32_bf16(A4, Bih, r_, 0, 0, 0);
                r_ = __builtin_amdgcn_mfma_f32_16x16x32_bf16(A5, Bih, r_, 0, 0, 0);
                accR[rt] = r_;
                float4v i_ = accI[rt];
                i_ = __builtin_amdgcn_mfma_f32_16x16x32_bf16(A2, Brh, i_, 0, 0, 0);
                i_ = __builtin_amdgcn_mfma_f32_16x16x32_bf16(A3, Brh, i_, 0, 0, 0);
                i_ = __builtin_amdgcn_mfma_f32_16x16x32_bf16(A0, Bih, i_, 0, 0, 0);
                i_ = __builtin_amdgcn_mfma_f32_16x16x32_bf16(A1, Bih, i_, 0, 0, 0);
                accI[rt] = i_;
            }
        }
        int m = pt * 16 + colp;
#pragma unroll
        for (int rt = 0; rt < 2; ++rt) {
            int o0 = (rt0 + rt) * 16 + rowq * 4;
#pragma unroll
            for (int q = 0; q < 4; ++q) {
                unsigned int pw = (unsigned int)f2bf(accR[rt][q])
                                | ((unsigned int)f2bf(accI[rt][q]) << 16);
                OFh[(size_t)k * 32768 + (size_t)b * 8192 + (size_t)(o0 + q) * 64 + m] = pw;
            }
        }
    }
}

// FUSED IH-GEMM + inverse-W MFMA. Block = one bo (b*128+o), 512 threads (8 waves).
// Phase 1 B-operand now bf16-hi packed (2 planes, 8 MFMAs per (kc,rt)).
__global__ __launch_bounds__(512) void k_ihinv(const unsigned short* __restrict__ AF2,
                                               const unsigned int* __restrict__ OFh,
                                               const unsigned short* __restrict__ EF,
                                               float* __restrict__ out) {
    constexpr int SG = 16, KC = 4, RTOT = 16;
    __shared__ __align__(16) unsigned short zs[2 * 256 * 64];     // 64 KB
    __shared__ __align__(16) unsigned short bs[2 * SG * 16 * 8];  // 8 KB
    int t = threadIdx.x;
    int wave = t >> 6, lane = t & 63;
    int colp = lane & 15, rowq = lane >> 4;
    int rt0 = wave * 2;
    int bo = blockIdx.x;
    size_t p0 = (size_t)bo * 64;
    const short8v* AFv = (const short8v*)AF2;
    const short8v* bsv = (const short8v*)bs;
    const size_t PLA = (size_t)KC * RTOT * 64;

    for (int pt = 0; pt < 4; ++pt) {
        __syncthreads();
        {   // stage B tile from OFh (packed): 512 threads x 4 rows each
            int li = t & 15, g = (t >> 4) & 15, half = t >> 8;
            int e0 = half * 4;
            short rh[4], ih[4];
#pragma unroll
            for (int j = 0; j < 4; ++j) {
                unsigned int w = OFh[(size_t)(g * 8 + e0 + j) * P_ + p0 + pt * 16 + li];
                rh[j] = (short)(w & 0xFFFFu);
                ih[j] = (short)(w >> 16);
            }
            int base = (g * 16 + li) * 8 + e0;
            *(short4*)&bs[0 * 2048 + base] = make_short4(rh[0], rh[1], rh[2], rh[3]);
            *(short4*)&bs[1 * 2048 + base] = make_short4(ih[0], ih[1], ih[2], ih[3]);
        }
        __syncthreads();
        float4v accR[2], accI[2];
#pragma unroll
        for (int rt = 0; rt < 2; ++rt) {
            accR[rt] = (float4v){0.f, 0.f, 0.f, 0.f};
            accI[rt] = (float4v){0.f, 0.f, 0.f, 0.f};
        }
#pragma unroll
        for (int kc = 0; kc < KC; ++kc) {
            int gi = kc * 4 + rowq;
            short8v Brh = bsv[((0 * SG + gi) << 4) + colp];
            short8v Bih = bsv[((1 * SG + gi) << 4) + colp];
#pragma unroll
            for (int rt = 0; rt < 2; ++rt) {
                size_t ab = ((size_t)kc * RTOT + rt0 + rt) * 64 + lane;
                short8v A0 = AFv[0 * PLA + ab];
                short8v A1 = AFv[1 * PLA + ab];
                short8v A2 = AFv[2 * PLA + ab];
                short8v A3 = AFv[3 * PLA + ab];
                short8v A4 = AFv[4 * PLA + ab];
                short8v A5 = AFv[5 * PLA + ab];
                float4v r_ = accR[rt];
                r_ = __builtin_amdgcn_mfma_f32_16x16x32_bf16(A0, Brh, r_, 0, 0, 0);
                r_ = __builtin_amdgcn_mfma_f32_16x16x32_bf16(A1, Brh, r_, 0, 0, 0);
                r_ = __builtin_amdgcn_mfma_f32_16x16x32_bf16(A4, Bih, r_, 0, 0, 0);
                r_ = __builtin_amdgcn_mfma_f32_16x16x32_bf16(A5, Bih, r_, 0, 0, 0);
                accR[rt] = r_;
                float4v i_ = accI[rt];
                i_ = __builtin_amdgcn_mfma_f32_16x16x32_bf16(A2, Brh, i_, 0, 0, 0);
                i_ = __builtin_amdgcn_mfma_f32_16x16x32_bf16(A3, Brh, i_, 0, 0, 0);
                i_ = __builtin_amdgcn_mfma_f32_16x16x32_bf16(A0, Bih, i_, 0, 0, 0);
                i_ = __builtin_amdgcn_mfma_f32_16x16x32_bf16(A1, Bih, i_, 0, 0, 0);
                accI[rt] = i_;
            }
        }
#pragma unroll
        for (int rt = 0; rt < 2; ++rt)
#pragma unroll
            for (int q = 0; q < 4; ++q) {
                int h = (rt0 + rt) * 16 + rowq * 4 + q;
                int kwsw = (pt * 16 + colp) ^ ((h & 7) << 3);
                zs[h * 64 + kwsw] = (unsigned short)f2bf(accR[rt][q]);
                zs[16384 + h * 64 + kwsw] = (unsigned short)f2bf(accI[rt][q]);
            }
    }
    __syncthreads();

    const short8v* EFv = (const short8v*)EF;
    for (int nt = 0; nt < 16; ++nt) {
        short8v Er0  = EFv[((0 * 2 + 0) * 16 + nt) * 64 + lane];
        short8v Er1  = EFv[((0 * 2 + 1) * 16 + nt) * 64 + lane];
        short8v nEi0 = EFv[((1 * 2 + 0) * 16 + nt) * 64 + lane];
        short8v nEi1 = EFv[((1 * 2 + 1) * 16 + nt) * 64 + lane];
#pragma unroll
        for (int mtl = 0; mtl < 2; ++mtl) {
            int h0 = (wave * 2 + mtl) * 16;
            int hA = h0 + colp;
            int sw = (hA & 7) << 3;
            short8v Zr0 = *(const short8v*)&zs[hA * 64 + ((8 * rowq) ^ sw)];
            short8v Zr1 = *(const short8v*)&zs[hA * 64 + ((32 + 8 * rowq) ^ sw)];
            short8v Zi0 = *(const short8v*)&zs[16384 + hA * 64 + ((8 * rowq) ^ sw)];
            short8v Zi1 = *(const short8v*)&zs[16384 + hA * 64 + ((32 + 8 * rowq) ^ sw)];
            float4v acc = {0.f, 0.f, 0.f, 0.f};
            acc = __builtin_amdgcn_mfma_f32_16x16x32_bf16(Zr0, Er0,  acc, 0, 0, 0);
            acc = __builtin_amdgcn_mfma_f32_16x16x32_bf16(Zi0, nEi0, acc, 0, 0, 0);
            acc = __builtin_amdgcn_mfma_f32_16x16x32_bf16(Zr1, Er1,  acc, 0, 0, 0);
            acc = __builtin_amdgcn_mfma_f32_16x16x32_bf16(Zi1, nEi1, acc, 0, 0, 0);
            size_t ob = ((size_t)bo * 256 + h0 + rowq * 4) * 256 + nt * 16 + colp;
#pragma unroll
            for (int q = 0; q < 4; ++q)
                out[ob + (size_t)q * 256] = acc[q];
        }
    }
}

extern "C" void kernel_launch(void* const* d_in, const int* in_sizes, int n_in,
                              void* d_out, int out_size, void* d_ws, size_t ws_size,
                              hipStream_t stream) {
    const float* x  = (const float*)d_in[0];
    const float* a1 = (const float*)d_in[1];
    const float* b1 = (const float*)d_in[2];
    const float* c1 = (const float*)d_in[3];
    const float* d1 = (const float*)d_in[4];
    const float* a2 = (const float*)d_in[5];
    const float* b2 = (const float*)d_in[6];
    const float* c2 = (const float*)d_in[7];
    const float* d2 = (const float*)d_in[8];
    float* out = (float*)d_out;
    float* wsf = (float*)d_ws;

    if (ws_size < WS_FLOATS * sizeof(float)) return;

    unsigned short* Yt  = (unsigned short*)(wsf + oYT);
    unsigned int*   XFh = (unsigned int*)(wsf + oXF);
    unsigned int*   OFh = (unsigned int*)(wsf + oOF);
    float2*         G   = (float2*)(wsf + oOF);          // G lives in OF region until prepBG
    unsigned short* BF  = (unsigned short*)(wsf + oBF);
    unsigned short* AF1 = (unsigned short*)(wsf + oAF1);
    unsigned short* AF2 = (unsigned short*)(wsf + oAF2);
    unsigned short* bA  = (unsigned short*)(wsf + oYT);  // after cmfma1, Yt region is dead
    unsigned short* gB  = bA + 1048576;
    unsigned short* tA  = (unsigned short*)(wsf + oTA);
    unsigned short* AFa = (unsigned short*)(wsf + oG);
    unsigned short* EF  = (unsigned short*)(wsf + oEF);

    k_prepTables<<<2304, 256, 0, stream>>>(a1, a2, AF1, AF2, BF, EF, AFa);
    k_g<<<1024, 256, 0, stream>>>(c1, d1, c2, d2, G);
    k_stage1m<<<1024, 256, 0, stream>>>(x, BF, Yt);
    k_cmfma<256, 2><<<512, 256, 0, stream>>>(AF1, Yt, XFh);
    k_prepBG<<<7168, 256, 0, stream>>>(b1, b2, G, bA, gB);
    k_contractA<<<512, 256, 0, stream>>>(XFh, bA, gB, tA);
    k_amfma<<<512, 256, 0, stream>>>(AFa, tA, OFh);      // overwrites G (dead after prepBG)
    k_ihinv<<<512, 512, 0, stream>>>(AF2, OFh, EF, out);

    (void)in_sizes; (void)n_in; (void)out_size;
}

// Round 19
// 212.579 us; speedup vs baseline: 1.1416x; 1.0718x over previous
//
#include <hip/hip_runtime.h>
#include <math.h>

// FactorizedSpectralConv2d: pruned-DFT + TT contraction, MFMA everywhere matmul-shaped.
//
//   k_prepTables: split-bf16 A-frag tables FH/IH + FW B-frags + invW E B-frags + a A-frags
//   k_g         : g[r][j][x][y] = sum_k cc[j,x,k]*dc[k,y]  (G in then-dead OF region)
//   k_prepBG    : bf16 frag tables for b (A) and g (B) from G
//   k_stage1m   : W-DFT of x via MFMA -> Yt 2 bf16-HI planes [h/8][p][8] (LDS-staged twiddles)
//   k_cmfma     : XFh[k][p] = sum_h FH[k][h] Yt[h][p], packed bf16-hi (re|im<<16) in u32
//                 (B hi-only: 8 MFMAs per (kc,rt))
//   k_contractA : MFMA w-GEMM + fp32 t-update; packed XFh tile staged in 32KB LDS;
//                 t written as bf16-HI frag planes tA (2 planes)
//   k_amfma     : OFh[o,(k,b,m)] = sum_i a[o,i] tA[i,(k,b,m)], packed bf16-hi u32
//   k_ihinv     : FUSED per-bo block: phase1 Z = IH·OFh (2 B-planes, 8 MFMAs/(kc,rt),
//                 Z -> LDS bf16-hi XOR-swizzled); phase2 out = Re(Z . E) via MFMA from LDS.

#define TWO_PI 6.28318530717958647692f

typedef __attribute__((ext_vector_type(8))) short short8v;   // 8 bf16 (4 VGPRs)
typedef __attribute__((ext_vector_type(4))) float float4v;   // MFMA C/D

namespace {
constexpr size_t P_ = 32768;            // B*C*KW pixel batch width

// workspace float offsets
constexpr size_t oYT = 0;                     // Yt: 2 bf16-hi planes [32][32768][8]
                                              //   then bA/gB + tA (contract)
constexpr size_t oTA = 1048576;               // tA: 2 planes [8][32768][8] bf16
constexpr size_t oXF = 16777216;              // XFh u32 16.7MB (packed bf16-hi re|im)
constexpr size_t oOF = 25165824;              // G f2 (2MB, until prepBG) then OFh u32 16.7MB
constexpr size_t oBF = 33554432;              // FW B-frag table: 65536 shorts
constexpr size_t oAF1 = 33587200;             // FH frags: 196608 shorts
constexpr size_t oAF2 = 33685504;             // IH frags: 196608 shorts
constexpr size_t oG  = 33792000;              // AFa (98304 shorts) then EF (32768 shorts)
constexpr size_t oEF = oG + 262144;
constexpr size_t WS_FLOATS = oG + 524288;     // ~137.3 MB
}

__device__ __forceinline__ unsigned short f2bf(float f) {   // RNE float->bf16 bits
    unsigned int u = __float_as_uint(f);
    unsigned int r = (u + 0x7FFFu + ((u >> 16) & 1u)) >> 16;
    return (unsigned short)r;
}
__device__ __forceinline__ float bf2f(unsigned short b) {
    return __uint_as_float(((unsigned int)b) << 16);
}

// All static fragment tables in one launch.
__global__ __launch_bounds__(256) void k_prepTables(const float* __restrict__ a1,
                                                    const float* __restrict__ a2,
                                                    unsigned short* __restrict__ AF1,
                                                    unsigned short* __restrict__ AF2,
                                                    unsigned short* __restrict__ BF,
                                                    unsigned short* __restrict__ EF,
                                                    unsigned short* __restrict__ AFa) {
    int idx = blockIdx.x * 256 + threadIdx.x;      // < 589824
    if (idx < 393216) {
        int tbl = (idx >= 196608);
        int id = tbl ? (idx - 196608) : idx;
        int e = id & 7, lane = (id >> 3) & 63;
        int pl = id >> 15;
        float ang;
        if (!tbl) {
            int rt = (id >> 9) & 7, kc = (id >> 12) & 7;
            int r = rt * 16 + (lane & 15);             // k-row (128)
            int s = kc * 32 + 8 * (lane >> 4) + e;     // h (256)
            int kh = r + ((r >= 64) ? 128 : 0);
            int ph = (kh * s) & 255;
            ang = -TWO_PI * (float)ph / 256.0f;
        } else {
            int rt = (id >> 9) & 15, kc = (id >> 13) & 3;
            int r = rt * 16 + (lane & 15);             // h (256)
            int s = kc * 32 + 8 * (lane >> 4) + e;     // k (128)
            int kh = s + ((s >= 64) ? 128 : 0);
            int ph = (kh * r) & 255;
            ang = TWO_PI * (float)ph / 256.0f;
        }
        float sn, cs; sincosf(ang, &sn, &cs);
        float base = (pl < 2) ? cs : ((pl < 4) ? sn : -sn);
        unsigned short hi = f2bf(base);
        unsigned short out = (pl & 1) ? f2bf(base - bf2f(hi)) : hi;
        (tbl ? AF2 : AF1)[id] = out;
    } else if (idx < 458752) {
        int id = idx - 393216;                          // < 65536
        int e = id & 7, lane = (id >> 3) & 63;
        int nt = (id >> 9) & 3, kc = (id >> 11) & 7;
        int pl = id >> 14;                              // 0..3
        int kw = nt * 16 + (lane & 15);
        int w = kc * 32 + 8 * (lane >> 4) + e;
        int ph = (w * kw) & 255;
        float ang = -TWO_PI * (float)ph / 256.0f;
        float sn, cs; sincosf(ang, &sn, &cs);
        float base = (pl < 2) ? cs : sn;
        unsigned short hi = f2bf(base);
        unsigned short out = (pl & 1) ? f2bf(base - bf2f(hi)) : hi;
        BF[id] = out;
    } else if (idx < 491520) {
        int id = idx - 458752;                          // < 32768
        int e = id & 7, lane = (id >> 3) & 63;
        int nt = (id >> 9) & 15, kc = (id >> 13) & 1, pl = id >> 14;
        int w = nt * 16 + (lane & 15);
        int kw = kc * 32 + 8 * (lane >> 4) + e;
        int ph = (kw * w) & 255;
        float ang = TWO_PI * (float)ph / 256.0f;
        float sn, cs; sincosf(ang, &sn, &cs);
        float sc = ((kw == 0) ? 1.0f : 2.0f) / 65536.0f;
        float v = (pl == 0) ? (sc * cs) : (-sc * sn);
        EF[id] = f2bf(v);
    } else {
        int id = idx - 491520;                          // < 98304
        int e = id & 7, lane = (id >> 3) & 63;
        int rt = (id >> 9) & 7, kc = (id >> 12) & 1;
        int plreg = id >> 13;                           // 0..11
        int reg = plreg / 6, pl = plreg % 6;
        int o = rt * 16 + (lane & 15);
        int i = kc * 32 + 8 * (lane >> 4) + e;
        const float* ap = reg ? a2 : a1;
        float ar = ap[(o * 64 + i) * 2 + 0];
        float ai = ap[(o * 64 + i) * 2 + 1];
        float base = (pl < 2) ? ar : ((pl < 4) ? ai : -ai);
        unsigned short hi = f2bf(base);
        unsigned short out = (pl & 1) ? f2bf(base - bf2f(hi)) : hi;
        AFa[id] = out;
    }
}

// g[r][j][x][y] = sum_k cc[j,x,k] * dc[k,y]
__global__ __launch_bounds__(256) void k_g(const float* __restrict__ c1, const float* __restrict__ d1,
                                           const float* __restrict__ c2, const float* __restrict__ d2,
                                           float2* __restrict__ G) {
    int idx = blockIdx.x * 256 + threadIdx.x;      // < 262144
    int r = idx >> 17;
    int rem = idx & 131071;
    int j = rem >> 12;
    int xy = rem & 4095;
    int xm = xy >> 6, ym = xy & 63;
    const float* cp = r ? c2 : c1;
    const float* dp = r ? d2 : d1;
    float sr = 0.f, si = 0.f;
    for (int kk = 0; kk < 32; ++kk) {
        float cr = cp[((j * 64 + xm) * 32 + kk) * 2 + 0];
        float ci = cp[((j * 64 + xm) * 32 + kk) * 2 + 1];
        float dr = dp[(kk * 64 + ym) * 2 + 0];
        float di = dp[(kk * 64 + ym) * 2 + 1];
        sr = fmaf(cr, dr, fmaf(-ci, di, sr));
        si = fmaf(cr, di, fmaf( ci, dr, si));
    }
    G[(size_t)(r * 32 + j) * 4096 + xy] = make_float2(sr, si);
}

// bf16 fragment tables for the contraction (reads G).
__global__ __launch_bounds__(256) void k_prepBG(const float* __restrict__ b1, const float* __restrict__ b2,
                                                const float2* __restrict__ G,
                                                unsigned short* __restrict__ bA,
                                                unsigned short* __restrict__ gB) {
    size_t idx = (size_t)blockIdx.x * 256 + threadIdx.x;
    if (idx < 1048576) {
        int e     = idx & 7;
        int lane  = (idx >> 3) & 63;
        int c     = (idx >> 9) & 127;
        int itile = (idx >> 16) & 3;
        int reg   = (idx >> 18) & 1;
        int plane = (idx >> 19) & 1;
        int i = itile * 16 + (lane & 15);
        int j = 8 * (lane >> 4) + e;
        const float* bp = reg ? b2 : b1;
        float v = bp[((size_t)(i * 128 + c) * 32 + j) * 2 + plane];
        bA[idx] = f2bf(v);
    } else if (idx < 1048576 + 786432) {
        size_t i2 = idx - 1048576;
        int e     = i2 & 7;
        int lane  = (i2 >> 3) & 63;
        int ytile = (i2 >> 9) & 3;
        int x     = (i2 >> 11) & 63;
        int reg   = (i2 >> 17) & 1;
        int plane = (int)(i2 >> 18);           // 0,1,2
        int y = ytile * 16 + (lane & 15);
        int j = 8 * (lane >> 4) + e;
        float2 gv = G[(size_t)(reg * 32 + j) * 4096 + x * 64 + y];
        float v = (plane == 0) ? gv.x : ((plane == 1) ? gv.y : -gv.y);
        gB[i2] = f2bf(v);
    }
}

// MFMA W-DFT v5: BF staged via LDS in 32KB barrier-synced phases (2 kc each).
// Yt output = 2 bf16-HI planes (re, im).
__global__ __launch_bounds__(256) void k_stage1m(const float* __restrict__ x,
                                                 const unsigned short* __restrict__ BF,
                                                 unsigned short* __restrict__ Yt) {
    __shared__ __align__(16) unsigned short es[16384];   // 32 KB
    int t = threadIdx.x;
    int wave = t >> 6, lane = t & 63;
    size_t row0 = (size_t)blockIdx.x * 128 + (size_t)wave * 32;
    int colp = lane & 15, rowq = lane >> 4;
    const short8v* esv = (const short8v*)es;

    float4v accR[2][4], accI[2][4];
#pragma unroll
    for (int rt = 0; rt < 2; ++rt)
#pragma unroll
        for (int nt = 0; nt < 4; ++nt) {
            accR[rt][nt] = (float4v){0.f, 0.f, 0.f, 0.f};
            accI[rt][nt] = (float4v){0.f, 0.f, 0.f, 0.f};
        }

    const float* xb0 = x + (row0 + colp) * 256 + 8 * rowq;
    const float* xb1 = xb0 + 16 * 256;
    float4 nv[2][2];
    nv[0][0] = *(const float4*)(xb0);  nv[0][1] = *(const float4*)(xb0 + 4);
    nv[1][0] = *(const float4*)(xb1);  nv[1][1] = *(const float4*)(xb1 + 4);

    const float4* bf4 = (const float4*)BF;
    for (int ph = 0; ph < 4; ++ph) {
        __syncthreads();
        {
#pragma unroll
            for (int i = 0; i < 8; ++i) {
                int idx = t + 256 * i;
                int li  = idx & 63;
                int nt  = (idx >> 6) & 3;
                int kcl = (idx >> 8) & 1;
                int pl  = idx >> 9;
                ((float4*)es)[idx] = bf4[((size_t)(pl * 8 + ph * 2 + kcl) * 4 + nt) * 64 + li];
            }
        }
        __syncthreads();
        for (int kcl = 0; kcl < 2; ++kcl) {
            int kc = ph * 2 + kcl;
            short8v xh[2];
#pragma unroll
            for (int rt = 0; rt < 2; ++rt) {
                float4 v0 = nv[rt][0], v1 = nv[rt][1];
                float vv[8] = {v0.x, v0.y, v0.z, v0.w, v1.x, v1.y, v1.z, v1.w};
#pragma unroll
                for (int j = 0; j < 8; ++j) xh[rt][j] = (short)f2bf(vv[j]);
            }
            if (kc < 7) {
                nv[0][0] = *(const float4*)(xb0 + (kc + 1) * 32);
                nv[0][1] = *(const float4*)(xb0 + (kc + 1) * 32 + 4);
                nv[1][0] = *(const float4*)(xb1 + (kc + 1) * 32);
                nv[1][1] = *(const float4*)(xb1 + (kc + 1) * 32 + 4);
            }
#pragma unroll
            for (int nt = 0; nt < 4; ++nt) {
                short8v Bch = esv[((0 * 2 + kcl) * 4 + nt) * 64 + lane];
                short8v Bcl = esv[((1 * 2 + kcl) * 4 + nt) * 64 + lane];
                short8v Bsh = esv[((2 * 2 + kcl) * 4 + nt) * 64 + lane];
                short8v Bsl = esv[((3 * 2 + kcl) * 4 + nt) * 64 + lane];
#pragma unroll
                for (int rt = 0; rt < 2; ++rt) {
                    float4v r_ = accR[rt][nt];
                    r_ = __builtin_amdgcn_mfma_f32_16x16x32_bf16(xh[rt], Bch, r_, 0, 0, 0);
                    r_ = __builtin_amdgcn_mfma_f32_16x16x32_bf16(xh[rt], Bcl, r_, 0, 0, 0);
                    accR[rt][nt] = r_;
                    float4v i_ = accI[rt][nt];
                    i_ = __builtin_amdgcn_mfma_f32_16x16x32_bf16(xh[rt], Bsh, i_, 0, 0, 0);
                    i_ = __builtin_amdgcn_mfma_f32_16x16x32_bf16(xh[rt], Bsl, i_, 0, 0, 0);
                    accI[rt][nt] = i_;
                }
            }
        }
    }

    short* Yts = (short*)Yt;
    const size_t PLY = (size_t)32 * 32768 * 8;
#pragma unroll
    for (int rt = 0; rt < 2; ++rt) {
        size_t xrow0 = row0 + rt * 16 + rowq * 4;
        int h = (int)(xrow0 & 255), bc = (int)(xrow0 >> 8);
        size_t gbase = (size_t)(h >> 3) * 32768;
        int e0 = h & 7;
#pragma unroll
        for (int nt = 0; nt < 4; ++nt) {
            size_t p = (size_t)bc * 64 + nt * 16 + colp;
            size_t off = (gbase + p) * 8 + e0;
            float4v R = accR[rt][nt], I = accI[rt][nt];
            short rh[4], ih[4];
#pragma unroll
            for (int q = 0; q < 4; ++q) {
                rh[q] = (short)f2bf(R[q]);
                ih[q] = (short)f2bf(I[q]);
            }
            *(short4*)&Yts[0 * PLY + off] = make_short4(rh[0], rh[1], rh[2], rh[3]);
            *(short4*)&Yts[1 * PLY + off] = make_short4(ih[0], ih[1], ih[2], ih[3]);
        }
    }
}

// bf16-hi complex MFMA GEMM (FH split-A x Yt hi-B -> XFh packed bf16-hi u32).
template<int S, int RT_W>
__global__ __launch_bounds__(256) void k_cmfma(const unsigned short* __restrict__ AF,
                                               const unsigned short* __restrict__ Bt,
                                               unsigned int* __restrict__ XFh) {
    constexpr int KC = S / 32;
    constexpr int SG = S / 8;
    constexpr int RTOT = RT_W * 4;
    __shared__ __align__(16) unsigned short bs[2 * SG * 16 * 8];   // 16 KB (S=256)
    int t = threadIdx.x;
    int wave = t >> 6, lane = t & 63;
    int rt0 = wave * RT_W;
    int colp = lane & 15, rowq = lane >> 4;
    const short8v* AFv = (const short8v*)AF;
    const short8v* bsv = (const short8v*)bs;
    const size_t PLA = (size_t)KC * RTOT * 64;

    for (int pt = 0; pt < 4; ++pt) {
        int p0 = blockIdx.x * 64 + pt * 16;
        __syncthreads();
        {
            const float4* src = (const float4*)Bt;
            float4* dst = (float4*)bs;
            for (int e = t; e < 2 * SG * 16; e += 256) {
                int pl = e / (SG * 16); int rem = e - pl * (SG * 16);
                int g = rem >> 4, li = rem & 15;
                dst[e] = src[((size_t)pl * SG + g) * 32768 + p0 + li];
            }
        }
        __syncthreads();
        float4v accR[RT_W], accI[RT_W];
#pragma unroll
        for (int rt = 0; rt < RT_W; ++rt) {
            accR[rt] = (float4v){0.f, 0.f, 0.f, 0.f};
            accI[rt] = (float4v){0.f, 0.f, 0.f, 0.f};
        }
#pragma unroll
        for (int kc = 0; kc < KC; ++kc) {
            int gi = kc * 4 + rowq;
            short8v Brh = bsv[((0 * SG + gi) << 4) + colp];
            short8v Bih = bsv[((1 * SG + gi) << 4) + colp];
#pragma unroll
            for (int rt = 0; rt < RT_W; ++rt) {
                size_t ab = ((size_t)kc * RTOT + rt0 + rt) * 64 + lane;
                short8v A0 = AFv[0 * PLA + ab];
                short8v A1 = AFv[1 * PLA + ab];
                short8v A2 = AFv[2 * PLA + ab];
                short8v A3 = AFv[3 * PLA + ab];
                short8v A4 = AFv[4 * PLA + ab];
                short8v A5 = AFv[5 * PLA + ab];
                float4v r_ = accR[rt];
                r_ = __builtin_amdgcn_mfma_f32_16x16x32_bf16(A0, Brh, r_, 0, 0, 0);
                r_ = __builtin_amdgcn_mfma_f32_16x16x32_bf16(A1, Brh, r_, 0, 0, 0);
                r_ = __builtin_amdgcn_mfma_f32_16x16x32_bf16(A4, Bih, r_, 0, 0, 0);
                r_ = __builtin_amdgcn_mfma_f32_16x16x32_bf16(A5, Bih, r_, 0, 0, 0);
                accR[rt] = r_;
                float4v i_ = accI[rt];
                i_ = __builtin_amdgcn_mfma_f32_16x16x32_bf16(A2, Brh, i_, 0, 0, 0);
                i_ = __builtin_amdgcn_mfma_f32_16x16x32_bf16(A3, Brh, i_, 0, 0, 0);
                i_ = __builtin_amdgcn_mfma_f32_16x16x32_bf16(A0, Bih, i_, 0, 0, 0);
                i_ = __builtin_amdgcn_mfma_f32_16x16x32_bf16(A1, Bih, i_, 0, 0, 0);
                accI[rt] = i_;
            }
        }
#pragma unroll
        for (int rt = 0; rt < RT_W; ++rt) {
            int rbase = (rt0 + rt) * 16 + rowq * 4;
#pragma unroll
            for (int q = 0; q < 4; ++q) {
                unsigned int pw = (unsigned int)f2bf(accR[rt][q])
                                | ((unsigned int)f2bf(accI[rt][q]) << 16);
                XFh[(size_t)(rbase + q) * P_ + p0 + colp] = pw;
            }
        }
    }
}

// MFMA contract, phase A -> tA bf16-HI only (2 planes).
// Packed XFh tile (4 b x 128 c x 16 y u32 = 32 KB) staged in LDS.
__global__ __launch_bounds__(256) void k_contractA(const unsigned int* __restrict__ XFh,
                                                   const unsigned short* __restrict__ bA,
                                                   const unsigned short* __restrict__ gB,
                                                   unsigned short* __restrict__ tA) {
    __shared__ __align__(16) unsigned int xfs[4][128][16];   // 32 KB
    int t = threadIdx.x;
    int k = blockIdx.x >> 2;
    int ytile = blockIdx.x & 3;
    int y0 = ytile << 4;
    int reg = (k >= 64) ? 1 : 0;
    int x = k & 63;
    int itile = t >> 6, lane = t & 63;
    int ylane = lane & 15, qg = lane >> 4;

    {   // stage XFh tile: 2048 uint4, 8 per thread
        const uint4* src = (const uint4*)XFh;
        uint4* dst = (uint4*)xfs;
        size_t kbase = ((size_t)k * 32768 + y0) >> 2;   // uint4 units
#pragma unroll
        for (int i = 0; i < 8; ++i) {
            int e = t + 256 * i;
            int f4w = e & 3;          // which uint4 within the 16-u32 row
            int bc  = e >> 2;         // b*128 + c
            int b   = bc >> 7, c = bc & 127;
            dst[e] = src[kbase + (size_t)b * 2048 + (size_t)c * 16 + f4w];
        }
    }

    const short8v* gBv = (const short8v*)gB;
    short8v g_r  = gBv[(((size_t)(0 * 2 + reg) * 64 + x) * 4 + ytile) * 64 + lane];
    short8v g_i  = gBv[(((size_t)(1 * 2 + reg) * 64 + x) * 4 + ytile) * 64 + lane];
    short8v g_ni = gBv[(((size_t)(2 * 2 + reg) * 64 + x) * 4 + ytile) * 64 + lane];

    const short8v* bAv = (const short8v*)bA;
    size_t aR = (((size_t)(0 * 2 + reg) * 4 + itile) * 128) * 64 + lane;
    size_t aI = (((size_t)(1 * 2 + reg) * 4 + itile) * 128) * 64 + lane;

    float tr[4][4], ti[4][4];
#pragma unroll
    for (int q = 0; q < 4; ++q)
#pragma unroll
        for (int b = 0; b < 4; ++b) { tr[q][b] = 0.f; ti[q][b] = 0.f; }

    __syncthreads();     // XFh tile ready

#pragma unroll 2
    for (int c = 0; c < 128; ++c) {
        short8v av = bAv[aR + (size_t)c * 64];
        short8v aw = bAv[aI + (size_t)c * 64];
        float4v z4 = {0.f, 0.f, 0.f, 0.f};
        float4v wr = __builtin_amdgcn_mfma_f32_16x16x32_bf16(av, g_r, z4, 0, 0, 0);
        wr = __builtin_amdgcn_mfma_f32_16x16x32_bf16(aw, g_ni, wr, 0, 0, 0);
        float4v wi = __builtin_amdgcn_mfma_f32_16x16x32_bf16(av, g_i, z4, 0, 0, 0);
        wi = __builtin_amdgcn_mfma_f32_16x16x32_bf16(aw, g_r, wi, 0, 0, 0);
#pragma unroll
        for (int b = 0; b < 4; ++b) {
            unsigned int xw = xfs[b][c][ylane];
            float xr = bf2f((unsigned short)(xw & 0xFFFFu));
            float xi = bf2f((unsigned short)(xw >> 16));
#pragma unroll
            for (int q = 0; q < 4; ++q) {
                tr[q][b] = fmaf(wr[q], xr, fmaf(-wi[q], xi, tr[q][b]));
                ti[q][b] = fmaf(wr[q], xi, fmaf( wi[q], xr, ti[q][b]));
            }
        }
    }

    short* tAs = (short*)tA;
    const size_t PLT = (size_t)8 * 32768 * 8;     // plane stride (shorts)
    int gidx = itile * 2 + (qg >> 1);
    int e0 = (qg & 1) * 4;
#pragma unroll
    for (int b = 0; b < 4; ++b) {
        size_t col = (size_t)k * 256 + (size_t)b * 64 + y0 + ylane;
        size_t off = ((size_t)gidx * 32768 + col) * 8 + e0;
        short rh[4], ih[4];
#pragma unroll
        for (int q = 0; q < 4; ++q) {
            rh[q] = (short)f2bf(tr[q][b]);
            ih[q] = (short)f2bf(ti[q][b]);
        }
        *(short4*)&tAs[0 * PLT + off] = make_short4(rh[0], rh[1], rh[2], rh[3]);
        *(short4*)&tAs[1 * PLT + off] = make_short4(ih[0], ih[1], ih[2], ih[3]);
    }
}

// MFMA contract, phase B -> OFh packed bf16-hi u32.
__global__ __launch_bounds__(256) void k_amfma(const unsigned short* __restrict__ AFa,
                                               const unsigned short* __restrict__ tA,
                                               unsigned int* __restrict__ OFh) {
    constexpr int SG = 8;
    __shared__ __align__(16) unsigned short bs[2 * SG * 16 * 8];   // 4 KB
    int t = threadIdx.x;
    int wave = t >> 6, lane = t & 63;
    int rt0 = wave * 2;
    int colp = lane & 15, rowq = lane >> 4;
    int k = blockIdx.x >> 2, b = blockIdx.x & 3;
    int reg = (k >= 64) ? 1 : 0;
    const short8v* AFv = (const short8v*)(AFa + (size_t)reg * 6 * 2 * 8 * 512);
    const size_t PLA = 2 * 8 * 64;
    const short8v* bsv = (const short8v*)bs;
    size_t p0 = (size_t)blockIdx.x * 64;

    for (int pt = 0; pt < 4; ++pt) {
        __syncthreads();
        {
            const float4* src = (const float4*)tA;
            float4* dst = (float4*)bs;
            int e = t;
            int pl = e >> 7; int rem = e & 127;
            int g = rem >> 4, li = rem & 15;
            dst[e] = src[((size_t)pl * SG + g) * 32768 + p0 + pt * 16 + li];
        }
        __syncthreads();
        float4v accR[2], accI[2];
#pragma unroll
        for (int rt = 0; rt < 2; ++rt) {
            accR[rt] = (float4v){0.f, 0.f, 0.f, 0.f};
            accI[rt] = (float4v){0.f, 0.f, 0.f, 0.f};
        }
#pragma unroll
        for (int kc = 0; kc < 2; ++kc) {
            int gi = kc * 4 + rowq;
            short8v Brh = bsv[((0 * SG + gi) << 4) + colp];
            short8v Bih = bsv[((1 * SG + gi) << 4) + colp];
#pragma unroll
            for (int rt = 0; rt < 2; ++rt) {
                size_t ab = ((size_t)kc * 8 + rt0 + rt) * 64 + lane;
                short8v A0 = AFv[0 * PLA + ab];
                short8v A1 = AFv[1 * PLA + ab];
                short8v A2 = AFv[2 * PLA + ab];
                short8v A3 = AFv[3 * PLA + ab];
                short8v A4 = AFv[4 * PLA + ab];
                short8v A5 = AFv[5 * PLA + ab];
                float4v r_ = accR[rt];
                r_ = __builtin_amdgcn_mfma_f32_16x16x32_bf16(A0, Brh, r_, 0, 0, 0);
                r_ = __builtin_amdgcn_mfma_f32_16x16x32_bf16(A1, Brh, r_, 0, 0, 0);
                r_ = __builtin_amdgcn_mfma_f32_16x16x32_bf16(A4, Bih, r_, 0, 0, 0);
                r_ = __builtin_amdgcn_mfma_f32_16x16x32_bf16(A5, Bih, r_, 0, 0, 0);
                accR[rt] = r_;
                float4v i_ = accI[rt];
                i_ = __builtin_amdgcn_mfma_f32_16x16x32_bf16(A2, Brh, i_, 0, 0, 0);
                i_ = __builtin_amdgcn_mfma_f32_16x16x32_bf16(A3, Brh, i_, 0, 0, 0);
                i_ = __builtin_amdgcn_mfma_f32_16x16x32_bf16(A0, Bih, i_, 0, 0, 0);
                i_ = __builtin_amdgcn_mfma_f32_16x16x32_bf16(A1, Bih, i_, 0, 0, 0);
                accI[rt] = i_;
            }
        }
        int m = pt * 16 + colp;
#pragma unroll
        for (int rt = 0; rt < 2; ++rt) {
            int o0 = (rt0 + rt) * 16 + rowq * 4;
#pragma unroll
            for (int q = 0; q < 4; ++q) {
                unsigned int pw = (unsigned int)f2bf(accR[rt][q])
                                | ((unsigned int)f2bf(accI[rt][q]) << 16);
                OFh[(size_t)k * 32768 + (size_t)b * 8192 + (size_t)(o0 + q) * 64 + m] = pw;
            }
        }
    }
}

// FUSED IH-GEMM + inverse-W MFMA. Block = one bo (b*128+o), 512 threads (8 waves).
__global__ __launch_bounds__(512) void k_ihinv(const unsigned short* __restrict__ AF2,
                                               const unsigned int* __restrict__ OFh,
                                               const unsigned short* __restrict__ EF,
                                               float* __restrict__ out) {
    constexpr int SG = 16, KC = 4, RTOT = 16;
    __shared__ __align__(16) unsigned short zs[2 * 256 * 64];     // 64 KB
    __shared__ __align__(16) unsigned short bs[2 * SG * 16 * 8];  // 8 KB
    int t = threadIdx.x;
    int wave = t >> 6, lane = t & 63;
    int colp = lane & 15, rowq = lane >> 4;
    int rt0 = wave * 2;
    int bo = blockIdx.x;
    size_t p0 = (size_t)bo * 64;
    const short8v* AFv = (const short8v*)AF2;
    const short8v* bsv = (const short8v*)bs;
    const size_t PLA = (size_t)KC * RTOT * 64;

    for (int pt = 0; pt < 4; ++pt) {
        __syncthreads();
        {   // stage B tile from OFh (packed): 512 threads x 4 rows each
            int li = t & 15, g = (t >> 4) & 15, half = t >> 8;
            int e0 = half * 4;
            short rh[4], ih[4];
#pragma unroll
            for (int j = 0; j < 4; ++j) {
                unsigned int w = OFh[(size_t)(g * 8 + e0 + j) * P_ + p0 + pt * 16 + li];
                rh[j] = (short)(w & 0xFFFFu);
                ih[j] = (short)(w >> 16);
            }
            int base = (g * 16 + li) * 8 + e0;
            *(short4*)&bs[0 * 2048 + base] = make_short4(rh[0], rh[1], rh[2], rh[3]);
            *(short4*)&bs[1 * 2048 + base] = make_short4(ih[0], ih[1], ih[2], ih[3]);
        }
        __syncthreads();
        float4v accR[2], accI[2];
#pragma unroll
        for (int rt = 0; rt < 2; ++rt) {
            accR[rt] = (float4v){0.f, 0.f, 0.f, 0.f};
            accI[rt] = (float4v){0.f, 0.f, 0.f, 0.f};
        }
#pragma unroll
        for (int kc = 0; kc < KC; ++kc) {
            int gi = kc * 4 + rowq;
            short8v Brh = bsv[((0 * SG + gi) << 4) + colp];
            short8v Bih = bsv[((1 * SG + gi) << 4) + colp];
#pragma unroll
            for (int rt = 0; rt < 2; ++rt) {
                size_t ab = ((size_t)kc * RTOT + rt0 + rt) * 64 + lane;
                short8v A0 = AFv[0 * PLA + ab];
                short8v A1 = AFv[1 * PLA + ab];
                short8v A2 = AFv[2 * PLA + ab];
                short8v A3 = AFv[3 * PLA + ab];
                short8v A4 = AFv[4 * PLA + ab];
                short8v A5 = AFv[5 * PLA + ab];
                float4v r_ = accR[rt];
                r_ = __builtin_amdgcn_mfma_f32_16x16x32_bf16(A0, Brh, r_, 0, 0, 0);
                r_ = __builtin_amdgcn_mfma_f32_16x16x32_bf16(A1, Brh, r_, 0, 0, 0);
                r_ = __builtin_amdgcn_mfma_f32_16x16x32_bf16(A4, Bih, r_, 0, 0, 0);
                r_ = __builtin_amdgcn_mfma_f32_16x16x32_bf16(A5, Bih, r_, 0, 0, 0);
                accR[rt] = r_;
                float4v i_ = accI[rt];
                i_ = __builtin_amdgcn_mfma_f32_16x16x32_bf16(A2, Brh, i_, 0, 0, 0);
                i_ = __builtin_amdgcn_mfma_f32_16x16x32_bf16(A3, Brh, i_, 0, 0, 0);
                i_ = __builtin_amdgcn_mfma_f32_16x16x32_bf16(A0, Bih, i_, 0, 0, 0);
                i_ = __builtin_amdgcn_mfma_f32_16x16x32_bf16(A1, Bih, i_, 0, 0, 0);
                accI[rt] = i_;
            }
        }
#pragma unroll
        for (int rt = 0; rt < 2; ++rt)
#pragma unroll
            for (int q = 0; q < 4; ++q) {
                int h = (rt0 + rt) * 16 + rowq * 4 + q;
                int kwsw = (pt * 16 + colp) ^ ((h & 7) << 3);
                zs[h * 64 + kwsw] = (unsigned short)f2bf(accR[rt][q]);
                zs[16384 + h * 64 + kwsw] = (unsigned short)f2bf(accI[rt][q]);
            }
    }
    __syncthreads();

    const short8v* EFv = (const short8v*)EF;
    for (int nt = 0; nt < 16; ++nt) {
        short8v Er0  = EFv[((0 * 2 + 0) * 16 + nt) * 64 + lane];
        short8v Er1  = EFv[((0 * 2 + 1) * 16 + nt) * 64 + lane];
        short8v nEi0 = EFv[((1 * 2 + 0) * 16 + nt) * 64 + lane];
        short8v nEi1 = EFv[((1 * 2 + 1) * 16 + nt) * 64 + lane];
#pragma unroll
        for (int mtl = 0; mtl < 2; ++mtl) {
            int h0 = (wave * 2 + mtl) * 16;
            int hA = h0 + colp;
            int sw = (hA & 7) << 3;
            short8v Zr0 = *(const short8v*)&zs[hA * 64 + ((8 * rowq) ^ sw)];
            short8v Zr1 = *(const short8v*)&zs[hA * 64 + ((32 + 8 * rowq) ^ sw)];
            short8v Zi0 = *(const short8v*)&zs[16384 + hA * 64 + ((8 * rowq) ^ sw)];
            short8v Zi1 = *(const short8v*)&zs[16384 + hA * 64 + ((32 + 8 * rowq) ^ sw)];
            float4v acc = {0.f, 0.f, 0.f, 0.f};
            acc = __builtin_amdgcn_mfma_f32_16x16x32_bf16(Zr0, Er0,  acc, 0, 0, 0);
            acc = __builtin_amdgcn_mfma_f32_16x16x32_bf16(Zi0, nEi0, acc, 0, 0, 0);
            acc = __builtin_amdgcn_mfma_f32_16x16x32_bf16(Zr1, Er1,  acc, 0, 0, 0);
            acc = __builtin_amdgcn_mfma_f32_16x16x32_bf16(Zi1, nEi1, acc, 0, 0, 0);
            size_t ob = ((size_t)bo * 256 + h0 + rowq * 4) * 256 + nt * 16 + colp;
#pragma unroll
            for (int q = 0; q < 4; ++q)
                out[ob + (size_t)q * 256] = acc[q];
        }
    }
}

extern "C" void kernel_launch(void* const* d_in, const int* in_sizes, int n_in,
                              void* d_out, int out_size, void* d_ws, size_t ws_size,
                              hipStream_t stream) {
    const float* x  = (const float*)d_in[0];
    const float* a1 = (const float*)d_in[1];
    const float* b1 = (const float*)d_in[2];
    const float* c1 = (const float*)d_in[3];
    const float* d1 = (const float*)d_in[4];
    const float* a2 = (const float*)d_in[5];
    const float* b2 = (const float*)d_in[6];
    const float* c2 = (const float*)d_in[7];
    const float* d2 = (const float*)d_in[8];
    float* out = (float*)d_out;
    float* wsf = (float*)d_ws;

    if (ws_size < WS_FLOATS * sizeof(float)) return;

    unsigned short* Yt  = (unsigned short*)(wsf + oYT);
    unsigned int*   XFh = (unsigned int*)(wsf + oXF);
    unsigned int*   OFh = (unsigned int*)(wsf + oOF);
    float2*         G   = (float2*)(wsf + oOF);          // G lives in OF region until prepBG
    unsigned short* BF  = (unsigned short*)(wsf + oBF);
    unsigned short* AF1 = (unsigned short*)(wsf + oAF1);
    unsigned short* AF2 = (unsigned short*)(wsf + oAF2);
    unsigned short* bA  = (unsigned short*)(wsf + oYT);  // after cmfma1, Yt region is dead
    unsigned short* gB  = bA + 1048576;
    unsigned short* tA  = (unsigned short*)(wsf + oTA);
    unsigned short* AFa = (unsigned short*)(wsf + oG);
    unsigned short* EF  = (unsigned short*)(wsf + oEF);

    k_prepTables<<<2304, 256, 0, stream>>>(a1, a2, AF1, AF2, BF, EF, AFa);
    k_g<<<1024, 256, 0, stream>>>(c1, d1, c2, d2, G);
    k_stage1m<<<1024, 256, 0, stream>>>(x, BF, Yt);
    k_cmfma<256, 2><<<512, 256, 0, stream>>>(AF1, Yt, XFh);
    k_prepBG<<<7168, 256, 0, stream>>>(b1, b2, G, bA, gB);
    k_contractA<<<512, 256, 0, stream>>>(XFh, bA, gB, tA);
    k_amfma<<<512, 256, 0, stream>>>(AFa, tA, OFh);      // overwrites G (dead after prepBG)
    k_ihinv<<<512, 512, 0, stream>>>(AF2, OFh, EF, out);

    (void)in_sizes; (void)n_in; (void)out_size;
}

// Round 20
// 187.488 us; speedup vs baseline: 1.2943x; 1.1338x over previous
//
#include <hip/hip_runtime.h>
#include <math.h>

// FactorizedSpectralConv2d: pruned-DFT + TT contraction, MFMA everywhere matmul-shaped.
// All intermediates and operand tables bf16-hi (fp32 MFMA accumulation throughout).
//
//   k_prepTables: bf16-hi A-frag tables FH/IH (3 planes) + FW B-frags (split) +
//                 invW E B-frags + a A-frags (3 planes)
//   k_g         : g[r][j][x][y] = sum_k cc[j,x,k]*dc[k,y]  (G in then-dead OF region)
//   k_prepBG    : bf16 frag tables for b (A) and g (B) from G
//   k_stage1m   : W-DFT of x via MFMA -> Yt 2 bf16-HI planes (LDS-staged split twiddles)
//   k_cmfma     : XFh[k][p] = sum_h FH[k][h] Yt[h][p], packed bf16-hi u32 (4 MFMAs/(kc,rt))
//   k_contractA : MFMA w-GEMM + fp32 t-update; packed XFh tile staged in 32KB LDS;
//                 t written as bf16-HI frag planes tA (2 planes)
//   k_amfma     : OFh[o,(k,b,m)] = sum_i a[o,i] tA[i,(k,b,m)], packed bf16-hi u32 (4 MFMAs)
//   k_ihinv     : FUSED per-bo block: phase1 Z = IH·OFh (4 MFMAs/(kc,rt), Z -> LDS bf16-hi
//                 XOR-swizzled); phase2 out = Re(Z . E) via MFMA from LDS.

#define TWO_PI 6.28318530717958647692f

typedef __attribute__((ext_vector_type(8))) short short8v;   // 8 bf16 (4 VGPRs)
typedef __attribute__((ext_vector_type(4))) float float4v;   // MFMA C/D

namespace {
constexpr size_t P_ = 32768;            // B*C*KW pixel batch width

// workspace float offsets
constexpr size_t oYT = 0;                     // Yt: 2 bf16-hi planes [32][32768][8]
                                              //   then bA/gB + tA (contract)
constexpr size_t oTA = 1048576;               // tA: 2 planes [8][32768][8] bf16
constexpr size_t oXF = 16777216;              // XFh u32 16.7MB (packed bf16-hi re|im)
constexpr size_t oOF = 25165824;              // G f2 (2MB, until prepBG) then OFh u32 16.7MB
constexpr size_t oBF = 33554432;              // FW B-frag table: 65536 shorts
constexpr size_t oAF1 = 33587200;             // FH frags: 98304 shorts (3 planes)
constexpr size_t oAF2 = 33685504;             // IH frags: 98304 shorts (3 planes)
constexpr size_t oG  = 33792000;              // AFa (49152 shorts) then EF (32768 shorts)
constexpr size_t oEF = oG + 262144;
constexpr size_t WS_FLOATS = oG + 524288;     // ~137.3 MB
}

__device__ __forceinline__ unsigned short f2bf(float f) {   // RNE float->bf16 bits
    unsigned int u = __float_as_uint(f);
    unsigned int r = (u + 0x7FFFu + ((u >> 16) & 1u)) >> 16;
    return (unsigned short)r;
}
__device__ __forceinline__ float bf2f(unsigned short b) {
    return __uint_as_float(((unsigned int)b) << 16);
}

// All static fragment tables in one launch:
//   [0, 98304)        AF1 (FH) bf16-hi A-frags, 3 planes: cos, sin, -sin
//   [98304, 196608)   AF2 (IH) bf16-hi A-frags, 3 planes
//   [196608, 262144)  BF: FW B-frags (4 planes ch,cl,sh,sl — split kept for stage1m)
//   [262144, 294912)  EF: invW twiddle B-frags (2 planes Er, -Ei; bf16-hi, scaled)
//   [294912, 344064)  AFa: a1/a2 bf16-hi A-frags, 3 planes per reg: ar, ai, -ai
__global__ __launch_bounds__(256) void k_prepTables(const float* __restrict__ a1,
                                                    const float* __restrict__ a2,
                                                    unsigned short* __restrict__ AF1,
                                                    unsigned short* __restrict__ AF2,
                                                    unsigned short* __restrict__ BF,
                                                    unsigned short* __restrict__ EF,
                                                    unsigned short* __restrict__ AFa) {
    int idx = blockIdx.x * 256 + threadIdx.x;      // < 344064
    if (idx < 196608) {
        int tbl = (idx >= 98304);
        int id = tbl ? (idx - 98304) : idx;        // < 98304
        int e = id & 7, lane = (id >> 3) & 63;
        int pl = id >> 15;                          // 0..2
        float ang;
        if (!tbl) {
            int rt = (id >> 9) & 7, kc = (id >> 12) & 7;
            int r = rt * 16 + (lane & 15);             // k-row (128)
            int s = kc * 32 + 8 * (lane >> 4) + e;     // h (256)
            int kh = r + ((r >= 64) ? 128 : 0);
            int ph = (kh * s) & 255;
            ang = -TWO_PI * (float)ph / 256.0f;
        } else {
            int rt = (id >> 9) & 15, kc = (id >> 13) & 3;
            int r = rt * 16 + (lane & 15);             // h (256)
            int s = kc * 32 + 8 * (lane >> 4) + e;     // k (128)
            int kh = s + ((s >= 64) ? 128 : 0);
            int ph = (kh * r) & 255;
            ang = TWO_PI * (float)ph / 256.0f;
        }
        float sn, cs; sincosf(ang, &sn, &cs);
        float v = (pl == 0) ? cs : ((pl == 1) ? sn : -sn);
        (tbl ? AF2 : AF1)[id] = f2bf(v);
    } else if (idx < 262144) {
        int id = idx - 196608;                          // < 65536
        int e = id & 7, lane = (id >> 3) & 63;
        int nt = (id >> 9) & 3, kc = (id >> 11) & 7;
        int pl = id >> 14;                              // 0..3
        int kw = nt * 16 + (lane & 15);
        int w = kc * 32 + 8 * (lane >> 4) + e;
        int ph = (w * kw) & 255;
        float ang = -TWO_PI * (float)ph / 256.0f;
        float sn, cs; sincosf(ang, &sn, &cs);
        float base = (pl < 2) ? cs : sn;
        unsigned short hi = f2bf(base);
        unsigned short out = (pl & 1) ? f2bf(base - bf2f(hi)) : hi;
        BF[id] = out;
    } else if (idx < 294912) {
        int id = idx - 262144;                          // < 32768
        int e = id & 7, lane = (id >> 3) & 63;
        int nt = (id >> 9) & 15, kc = (id >> 13) & 1, pl = id >> 14;
        int w = nt * 16 + (lane & 15);
        int kw = kc * 32 + 8 * (lane >> 4) + e;
        int ph = (kw * w) & 255;
        float ang = TWO_PI * (float)ph / 256.0f;
        float sn, cs; sincosf(ang, &sn, &cs);
        float sc = ((kw == 0) ? 1.0f : 2.0f) / 65536.0f;
        float v = (pl == 0) ? (sc * cs) : (-sc * sn);
        EF[id] = f2bf(v);
    } else {
        int id = idx - 294912;                          // < 49152
        int e = id & 7, lane = (id >> 3) & 63;
        int rt = (id >> 9) & 7, kc = (id >> 12) & 1;
        int plreg = id >> 13;                           // 0..5
        int reg = plreg / 3, pl = plreg % 3;
        int o = rt * 16 + (lane & 15);
        int i = kc * 32 + 8 * (lane >> 4) + e;
        const float* ap = reg ? a2 : a1;
        float ar = ap[(o * 64 + i) * 2 + 0];
        float ai = ap[(o * 64 + i) * 2 + 1];
        float v = (pl == 0) ? ar : ((pl == 1) ? ai : -ai);
        AFa[id] = f2bf(v);
    }
}

// g[r][j][x][y] = sum_k cc[j,x,k] * dc[k,y]
__global__ __launch_bounds__(256) void k_g(const float* __restrict__ c1, const float* __restrict__ d1,
                                           const float* __restrict__ c2, const float* __restrict__ d2,
                                           float2* __restrict__ G) {
    int idx = blockIdx.x * 256 + threadIdx.x;      // < 262144
    int r = idx >> 17;
    int rem = idx & 131071;
    int j = rem >> 12;
    int xy = rem & 4095;
    int xm = xy >> 6, ym = xy & 63;
    const float* cp = r ? c2 : c1;
    const float* dp = r ? d2 : d1;
    float sr = 0.f, si = 0.f;
    for (int kk = 0; kk < 32; ++kk) {
        float cr = cp[((j * 64 + xm) * 32 + kk) * 2 + 0];
        float ci = cp[((j * 64 + xm) * 32 + kk) * 2 + 1];
        float dr = dp[(kk * 64 + ym) * 2 + 0];
        float di = dp[(kk * 64 + ym) * 2 + 1];
        sr = fmaf(cr, dr, fmaf(-ci, di, sr));
        si = fmaf(cr, di, fmaf( ci, dr, si));
    }
    G[(size_t)(r * 32 + j) * 4096 + xy] = make_float2(sr, si);
}

// bf16 fragment tables for the contraction (reads G).
__global__ __launch_bounds__(256) void k_prepBG(const float* __restrict__ b1, const float* __restrict__ b2,
                                                const float2* __restrict__ G,
                                                unsigned short* __restrict__ bA,
                                                unsigned short* __restrict__ gB) {
    size_t idx = (size_t)blockIdx.x * 256 + threadIdx.x;
    if (idx < 1048576) {
        int e     = idx & 7;
        int lane  = (idx >> 3) & 63;
        int c     = (idx >> 9) & 127;
        int itile = (idx >> 16) & 3;
        int reg   = (idx >> 18) & 1;
        int plane = (idx >> 19) & 1;
        int i = itile * 16 + (lane & 15);
        int j = 8 * (lane >> 4) + e;
        const float* bp = reg ? b2 : b1;
        float v = bp[((size_t)(i * 128 + c) * 32 + j) * 2 + plane];
        bA[idx] = f2bf(v);
    } else if (idx < 1048576 + 786432) {
        size_t i2 = idx - 1048576;
        int e     = i2 & 7;
        int lane  = (i2 >> 3) & 63;
        int ytile = (i2 >> 9) & 3;
        int x     = (i2 >> 11) & 63;
        int reg   = (i2 >> 17) & 1;
        int plane = (int)(i2 >> 18);           // 0,1,2
        int y = ytile * 16 + (lane & 15);
        int j = 8 * (lane >> 4) + e;
        float2 gv = G[(size_t)(reg * 32 + j) * 4096 + x * 64 + y];
        float v = (plane == 0) ? gv.x : ((plane == 1) ? gv.y : -gv.y);
        gB[i2] = f2bf(v);
    }
}

// MFMA W-DFT v5: BF staged via LDS in 32KB barrier-synced phases (2 kc each).
// Yt output = 2 bf16-HI planes (re, im).
__global__ __launch_bounds__(256) void k_stage1m(const float* __restrict__ x,
                                                 const unsigned short* __restrict__ BF,
                                                 unsigned short* __restrict__ Yt) {
    __shared__ __align__(16) unsigned short es[16384];   // 32 KB
    int t = threadIdx.x;
    int wave = t >> 6, lane = t & 63;
    size_t row0 = (size_t)blockIdx.x * 128 + (size_t)wave * 32;
    int colp = lane & 15, rowq = lane >> 4;
    const short8v* esv = (const short8v*)es;

    float4v accR[2][4], accI[2][4];
#pragma unroll
    for (int rt = 0; rt < 2; ++rt)
#pragma unroll
        for (int nt = 0; nt < 4; ++nt) {
            accR[rt][nt] = (float4v){0.f, 0.f, 0.f, 0.f};
            accI[rt][nt] = (float4v){0.f, 0.f, 0.f, 0.f};
        }

    const float* xb0 = x + (row0 + colp) * 256 + 8 * rowq;
    const float* xb1 = xb0 + 16 * 256;
    float4 nv[2][2];
    nv[0][0] = *(const float4*)(xb0);  nv[0][1] = *(const float4*)(xb0 + 4);
    nv[1][0] = *(const float4*)(xb1);  nv[1][1] = *(const float4*)(xb1 + 4);

    const float4* bf4 = (const float4*)BF;
    for (int ph = 0; ph < 4; ++ph) {
        __syncthreads();
        {
#pragma unroll
            for (int i = 0; i < 8; ++i) {
                int idx = t + 256 * i;
                int li  = idx & 63;
                int nt  = (idx >> 6) & 3;
                int kcl = (idx >> 8) & 1;
                int pl  = idx >> 9;
                ((float4*)es)[idx] = bf4[((size_t)(pl * 8 + ph * 2 + kcl) * 4 + nt) * 64 + li];
            }
        }
        __syncthreads();
        for (int kcl = 0; kcl < 2; ++kcl) {
            int kc = ph * 2 + kcl;
            short8v xh[2];
#pragma unroll
            for (int rt = 0; rt < 2; ++rt) {
                float4 v0 = nv[rt][0], v1 = nv[rt][1];
                float vv[8] = {v0.x, v0.y, v0.z, v0.w, v1.x, v1.y, v1.z, v1.w};
#pragma unroll
                for (int j = 0; j < 8; ++j) xh[rt][j] = (short)f2bf(vv[j]);
            }
            if (kc < 7) {
                nv[0][0] = *(const float4*)(xb0 + (kc + 1) * 32);
                nv[0][1] = *(const float4*)(xb0 + (kc + 1) * 32 + 4);
                nv[1][0] = *(const float4*)(xb1 + (kc + 1) * 32);
                nv[1][1] = *(const float4*)(xb1 + (kc + 1) * 32 + 4);
            }
#pragma unroll
            for (int nt = 0; nt < 4; ++nt) {
                short8v Bch = esv[((0 * 2 + kcl) * 4 + nt) * 64 + lane];
                short8v Bcl = esv[((1 * 2 + kcl) * 4 + nt) * 64 + lane];
                short8v Bsh = esv[((2 * 2 + kcl) * 4 + nt) * 64 + lane];
                short8v Bsl = esv[((3 * 2 + kcl) * 4 + nt) * 64 + lane];
#pragma unroll
                for (int rt = 0; rt < 2; ++rt) {
                    float4v r_ = accR[rt][nt];
                    r_ = __builtin_amdgcn_mfma_f32_16x16x32_bf16(xh[rt], Bch, r_, 0, 0, 0);
                    r_ = __builtin_amdgcn_mfma_f32_16x16x32_bf16(xh[rt], Bcl, r_, 0, 0, 0);
                    accR[rt][nt] = r_;
                    float4v i_ = accI[rt][nt];
                    i_ = __builtin_amdgcn_mfma_f32_16x16x32_bf16(xh[rt], Bsh, i_, 0, 0, 0);
                    i_ = __builtin_amdgcn_mfma_f32_16x16x32_bf16(xh[rt], Bsl, i_, 0, 0, 0);
                    accI[rt][nt] = i_;
                }
            }
        }
    }

    short* Yts = (short*)Yt;
    const size_t PLY = (size_t)32 * 32768 * 8;
#pragma unroll
    for (int rt = 0; rt < 2; ++rt) {
        size_t xrow0 = row0 + rt * 16 + rowq * 4;
        int h = (int)(xrow0 & 255), bc = (int)(xrow0 >> 8);
        size_t gbase = (size_t)(h >> 3) * 32768;
        int e0 = h & 7;
#pragma unroll
        for (int nt = 0; nt < 4; ++nt) {
            size_t p = (size_t)bc * 64 + nt * 16 + colp;
            size_t off = (gbase + p) * 8 + e0;
            float4v R = accR[rt][nt], I = accI[rt][nt];
            short rh[4], ih[4];
#pragma unroll
            for (int q = 0; q < 4; ++q) {
                rh[q] = (short)f2bf(R[q]);
                ih[q] = (short)f2bf(I[q]);
            }
            *(short4*)&Yts[0 * PLY + off] = make_short4(rh[0], rh[1], rh[2], rh[3]);
            *(short4*)&Yts[1 * PLY + off] = make_short4(ih[0], ih[1], ih[2], ih[3]);
        }
    }
}

// bf16-hi complex MFMA GEMM (FH hi-A x Yt hi-B -> XFh packed bf16-hi u32).
// A planes: 0=cos, 1=sin, 2=-sin.  4 MFMAs per (kc,rt).
template<int S, int RT_W>
__global__ __launch_bounds__(256) void k_cmfma(const unsigned short* __restrict__ AF,
                                               const unsigned short* __restrict__ Bt,
                                               unsigned int* __restrict__ XFh) {
    constexpr int KC = S / 32;
    constexpr int SG = S / 8;
    constexpr int RTOT = RT_W * 4;
    __shared__ __align__(16) unsigned short bs[2 * SG * 16 * 8];   // 16 KB (S=256)
    int t = threadIdx.x;
    int wave = t >> 6, lane = t & 63;
    int rt0 = wave * RT_W;
    int colp = lane & 15, rowq = lane >> 4;
    const short8v* AFv = (const short8v*)AF;
    const short8v* bsv = (const short8v*)bs;
    const size_t PLA = (size_t)KC * RTOT * 64;

    for (int pt = 0; pt < 4; ++pt) {
        int p0 = blockIdx.x * 64 + pt * 16;
        __syncthreads();
        {
            const float4* src = (const float4*)Bt;
            float4* dst = (float4*)bs;
            for (int e = t; e < 2 * SG * 16; e += 256) {
                int pl = e / (SG * 16); int rem = e - pl * (SG * 16);
                int g = rem >> 4, li = rem & 15;
                dst[e] = src[((size_t)pl * SG + g) * 32768 + p0 + li];
            }
        }
        __syncthreads();
        float4v accR[RT_W], accI[RT_W];
#pragma unroll
        for (int rt = 0; rt < RT_W; ++rt) {
            accR[rt] = (float4v){0.f, 0.f, 0.f, 0.f};
            accI[rt] = (float4v){0.f, 0.f, 0.f, 0.f};
        }
#pragma unroll
        for (int kc = 0; kc < KC; ++kc) {
            int gi = kc * 4 + rowq;
            short8v Brh = bsv[((0 * SG + gi) << 4) + colp];
            short8v Bih = bsv[((1 * SG + gi) << 4) + colp];
#pragma unroll
            for (int rt = 0; rt < RT_W; ++rt) {
                size_t ab = ((size_t)kc * RTOT + rt0 + rt) * 64 + lane;
                short8v Ac  = AFv[0 * PLA + ab];   // cos
                short8v As  = AFv[1 * PLA + ab];   // sin
                short8v Ans = AFv[2 * PLA + ab];   // -sin
                float4v r_ = accR[rt];
                r_ = __builtin_amdgcn_mfma_f32_16x16x32_bf16(Ac,  Brh, r_, 0, 0, 0);
                r_ = __builtin_amdgcn_mfma_f32_16x16x32_bf16(Ans, Bih, r_, 0, 0, 0);
                accR[rt] = r_;
                float4v i_ = accI[rt];
                i_ = __builtin_amdgcn_mfma_f32_16x16x32_bf16(As, Brh, i_, 0, 0, 0);
                i_ = __builtin_amdgcn_mfma_f32_16x16x32_bf16(Ac, Bih, i_, 0, 0, 0);
                accI[rt] = i_;
            }
        }
#pragma unroll
        for (int rt = 0; rt < RT_W; ++rt) {
            int rbase = (rt0 + rt) * 16 + rowq * 4;
#pragma unroll
            for (int q = 0; q < 4; ++q) {
                unsigned int pw = (unsigned int)f2bf(accR[rt][q])
                                | ((unsigned int)f2bf(accI[rt][q]) << 16);
                XFh[(size_t)(rbase + q) * P_ + p0 + colp] = pw;
            }
        }
    }
}

// MFMA contract, phase A -> tA bf16-HI only (2 planes).
// Packed XFh tile (4 b x 128 c x 16 y u32 = 32 KB) staged in LDS.
__global__ __launch_bounds__(256) void k_contractA(const unsigned int* __restrict__ XFh,
                                                   const unsigned short* __restrict__ bA,
                                                   const unsigned short* __restrict__ gB,
                                                   unsigned short* __restrict__ tA) {
    __shared__ __align__(16) unsigned int xfs[4][128][16];   // 32 KB
    int t = threadIdx.x;
    int k = blockIdx.x >> 2;
    int ytile = blockIdx.x & 3;
    int y0 = ytile << 4;
    int reg = (k >= 64) ? 1 : 0;
    int x = k & 63;
    int itile = t >> 6, lane = t & 63;
    int ylane = lane & 15, qg = lane >> 4;

    {   // stage XFh tile: 2048 uint4, 8 per thread
        const uint4* src = (const uint4*)XFh;
        uint4* dst = (uint4*)xfs;
        size_t kbase = ((size_t)k * 32768 + y0) >> 2;   // uint4 units
#pragma unroll
        for (int i = 0; i < 8; ++i) {
            int e = t + 256 * i;
            int f4w = e & 3;          // which uint4 within the 16-u32 row
            int bc  = e >> 2;         // b*128 + c
            int b   = bc >> 7, c = bc & 127;
            dst[e] = src[kbase + (size_t)b * 2048 + (size_t)c * 16 + f4w];
        }
    }

    const short8v* gBv = (const short8v*)gB;
    short8v g_r  = gBv[(((size_t)(0 * 2 + reg) * 64 + x) * 4 + ytile) * 64 + lane];
    short8v g_i  = gBv[(((size_t)(1 * 2 + reg) * 64 + x) * 4 + ytile) * 64 + lane];
    short8v g_ni = gBv[(((size_t)(2 * 2 + reg) * 64 + x) * 4 + ytile) * 64 + lane];

    const short8v* bAv = (const short8v*)bA;
    size_t aR = (((size_t)(0 * 2 + reg) * 4 + itile) * 128) * 64 + lane;
    size_t aI = (((size_t)(1 * 2 + reg) * 4 + itile) * 128) * 64 + lane;

    float tr[4][4], ti[4][4];
#pragma unroll
    for (int q = 0; q < 4; ++q)
#pragma unroll
        for (int b = 0; b < 4; ++b) { tr[q][b] = 0.f; ti[q][b] = 0.f; }

    __syncthreads();     // XFh tile ready

#pragma unroll 2
    for (int c = 0; c < 128; ++c) {
        short8v av = bAv[aR + (size_t)c * 64];
        short8v aw = bAv[aI + (size_t)c * 64];
        float4v z4 = {0.f, 0.f, 0.f, 0.f};
        float4v wr = __builtin_amdgcn_mfma_f32_16x16x32_bf16(av, g_r, z4, 0, 0, 0);
        wr = __builtin_amdgcn_mfma_f32_16x16x32_bf16(aw, g_ni, wr, 0, 0, 0);
        float4v wi = __builtin_amdgcn_mfma_f32_16x16x32_bf16(av, g_i, z4, 0, 0, 0);
        wi = __builtin_amdgcn_mfma_f32_16x16x32_bf16(aw, g_r, wi, 0, 0, 0);
#pragma unroll
        for (int b = 0; b < 4; ++b) {
            unsigned int xw = xfs[b][c][ylane];
            float xr = bf2f((unsigned short)(xw & 0xFFFFu));
            float xi = bf2f((unsigned short)(xw >> 16));
#pragma unroll
            for (int q = 0; q < 4; ++q) {
                tr[q][b] = fmaf(wr[q], xr, fmaf(-wi[q], xi, tr[q][b]));
                ti[q][b] = fmaf(wr[q], xi, fmaf( wi[q], xr, ti[q][b]));
            }
        }
    }

    short* tAs = (short*)tA;
    const size_t PLT = (size_t)8 * 32768 * 8;     // plane stride (shorts)
    int gidx = itile * 2 + (qg >> 1);
    int e0 = (qg & 1) * 4;
#pragma unroll
    for (int b = 0; b < 4; ++b) {
        size_t col = (size_t)k * 256 + (size_t)b * 64 + y0 + ylane;
        size_t off = ((size_t)gidx * 32768 + col) * 8 + e0;
        short rh[4], ih[4];
#pragma unroll
        for (int q = 0; q < 4; ++q) {
            rh[q] = (short)f2bf(tr[q][b]);
            ih[q] = (short)f2bf(ti[q][b]);
        }
        *(short4*)&tAs[0 * PLT + off] = make_short4(rh[0], rh[1], rh[2], rh[3]);
        *(short4*)&tAs[1 * PLT + off] = make_short4(ih[0], ih[1], ih[2], ih[3]);
    }
}

// MFMA contract, phase B -> OFh packed bf16-hi u32.
// AFa planes: 0=ar, 1=ai, 2=-ai.  4 MFMAs per (kc,rt).
__global__ __launch_bounds__(256) void k_amfma(const unsigned short* __restrict__ AFa,
                                               const unsigned short* __restrict__ tA,
                                               unsigned int* __restrict__ OFh) {
    constexpr int SG = 8;
    __shared__ __align__(16) unsigned short bs[2 * SG * 16 * 8];   // 4 KB
    int t = threadIdx.x;
    int wave = t >> 6, lane = t & 63;
    int rt0 = wave * 2;
    int colp = lane & 15, rowq = lane >> 4;
    int k = blockIdx.x >> 2, b = blockIdx.x & 3;
    int reg = (k >= 64) ? 1 : 0;
    const short8v* AFv = (const short8v*)(AFa + (size_t)reg * 3 * 2 * 8 * 512);
    const size_t PLA = 2 * 8 * 64;
    const short8v* bsv = (const short8v*)bs;
    size_t p0 = (size_t)blockIdx.x * 64;

    for (int pt = 0; pt < 4; ++pt) {
        __syncthreads();
        {
            const float4* src = (const float4*)tA;
            float4* dst = (float4*)bs;
            int e = t;
            int pl = e >> 7; int rem = e & 127;
            int g = rem >> 4, li = rem & 15;
            dst[e] = src[((size_t)pl * SG + g) * 32768 + p0 + pt * 16 + li];
        }
        __syncthreads();
        float4v accR[2], accI[2];
#pragma unroll
        for (int rt = 0; rt < 2; ++rt) {
            accR[rt] = (float4v){0.f, 0.f, 0.f, 0.f};
            accI[rt] = (float4v){0.f, 0.f, 0.f, 0.f};
        }
#pragma unroll
        for (int kc = 0; kc < 2; ++kc) {
            int gi = kc * 4 + rowq;
            short8v Brh = bsv[((0 * SG + gi) << 4) + colp];
            short8v Bih = bsv[((1 * SG + gi) << 4) + colp];
#pragma unroll
            for (int rt = 0; rt < 2; ++rt) {
                size_t ab = ((size_t)kc * 8 + rt0 + rt) * 64 + lane;
                short8v Ar  = AFv[0 * PLA + ab];
                short8v Ai  = AFv[1 * PLA + ab];
                short8v Ani = AFv[2 * PLA + ab];
                float4v r_ = accR[rt];
                r_ = __builtin_amdgcn_mfma_f32_16x16x32_bf16(Ar,  Brh, r_, 0, 0, 0);
                r_ = __builtin_amdgcn_mfma_f32_16x16x32_bf16(Ani, Bih, r_, 0, 0, 0);
                accR[rt] = r_;
                float4v i_ = accI[rt];
                i_ = __builtin_amdgcn_mfma_f32_16x16x32_bf16(Ai, Brh, i_, 0, 0, 0);
                i_ = __builtin_amdgcn_mfma_f32_16x16x32_bf16(Ar, Bih, i_, 0, 0, 0);
                accI[rt] = i_;
            }
        }
        int m = pt * 16 + colp;
#pragma unroll
        for (int rt = 0; rt < 2; ++rt) {
            int o0 = (rt0 + rt) * 16 + rowq * 4;
#pragma unroll
            for (int q = 0; q < 4; ++q) {
                unsigned int pw = (unsigned int)f2bf(accR[rt][q])
                                | ((unsigned int)f2bf(accI[rt][q]) << 16);
                OFh[(size_t)k * 32768 + (size_t)b * 8192 + (size_t)(o0 + q) * 64 + m] = pw;
            }
        }
    }
}

// FUSED IH-GEMM + inverse-W MFMA. Block = one bo (b*128+o), 512 threads (8 waves).
// Phase 1: IH hi-A (3 planes) x OFh hi-B: 4 MFMAs per (kc,rt).
__global__ __launch_bounds__(512) void k_ihinv(const unsigned short* __restrict__ AF2,
                                               const unsigned int* __restrict__ OFh,
                                               const unsigned short* __restrict__ EF,
                                               float* __restrict__ out) {
    constexpr int SG = 16, KC = 4, RTOT = 16;
    __shared__ __align__(16) unsigned short zs[2 * 256 * 64];     // 64 KB
    __shared__ __align__(16) unsigned short bs[2 * SG * 16 * 8];  // 8 KB
    int t = threadIdx.x;
    int wave = t >> 6, lane = t & 63;
    int colp = lane & 15, rowq = lane >> 4;
    int rt0 = wave * 2;
    int bo = blockIdx.x;
    size_t p0 = (size_t)bo * 64;
    const short8v* AFv = (const short8v*)AF2;
    const short8v* bsv = (const short8v*)bs;
    const size_t PLA = (size_t)KC * RTOT * 64;

    for (int pt = 0; pt < 4; ++pt) {
        __syncthreads();
        {   // stage B tile from OFh (packed): 512 threads x 4 rows each
            int li = t & 15, g = (t >> 4) & 15, half = t >> 8;
            int e0 = half * 4;
            short rh[4], ih[4];
#pragma unroll
            for (int j = 0; j < 4; ++j) {
                unsigned int w = OFh[(size_t)(g * 8 + e0 + j) * P_ + p0 + pt * 16 + li];
                rh[j] = (short)(w & 0xFFFFu);
                ih[j] = (short)(w >> 16);
            }
            int base = (g * 16 + li) * 8 + e0;
            *(short4*)&bs[0 * 2048 + base] = make_short4(rh[0], rh[1], rh[2], rh[3]);
            *(short4*)&bs[1 * 2048 + base] = make_short4(ih[0], ih[1], ih[2], ih[3]);
        }
        __syncthreads();
        float4v accR[2], accI[2];
#pragma unroll
        for (int rt = 0; rt < 2; ++rt) {
            accR[rt] = (float4v){0.f, 0.f, 0.f, 0.f};
            accI[rt] = (float4v){0.f, 0.f, 0.f, 0.f};
        }
#pragma unroll
        for (int kc = 0; kc < KC; ++kc) {
            int gi = kc * 4 + rowq;
            short8v Brh = bsv[((0 * SG + gi) << 4) + colp];
            short8v Bih = bsv[((1 * SG + gi) << 4) + colp];
#pragma unroll
            for (int rt = 0; rt < 2; ++rt) {
                size_t ab = ((size_t)kc * RTOT + rt0 + rt) * 64 + lane;
                short8v Ac  = AFv[0 * PLA + ab];
                short8v As  = AFv[1 * PLA + ab];
                short8v Ans = AFv[2 * PLA + ab];
                float4v r_ = accR[rt];
                r_ = __builtin_amdgcn_mfma_f32_16x16x32_bf16(Ac,  Brh, r_, 0, 0, 0);
                r_ = __builtin_amdgcn_mfma_f32_16x16x32_bf16(Ans, Bih, r_, 0, 0, 0);
                accR[rt] = r_;
                float4v i_ = accI[rt];
                i_ = __builtin_amdgcn_mfma_f32_16x16x32_bf16(As, Brh, i_, 0, 0, 0);
                i_ = __builtin_amdgcn_mfma_f32_16x16x32_bf16(Ac, Bih, i_, 0, 0, 0);
                accI[rt] = i_;
            }
        }
#pragma unroll
        for (int rt = 0; rt < 2; ++rt)
#pragma unroll
            for (int q = 0; q < 4; ++q) {
                int h = (rt0 + rt) * 16 + rowq * 4 + q;
                int kwsw = (pt * 16 + colp) ^ ((h & 7) << 3);
                zs[h * 64 + kwsw] = (unsigned short)f2bf(accR[rt][q]);
                zs[16384 + h * 64 + kwsw] = (unsigned short)f2bf(accI[rt][q]);
            }
    }
    __syncthreads();

    const short8v* EFv = (const short8v*)EF;
    for (int nt = 0; nt < 16; ++nt) {
        short8v Er0  = EFv[((0 * 2 + 0) * 16 + nt) * 64 + lane];
        short8v Er1  = EFv[((0 * 2 + 1) * 16 + nt) * 64 + lane];
        short8v nEi0 = EFv[((1 * 2 + 0) * 16 + nt) * 64 + lane];
        short8v nEi1 = EFv[((1 * 2 + 1) * 16 + nt) * 64 + lane];
#pragma unroll
        for (int mtl = 0; mtl < 2; ++mtl) {
            int h0 = (wave * 2 + mtl) * 16;
            int hA = h0 + colp;
            int sw = (hA & 7) << 3;
            short8v Zr0 = *(const short8v*)&zs[hA * 64 + ((8 * rowq) ^ sw)];
            short8v Zr1 = *(const short8v*)&zs[hA * 64 + ((32 + 8 * rowq) ^ sw)];
            short8v Zi0 = *(const short8v*)&zs[16384 + hA * 64 + ((8 * rowq) ^ sw)];
            short8v Zi1 = *(const short8v*)&zs[16384 + hA * 64 + ((32 + 8 * rowq) ^ sw)];
            float4v acc = {0.f, 0.f, 0.f, 0.f};
            acc = __builtin_amdgcn_mfma_f32_16x16x32_bf16(Zr0, Er0,  acc, 0, 0, 0);
            acc = __builtin_amdgcn_mfma_f32_16x16x32_bf16(Zi0, nEi0, acc, 0, 0, 0);
            acc = __builtin_amdgcn_mfma_f32_16x16x32_bf16(Zr1, Er1,  acc, 0, 0, 0);
            acc = __builtin_amdgcn_mfma_f32_16x16x32_bf16(Zi1, nEi1, acc, 0, 0, 0);
            size_t ob = ((size_t)bo * 256 + h0 + rowq * 4) * 256 + nt * 16 + colp;
#pragma unroll
            for (int q = 0; q < 4; ++q)
                out[ob + (size_t)q * 256] = acc[q];
        }
    }
}

extern "C" void kernel_launch(void* const* d_in, const int* in_sizes, int n_in,
                              void* d_out, int out_size, void* d_ws, size_t ws_size,
                              hipStream_t stream) {
    const float* x  = (const float*)d_in[0];
    const float* a1 = (const float*)d_in[1];
    const float* b1 = (const float*)d_in[2];
    const float* c1 = (const float*)d_in[3];
    const float* d1 = (const float*)d_in[4];
    const float* a2 = (const float*)d_in[5];
    const float* b2 = (const float*)d_in[6];
    const float* c2 = (const float*)d_in[7];
    const float* d2 = (const float*)d_in[8];
    float* out = (float*)d_out;
    float* wsf = (float*)d_ws;

    if (ws_size < WS_FLOATS * sizeof(float)) return;

    unsigned short* Yt  = (unsigned short*)(wsf + oYT);
    unsigned int*   XFh = (unsigned int*)(wsf + oXF);
    unsigned int*   OFh = (unsigned int*)(wsf + oOF);
    float2*         G   = (float2*)(wsf + oOF);          // G lives in OF region until prepBG
    unsigned short* BF  = (unsigned short*)(wsf + oBF);
    unsigned short* AF1 = (unsigned short*)(wsf + oAF1);
    unsigned short* AF2 = (unsigned short*)(wsf + oAF2);
    unsigned short* bA  = (unsigned short*)(wsf + oYT);  // after cmfma1, Yt region is dead
    unsigned short* gB  = bA + 1048576;
    unsigned short* tA  = (unsigned short*)(wsf + oTA);
    unsigned short* AFa = (unsigned short*)(wsf + oG);
    unsigned short* EF  = (unsigned short*)(wsf + oEF);

    k_prepTables<<<1344, 256, 0, stream>>>(a1, a2, AF1, AF2, BF, EF, AFa);
    k_g<<<1024, 256, 0, stream>>>(c1, d1, c2, d2, G);
    k_stage1m<<<1024, 256, 0, stream>>>(x, BF, Yt);
    k_cmfma<256, 2><<<512, 256, 0, stream>>>(AF1, Yt, XFh);
    k_prepBG<<<7168, 256, 0, stream>>>(b1, b2, G, bA, gB);
    k_contractA<<<512, 256, 0, stream>>>(XFh, bA, gB, tA);
    k_amfma<<<512, 256, 0, stream>>>(AFa, tA, OFh);      // overwrites G (dead after prepBG)
    k_ihinv<<<512, 512, 0, stream>>>(AF2, OFh, EF, out);

    (void)in_sizes; (void)n_in; (void)out_size;
}

// Round 21
// 182.663 us; speedup vs baseline: 1.3285x; 1.0264x over previous
//
#include <hip/hip_runtime.h>
#include <math.h>

// FactorizedSpectralConv2d: pruned-DFT + TT contraction, MFMA everywhere matmul-shaped.
// ALL operands bf16-hi (fp32 MFMA accumulation throughout); 2 complex-MFMA per product.
//
//   k_prepTables: bf16-hi A-frag tables FH/IH (3 planes) + FW B-frags (2 planes) +
//                 invW E B-frags + a A-frags (3 planes)
//   k_g         : g[r][j][x][y] = sum_k cc[j,x,k]*dc[k,y]  (G in then-dead OF region)
//   k_prepBG    : bf16 frag tables for b (A) and g (B) from G
//   k_stage1m   : W-DFT of x via MFMA -> Yt 2 bf16-HI planes (16KB LDS twiddle phases,
//                 2 MFMAs per (nt,rt))
//   k_cmfma     : XFh[k][p] = sum_h FH[k][h] Yt[h][p], packed bf16-hi u32 (4 MFMAs/(kc,rt))
//   k_contractA : MFMA w-GEMM + fp32 t-update; packed XFh tile staged in 32KB LDS;
//                 t written as bf16-HI frag planes tA (2 planes)
//   k_amfma     : OFh[o,(k,b,m)] = sum_i a[o,i] tA[i,(k,b,m)], packed bf16-hi u32 (4 MFMAs)
//   k_ihinv     : FUSED per-bo block: phase1 Z = IH·OFh (4 MFMAs/(kc,rt), Z -> LDS bf16-hi
//                 XOR-swizzled); phase2 out = Re(Z . E) via MFMA from LDS.

#define TWO_PI 6.28318530717958647692f

typedef __attribute__((ext_vector_type(8))) short short8v;   // 8 bf16 (4 VGPRs)
typedef __attribute__((ext_vector_type(4))) float float4v;   // MFMA C/D

namespace {
constexpr size_t P_ = 32768;            // B*C*KW pixel batch width

// workspace float offsets
constexpr size_t oYT = 0;                     // Yt: 2 bf16-hi planes [32][32768][8]
                                              //   then bA/gB + tA (contract)
constexpr size_t oTA = 1048576;               // tA: 2 planes [8][32768][8] bf16
constexpr size_t oXF = 16777216;              // XFh u32 16.7MB (packed bf16-hi re|im)
constexpr size_t oOF = 25165824;              // G f2 (2MB, until prepBG) then OFh u32 16.7MB
constexpr size_t oBF = 33554432;              // FW B-frag table: 32768 shorts (2 planes)
constexpr size_t oAF1 = 33587200;             // FH frags: 98304 shorts (3 planes)
constexpr size_t oAF2 = 33685504;             // IH frags: 98304 shorts (3 planes)
constexpr size_t oG  = 33792000;              // AFa (49152 shorts) then EF (32768 shorts)
constexpr size_t oEF = oG + 262144;
constexpr size_t WS_FLOATS = oG + 524288;     // ~137.3 MB
}

__device__ __forceinline__ unsigned short f2bf(float f) {   // RNE float->bf16 bits
    unsigned int u = __float_as_uint(f);
    unsigned int r = (u + 0x7FFFu + ((u >> 16) & 1u)) >> 16;
    return (unsigned short)r;
}
__device__ __forceinline__ float bf2f(unsigned short b) {
    return __uint_as_float(((unsigned int)b) << 16);
}

// All static fragment tables in one launch:
//   [0, 98304)        AF1 (FH) bf16-hi A-frags, 3 planes: cos, sin, -sin
//   [98304, 196608)   AF2 (IH) bf16-hi A-frags, 3 planes
//   [196608, 229376)  BF: FW B-frags, 2 planes (cos, sin) bf16-hi
//   [229376, 262144)  EF: invW twiddle B-frags (2 planes Er, -Ei; bf16-hi, scaled)
//   [262144, 311296)  AFa: a1/a2 bf16-hi A-frags, 3 planes per reg: ar, ai, -ai
__global__ __launch_bounds__(256) void k_prepTables(const float* __restrict__ a1,
                                                    const float* __restrict__ a2,
                                                    unsigned short* __restrict__ AF1,
                                                    unsigned short* __restrict__ AF2,
                                                    unsigned short* __restrict__ BF,
                                                    unsigned short* __restrict__ EF,
                                                    unsigned short* __restrict__ AFa) {
    int idx = blockIdx.x * 256 + threadIdx.x;      // < 311296
    if (idx < 196608) {
        int tbl = (idx >= 98304);
        int id = tbl ? (idx - 98304) : idx;        // < 98304
        int e = id & 7, lane = (id >> 3) & 63;
        int pl = id >> 15;                          // 0..2
        float ang;
        if (!tbl) {
            int rt = (id >> 9) & 7, kc = (id >> 12) & 7;
            int r = rt * 16 + (lane & 15);             // k-row (128)
            int s = kc * 32 + 8 * (lane >> 4) + e;     // h (256)
            int kh = r + ((r >= 64) ? 128 : 0);
            int ph = (kh * s) & 255;
            ang = -TWO_PI * (float)ph / 256.0f;
        } else {
            int rt = (id >> 9) & 15, kc = (id >> 13) & 3;
            int r = rt * 16 + (lane & 15);             // h (256)
            int s = kc * 32 + 8 * (lane >> 4) + e;     // k (128)
            int kh = s + ((s >= 64) ? 128 : 0);
            int ph = (kh * r) & 255;
            ang = TWO_PI * (float)ph / 256.0f;
        }
        float sn, cs; sincosf(ang, &sn, &cs);
        float v = (pl == 0) ? cs : ((pl == 1) ? sn : -sn);
        (tbl ? AF2 : AF1)[id] = f2bf(v);
    } else if (idx < 229376) {
        int id = idx - 196608;                          // < 32768
        int e = id & 7, lane = (id >> 3) & 63;
        int nt = (id >> 9) & 3, kc = (id >> 11) & 7;
        int pl = id >> 14;                              // 0..1
        int kw = nt * 16 + (lane & 15);
        int w = kc * 32 + 8 * (lane >> 4) + e;
        int ph = (w * kw) & 255;
        float ang = -TWO_PI * (float)ph / 256.0f;
        float sn, cs; sincosf(ang, &sn, &cs);
        BF[id] = f2bf((pl == 0) ? cs : sn);
    } else if (idx < 262144) {
        int id = idx - 229376;                          // < 32768
        int e = id & 7, lane = (id >> 3) & 63;
        int nt = (id >> 9) & 15, kc = (id >> 13) & 1, pl = id >> 14;
        int w = nt * 16 + (lane & 15);
        int kw = kc * 32 + 8 * (lane >> 4) + e;
        int ph = (kw * w) & 255;
        float ang = TWO_PI * (float)ph / 256.0f;
        float sn, cs; sincosf(ang, &sn, &cs);
        float sc = ((kw == 0) ? 1.0f : 2.0f) / 65536.0f;
        float v = (pl == 0) ? (sc * cs) : (-sc * sn);
        EF[id] = f2bf(v);
    } else {
        int id = idx - 262144;                          // < 49152
        int e = id & 7, lane = (id >> 3) & 63;
        int rt = (id >> 9) & 7, kc = (id >> 12) & 1;
        int plreg = id >> 13;                           // 0..5
        int reg = plreg / 3, pl = plreg % 3;
        int o = rt * 16 + (lane & 15);
        int i = kc * 32 + 8 * (lane >> 4) + e;
        const float* ap = reg ? a2 : a1;
        float ar = ap[(o * 64 + i) * 2 + 0];
        float ai = ap[(o * 64 + i) * 2 + 1];
        float v = (pl == 0) ? ar : ((pl == 1) ? ai : -ai);
        AFa[id] = f2bf(v);
    }
}

// g[r][j][x][y] = sum_k cc[j,x,k] * dc[k,y]
__global__ __launch_bounds__(256) void k_g(const float* __restrict__ c1, const float* __restrict__ d1,
                                           const float* __restrict__ c2, const float* __restrict__ d2,
                                           float2* __restrict__ G) {
    int idx = blockIdx.x * 256 + threadIdx.x;      // < 262144
    int r = idx >> 17;
    int rem = idx & 131071;
    int j = rem >> 12;
    int xy = rem & 4095;
    int xm = xy >> 6, ym = xy & 63;
    const float* cp = r ? c2 : c1;
    const float* dp = r ? d2 : d1;
    float sr = 0.f, si = 0.f;
    for (int kk = 0; kk < 32; ++kk) {
        float cr = cp[((j * 64 + xm) * 32 + kk) * 2 + 0];
        float ci = cp[((j * 64 + xm) * 32 + kk) * 2 + 1];
        float dr = dp[(kk * 64 + ym) * 2 + 0];
        float di = dp[(kk * 64 + ym) * 2 + 1];
        sr = fmaf(cr, dr, fmaf(-ci, di, sr));
        si = fmaf(cr, di, fmaf( ci, dr, si));
    }
    G[(size_t)(r * 32 + j) * 4096 + xy] = make_float2(sr, si);
}

// bf16 fragment tables for the contraction (reads G).
__global__ __launch_bounds__(256) void k_prepBG(const float* __restrict__ b1, const float* __restrict__ b2,
                                                const float2* __restrict__ G,
                                                unsigned short* __restrict__ bA,
                                                unsigned short* __restrict__ gB) {
    size_t idx = (size_t)blockIdx.x * 256 + threadIdx.x;
    if (idx < 1048576) {
        int e     = idx & 7;
        int lane  = (idx >> 3) & 63;
        int c     = (idx >> 9) & 127;
        int itile = (idx >> 16) & 3;
        int reg   = (idx >> 18) & 1;
        int plane = (idx >> 19) & 1;
        int i = itile * 16 + (lane & 15);
        int j = 8 * (lane >> 4) + e;
        const float* bp = reg ? b2 : b1;
        float v = bp[((size_t)(i * 128 + c) * 32 + j) * 2 + plane];
        bA[idx] = f2bf(v);
    } else if (idx < 1048576 + 786432) {
        size_t i2 = idx - 1048576;
        int e     = i2 & 7;
        int lane  = (i2 >> 3) & 63;
        int ytile = (i2 >> 9) & 3;
        int x     = (i2 >> 11) & 63;
        int reg   = (i2 >> 17) & 1;
        int plane = (int)(i2 >> 18);           // 0,1,2
        int y = ytile * 16 + (lane & 15);
        int j = 8 * (lane >> 4) + e;
        float2 gv = G[(size_t)(reg * 32 + j) * 4096 + x * 64 + y];
        float v = (plane == 0) ? gv.x : ((plane == 1) ? gv.y : -gv.y);
        gB[i2] = f2bf(v);
    }
}

// MFMA W-DFT v6: BF (2 planes) staged via LDS in 16KB barrier-synced phases (2 kc each).
// Yt output = 2 bf16-HI planes (re, im). 2 MFMAs per (nt,rt).
__global__ __launch_bounds__(256) void k_stage1m(const float* __restrict__ x,
                                                 const unsigned short* __restrict__ BF,
                                                 unsigned short* __restrict__ Yt) {
    __shared__ __align__(16) unsigned short es[8192];   // 16 KB
    int t = threadIdx.x;
    int wave = t >> 6, lane = t & 63;
    size_t row0 = (size_t)blockIdx.x * 128 + (size_t)wave * 32;
    int colp = lane & 15, rowq = lane >> 4;
    const short8v* esv = (const short8v*)es;

    float4v accR[2][4], accI[2][4];
#pragma unroll
    for (int rt = 0; rt < 2; ++rt)
#pragma unroll
        for (int nt = 0; nt < 4; ++nt) {
            accR[rt][nt] = (float4v){0.f, 0.f, 0.f, 0.f};
            accI[rt][nt] = (float4v){0.f, 0.f, 0.f, 0.f};
        }

    const float* xb0 = x + (row0 + colp) * 256 + 8 * rowq;
    const float* xb1 = xb0 + 16 * 256;
    float4 nv[2][2];
    nv[0][0] = *(const float4*)(xb0);  nv[0][1] = *(const float4*)(xb0 + 4);
    nv[1][0] = *(const float4*)(xb1);  nv[1][1] = *(const float4*)(xb1 + 4);

    const float4* bf4 = (const float4*)BF;
    for (int ph = 0; ph < 4; ++ph) {
        __syncthreads();
        {   // stage 2 planes x 2 kcl x 4 nt x 64 lanes = 1024 float4 = 16 KB
#pragma unroll
            for (int i = 0; i < 4; ++i) {
                int idx = t + 256 * i;
                int li  = idx & 63;
                int nt  = (idx >> 6) & 3;
                int kcl = (idx >> 8) & 1;
                int pl  = idx >> 9;            // 0..1
                ((float4*)es)[idx] = bf4[((size_t)(pl * 8 + ph * 2 + kcl) * 4 + nt) * 64 + li];
            }
        }
        __syncthreads();
        for (int kcl = 0; kcl < 2; ++kcl) {
            int kc = ph * 2 + kcl;
            short8v xh[2];
#pragma unroll
            for (int rt = 0; rt < 2; ++rt) {
                float4 v0 = nv[rt][0], v1 = nv[rt][1];
                float vv[8] = {v0.x, v0.y, v0.z, v0.w, v1.x, v1.y, v1.z, v1.w};
#pragma unroll
                for (int j = 0; j < 8; ++j) xh[rt][j] = (short)f2bf(vv[j]);
            }
            if (kc < 7) {
                nv[0][0] = *(const float4*)(xb0 + (kc + 1) * 32);
                nv[0][1] = *(const float4*)(xb0 + (kc + 1) * 32 + 4);
                nv[1][0] = *(const float4*)(xb1 + (kc + 1) * 32);
                nv[1][1] = *(const float4*)(xb1 + (kc + 1) * 32 + 4);
            }
#pragma unroll
            for (int nt = 0; nt < 4; ++nt) {
                short8v Bch = esv[((0 * 2 + kcl) * 4 + nt) * 64 + lane];
                short8v Bsh = esv[((1 * 2 + kcl) * 4 + nt) * 64 + lane];
#pragma unroll
                for (int rt = 0; rt < 2; ++rt) {
                    accR[rt][nt] = __builtin_amdgcn_mfma_f32_16x16x32_bf16(xh[rt], Bch, accR[rt][nt], 0, 0, 0);
                    accI[rt][nt] = __builtin_amdgcn_mfma_f32_16x16x32_bf16(xh[rt], Bsh, accI[rt][nt], 0, 0, 0);
                }
            }
        }
    }

    short* Yts = (short*)Yt;
    const size_t PLY = (size_t)32 * 32768 * 8;
#pragma unroll
    for (int rt = 0; rt < 2; ++rt) {
        size_t xrow0 = row0 + rt * 16 + rowq * 4;
        int h = (int)(xrow0 & 255), bc = (int)(xrow0 >> 8);
        size_t gbase = (size_t)(h >> 3) * 32768;
        int e0 = h & 7;
#pragma unroll
        for (int nt = 0; nt < 4; ++nt) {
            size_t p = (size_t)bc * 64 + nt * 16 + colp;
            size_t off = (gbase + p) * 8 + e0;
            float4v R = accR[rt][nt], I = accI[rt][nt];
            short rh[4], ih[4];
#pragma unroll
            for (int q = 0; q < 4; ++q) {
                rh[q] = (short)f2bf(R[q]);
                ih[q] = (short)f2bf(I[q]);
            }
            *(short4*)&Yts[0 * PLY + off] = make_short4(rh[0], rh[1], rh[2], rh[3]);
            *(short4*)&Yts[1 * PLY + off] = make_short4(ih[0], ih[1], ih[2], ih[3]);
        }
    }
}

// bf16-hi complex MFMA GEMM (FH hi-A x Yt hi-B -> XFh packed bf16-hi u32).
// A planes: 0=cos, 1=sin, 2=-sin.  4 MFMAs per (kc,rt).
template<int S, int RT_W>
__global__ __launch_bounds__(256) void k_cmfma(const unsigned short* __restrict__ AF,
                                               const unsigned short* __restrict__ Bt,
                                               unsigned int* __restrict__ XFh) {
    constexpr int KC = S / 32;
    constexpr int SG = S / 8;
    constexpr int RTOT = RT_W * 4;
    __shared__ __align__(16) unsigned short bs[2 * SG * 16 * 8];   // 16 KB (S=256)
    int t = threadIdx.x;
    int wave = t >> 6, lane = t & 63;
    int rt0 = wave * RT_W;
    int colp = lane & 15, rowq = lane >> 4;
    const short8v* AFv = (const short8v*)AF;
    const short8v* bsv = (const short8v*)bs;
    const size_t PLA = (size_t)KC * RTOT * 64;

    for (int pt = 0; pt < 4; ++pt) {
        int p0 = blockIdx.x * 64 + pt * 16;
        __syncthreads();
        {
            const float4* src = (const float4*)Bt;
            float4* dst = (float4*)bs;
            for (int e = t; e < 2 * SG * 16; e += 256) {
                int pl = e / (SG * 16); int rem = e - pl * (SG * 16);
                int g = rem >> 4, li = rem & 15;
                dst[e] = src[((size_t)pl * SG + g) * 32768 + p0 + li];
            }
        }
        __syncthreads();
        float4v accR[RT_W], accI[RT_W];
#pragma unroll
        for (int rt = 0; rt < RT_W; ++rt) {
            accR[rt] = (float4v){0.f, 0.f, 0.f, 0.f};
            accI[rt] = (float4v){0.f, 0.f, 0.f, 0.f};
        }
#pragma unroll
        for (int kc = 0; kc < KC; ++kc) {
            int gi = kc * 4 + rowq;
            short8v Brh = bsv[((0 * SG + gi) << 4) + colp];
            short8v Bih = bsv[((1 * SG + gi) << 4) + colp];
#pragma unroll
            for (int rt = 0; rt < RT_W; ++rt) {
                size_t ab = ((size_t)kc * RTOT + rt0 + rt) * 64 + lane;
                short8v Ac  = AFv[0 * PLA + ab];   // cos
                short8v As  = AFv[1 * PLA + ab];   // sin
                short8v Ans = AFv[2 * PLA + ab];   // -sin
                float4v r_ = accR[rt];
                r_ = __builtin_amdgcn_mfma_f32_16x16x32_bf16(Ac,  Brh, r_, 0, 0, 0);
                r_ = __builtin_amdgcn_mfma_f32_16x16x32_bf16(Ans, Bih, r_, 0, 0, 0);
                accR[rt] = r_;
                float4v i_ = accI[rt];
                i_ = __builtin_amdgcn_mfma_f32_16x16x32_bf16(As, Brh, i_, 0, 0, 0);
                i_ = __builtin_amdgcn_mfma_f32_16x16x32_bf16(Ac, Bih, i_, 0, 0, 0);
                accI[rt] = i_;
            }
        }
#pragma unroll
        for (int rt = 0; rt < RT_W; ++rt) {
            int rbase = (rt0 + rt) * 16 + rowq * 4;
#pragma unroll
            for (int q = 0; q < 4; ++q) {
                unsigned int pw = (unsigned int)f2bf(accR[rt][q])
                                | ((unsigned int)f2bf(accI[rt][q]) << 16);
                XFh[(size_t)(rbase + q) * P_ + p0 + colp] = pw;
            }
        }
    }
}

// MFMA contract, phase A -> tA bf16-HI only (2 planes).
// Packed XFh tile (4 b x 128 c x 16 y u32 = 32 KB) staged in LDS.
__global__ __launch_bounds__(256) void k_contractA(const unsigned int* __restrict__ XFh,
                                                   const unsigned short* __restrict__ bA,
                                                   const unsigned short* __restrict__ gB,
                                                   unsigned short* __restrict__ tA) {
    __shared__ __align__(16) unsigned int xfs[4][128][16];   // 32 KB
    int t = threadIdx.x;
    int k = blockIdx.x >> 2;
    int ytile = blockIdx.x & 3;
    int y0 = ytile << 4;
    int reg = (k >= 64) ? 1 : 0;
    int x = k & 63;
    int itile = t >> 6, lane = t & 63;
    int ylane = lane & 15, qg = lane >> 4;

    {   // stage XFh tile: 2048 uint4, 8 per thread
        const uint4* src = (const uint4*)XFh;
        uint4* dst = (uint4*)xfs;
        size_t kbase = ((size_t)k * 32768 + y0) >> 2;   // uint4 units
#pragma unroll
        for (int i = 0; i < 8; ++i) {
            int e = t + 256 * i;
            int f4w = e & 3;          // which uint4 within the 16-u32 row
            int bc  = e >> 2;         // b*128 + c
            int b   = bc >> 7, c = bc & 127;
            dst[e] = src[kbase + (size_t)b * 2048 + (size_t)c * 16 + f4w];
        }
    }

    const short8v* gBv = (const short8v*)gB;
    short8v g_r  = gBv[(((size_t)(0 * 2 + reg) * 64 + x) * 4 + ytile) * 64 + lane];
    short8v g_i  = gBv[(((size_t)(1 * 2 + reg) * 64 + x) * 4 + ytile) * 64 + lane];
    short8v g_ni = gBv[(((size_t)(2 * 2 + reg) * 64 + x) * 4 + ytile) * 64 + lane];

    const short8v* bAv = (const short8v*)bA;
    size_t aR = (((size_t)(0 * 2 + reg) * 4 + itile) * 128) * 64 + lane;
    size_t aI = (((size_t)(1 * 2 + reg) * 4 + itile) * 128) * 64 + lane;

    float tr[4][4], ti[4][4];
#pragma unroll
    for (int q = 0; q < 4; ++q)
#pragma unroll
        for (int b = 0; b < 4; ++b) { tr[q][b] = 0.f; ti[q][b] = 0.f; }

    __syncthreads();     // XFh tile ready

#pragma unroll 2
    for (int c = 0; c < 128; ++c) {
        short8v av = bAv[aR + (size_t)c * 64];
        short8v aw = bAv[aI + (size_t)c * 64];
        float4v z4 = {0.f, 0.f, 0.f, 0.f};
        float4v wr = __builtin_amdgcn_mfma_f32_16x16x32_bf16(av, g_r, z4, 0, 0, 0);
        wr = __builtin_amdgcn_mfma_f32_16x16x32_bf16(aw, g_ni, wr, 0, 0, 0);
        float4v wi = __builtin_amdgcn_mfma_f32_16x16x32_bf16(av, g_i, z4, 0, 0, 0);
        wi = __builtin_amdgcn_mfma_f32_16x16x32_bf16(aw, g_r, wi, 0, 0, 0);
#pragma unroll
        for (int b = 0; b < 4; ++b) {
            unsigned int xw = xfs[b][c][ylane];
            float xr = bf2f((unsigned short)(xw & 0xFFFFu));
            float xi = bf2f((unsigned short)(xw >> 16));
#pragma unroll
            for (int q = 0; q < 4; ++q) {
                tr[q][b] = fmaf(wr[q], xr, fmaf(-wi[q], xi, tr[q][b]));
                ti[q][b] = fmaf(wr[q], xi, fmaf( wi[q], xr, ti[q][b]));
            }
        }
    }

    short* tAs = (short*)tA;
    const size_t PLT = (size_t)8 * 32768 * 8;     // plane stride (shorts)
    int gidx = itile * 2 + (qg >> 1);
    int e0 = (qg & 1) * 4;
#pragma unroll
    for (int b = 0; b < 4; ++b) {
        size_t col = (size_t)k * 256 + (size_t)b * 64 + y0 + ylane;
        size_t off = ((size_t)gidx * 32768 + col) * 8 + e0;
        short rh[4], ih[4];
#pragma unroll
        for (int q = 0; q < 4; ++q) {
            rh[q] = (short)f2bf(tr[q][b]);
            ih[q] = (short)f2bf(ti[q][b]);
        }
        *(short4*)&tAs[0 * PLT + off] = make_short4(rh[0], rh[1], rh[2], rh[3]);
        *(short4*)&tAs[1 * PLT + off] = make_short4(ih[0], ih[1], ih[2], ih[3]);
    }
}

// MFMA contract, phase B -> OFh packed bf16-hi u32.
// AFa planes: 0=ar, 1=ai, 2=-ai.  4 MFMAs per (kc,rt).
__global__ __launch_bounds__(256) void k_amfma(const unsigned short* __restrict__ AFa,
                                               const unsigned short* __restrict__ tA,
                                               unsigned int* __restrict__ OFh) {
    constexpr int SG = 8;
    __shared__ __align__(16) unsigned short bs[2 * SG * 16 * 8];   // 4 KB
    int t = threadIdx.x;
    int wave = t >> 6, lane = t & 63;
    int rt0 = wave * 2;
    int colp = lane & 15, rowq = lane >> 4;
    int k = blockIdx.x >> 2, b = blockIdx.x & 3;
    int reg = (k >= 64) ? 1 : 0;
    const short8v* AFv = (const short8v*)(AFa + (size_t)reg * 3 * 2 * 8 * 512);
    const size_t PLA = 2 * 8 * 64;
    const short8v* bsv = (const short8v*)bs;
    size_t p0 = (size_t)blockIdx.x * 64;

    for (int pt = 0; pt < 4; ++pt) {
        __syncthreads();
        {
            const float4* src = (const float4*)tA;
            float4* dst = (float4*)bs;
            int e = t;
            int pl = e >> 7; int rem = e & 127;
            int g = rem >> 4, li = rem & 15;
            dst[e] = src[((size_t)pl * SG + g) * 32768 + p0 + pt * 16 + li];
        }
        __syncthreads();
        float4v accR[2], accI[2];
#pragma unroll
        for (int rt = 0; rt < 2; ++rt) {
            accR[rt] = (float4v){0.f, 0.f, 0.f, 0.f};
            accI[rt] = (float4v){0.f, 0.f, 0.f, 0.f};
        }
#pragma unroll
        for (int kc = 0; kc < 2; ++kc) {
            int gi = kc * 4 + rowq;
            short8v Brh = bsv[((0 * SG + gi) << 4) + colp];
            short8v Bih = bsv[((1 * SG + gi) << 4) + colp];
#pragma unroll
            for (int rt = 0; rt < 2; ++rt) {
                size_t ab = ((size_t)kc * 8 + rt0 + rt) * 64 + lane;
                short8v Ar  = AFv[0 * PLA + ab];
                short8v Ai  = AFv[1 * PLA + ab];
                short8v Ani = AFv[2 * PLA + ab];
                float4v r_ = accR[rt];
                r_ = __builtin_amdgcn_mfma_f32_16x16x32_bf16(Ar,  Brh, r_, 0, 0, 0);
                r_ = __builtin_amdgcn_mfma_f32_16x16x32_bf16(Ani, Bih, r_, 0, 0, 0);
                accR[rt] = r_;
                float4v i_ = accI[rt];
                i_ = __builtin_amdgcn_mfma_f32_16x16x32_bf16(Ai, Brh, i_, 0, 0, 0);
                i_ = __builtin_amdgcn_mfma_f32_16x16x32_bf16(Ar, Bih, i_, 0, 0, 0);
                accI[rt] = i_;
            }
        }
        int m = pt * 16 + colp;
#pragma unroll
        for (int rt = 0; rt < 2; ++rt) {
            int o0 = (rt0 + rt) * 16 + rowq * 4;
#pragma unroll
            for (int q = 0; q < 4; ++q) {
                unsigned int pw = (unsigned int)f2bf(accR[rt][q])
                                | ((unsigned int)f2bf(accI[rt][q]) << 16);
                OFh[(size_t)k * 32768 + (size_t)b * 8192 + (size_t)(o0 + q) * 64 + m] = pw;
            }
        }
    }
}

// FUSED IH-GEMM + inverse-W MFMA. Block = one bo (b*128+o), 512 threads (8 waves).
// Phase 1: IH hi-A (3 planes) x OFh hi-B: 4 MFMAs per (kc,rt).
__global__ __launch_bounds__(512) void k_ihinv(const unsigned short* __restrict__ AF2,
                                               const unsigned int* __restrict__ OFh,
                                               const unsigned short* __restrict__ EF,
                                               float* __restrict__ out) {
    constexpr int SG = 16, KC = 4, RTOT = 16;
    __shared__ __align__(16) unsigned short zs[2 * 256 * 64];     // 64 KB
    __shared__ __align__(16) unsigned short bs[2 * SG * 16 * 8];  // 8 KB
    int t = threadIdx.x;
    int wave = t >> 6, lane = t & 63;
    int colp = lane & 15, rowq = lane >> 4;
    int rt0 = wave * 2;
    int bo = blockIdx.x;
    size_t p0 = (size_t)bo * 64;
    const short8v* AFv = (const short8v*)AF2;
    const short8v* bsv = (const short8v*)bs;
    const size_t PLA = (size_t)KC * RTOT * 64;

    for (int pt = 0; pt < 4; ++pt) {
        __syncthreads();
        {   // stage B tile from OFh (packed): 512 threads x 4 rows each
            int li = t & 15, g = (t >> 4) & 15, half = t >> 8;
            int e0 = half * 4;
            short rh[4], ih[4];
#pragma unroll
            for (int j = 0; j < 4; ++j) {
                unsigned int w = OFh[(size_t)(g * 8 + e0 + j) * P_ + p0 + pt * 16 + li];
                rh[j] = (short)(w & 0xFFFFu);
                ih[j] = (short)(w >> 16);
            }
            int base = (g * 16 + li) * 8 + e0;
            *(short4*)&bs[0 * 2048 + base] = make_short4(rh[0], rh[1], rh[2], rh[3]);
            *(short4*)&bs[1 * 2048 + base] = make_short4(ih[0], ih[1], ih[2], ih[3]);
        }
        __syncthreads();
        float4v accR[2], accI[2];
#pragma unroll
        for (int rt = 0; rt < 2; ++rt) {
            accR[rt] = (float4v){0.f, 0.f, 0.f, 0.f};
            accI[rt] = (float4v){0.f, 0.f, 0.f, 0.f};
        }
#pragma unroll
        for (int kc = 0; kc < KC; ++kc) {
            int gi = kc * 4 + rowq;
            short8v Brh = bsv[((0 * SG + gi) << 4) + colp];
            short8v Bih = bsv[((1 * SG + gi) << 4) + colp];
#pragma unroll
            for (int rt = 0; rt < 2; ++rt) {
                size_t ab = ((size_t)kc * RTOT + rt0 + rt) * 64 + lane;
                short8v Ac  = AFv[0 * PLA + ab];
                short8v As  = AFv[1 * PLA + ab];
                short8v Ans = AFv[2 * PLA + ab];
                float4v r_ = accR[rt];
                r_ = __builtin_amdgcn_mfma_f32_16x16x32_bf16(Ac,  Brh, r_, 0, 0, 0);
                r_ = __builtin_amdgcn_mfma_f32_16x16x32_bf16(Ans, Bih, r_, 0, 0, 0);
                accR[rt] = r_;
                float4v i_ = accI[rt];
                i_ = __builtin_amdgcn_mfma_f32_16x16x32_bf16(As, Brh, i_, 0, 0, 0);
                i_ = __builtin_amdgcn_mfma_f32_16x16x32_bf16(Ac, Bih, i_, 0, 0, 0);
                accI[rt] = i_;
            }
        }
#pragma unroll
        for (int rt = 0; rt < 2; ++rt)
#pragma unroll
            for (int q = 0; q < 4; ++q) {
                int h = (rt0 + rt) * 16 + rowq * 4 + q;
                int kwsw = (pt * 16 + colp) ^ ((h & 7) << 3);
                zs[h * 64 + kwsw] = (unsigned short)f2bf(accR[rt][q]);
                zs[16384 + h * 64 + kwsw] = (unsigned short)f2bf(accI[rt][q]);
            }
    }
    __syncthreads();

    const short8v* EFv = (const short8v*)EF;
    for (int nt = 0; nt < 16; ++nt) {
        short8v Er0  = EFv[((0 * 2 + 0) * 16 + nt) * 64 + lane];
        short8v Er1  = EFv[((0 * 2 + 1) * 16 + nt) * 64 + lane];
        short8v nEi0 = EFv[((1 * 2 + 0) * 16 + nt) * 64 + lane];
        short8v nEi1 = EFv[((1 * 2 + 1) * 16 + nt) * 64 + lane];
#pragma unroll
        for (int mtl = 0; mtl < 2; ++mtl) {
            int h0 = (wave * 2 + mtl) * 16;
            int hA = h0 + colp;
            int sw = (hA & 7) << 3;
            short8v Zr0 = *(const short8v*)&zs[hA * 64 + ((8 * rowq) ^ sw)];
            short8v Zr1 = *(const short8v*)&zs[hA * 64 + ((32 + 8 * rowq) ^ sw)];
            short8v Zi0 = *(const short8v*)&zs[16384 + hA * 64 + ((8 * rowq) ^ sw)];
            short8v Zi1 = *(const short8v*)&zs[16384 + hA * 64 + ((32 + 8 * rowq) ^ sw)];
            float4v acc = {0.f, 0.f, 0.f, 0.f};
            acc = __builtin_amdgcn_mfma_f32_16x16x32_bf16(Zr0, Er0,  acc, 0, 0, 0);
            acc = __builtin_amdgcn_mfma_f32_16x16x32_bf16(Zi0, nEi0, acc, 0, 0, 0);
            acc = __builtin_amdgcn_mfma_f32_16x16x32_bf16(Zr1, Er1,  acc, 0, 0, 0);
            acc = __builtin_amdgcn_mfma_f32_16x16x32_bf16(Zi1, nEi1, acc, 0, 0, 0);
            size_t ob = ((size_t)bo * 256 + h0 + rowq * 4) * 256 + nt * 16 + colp;
#pragma unroll
            for (int q = 0; q < 4; ++q)
                out[ob + (size_t)q * 256] = acc[q];
        }
    }
}

extern "C" void kernel_launch(void* const* d_in, const int* in_sizes, int n_in,
                              void* d_out, int out_size, void* d_ws, size_t ws_size,
                              hipStream_t stream) {
    const float* x  = (const float*)d_in[0];
    const float* a1 = (const float*)d_in[1];
    const float* b1 = (const float*)d_in[2];
    const float* c1 = (const float*)d_in[3];
    const float* d1 = (const float*)d_in[4];
    const float* a2 = (const float*)d_in[5];
    const float* b2 = (const float*)d_in[6];
    const float* c2 = (const float*)d_in[7];
    const float* d2 = (const float*)d_in[8];
    float* out = (float*)d_out;
    float* wsf = (float*)d_ws;

    if (ws_size < WS_FLOATS * sizeof(float)) return;

    unsigned short* Yt  = (unsigned short*)(wsf + oYT);
    unsigned int*   XFh = (unsigned int*)(wsf + oXF);
    unsigned int*   OFh = (unsigned int*)(wsf + oOF);
    float2*         G   = (float2*)(wsf + oOF);          // G lives in OF region until prepBG
    unsigned short* BF  = (unsigned short*)(wsf + oBF);
    unsigned short* AF1 = (unsigned short*)(wsf + oAF1);
    unsigned short* AF2 = (unsigned short*)(wsf + oAF2);
    unsigned short* bA  = (unsigned short*)(wsf + oYT);  // after cmfma1, Yt region is dead
    unsigned short* gB  = bA + 1048576;
    unsigned short* tA  = (unsigned short*)(wsf + oTA);
    unsigned short* AFa = (unsigned short*)(wsf + oG);
    unsigned short* EF  = (unsigned short*)(wsf + oEF);

    k_prepTables<<<1216, 256, 0, stream>>>(a1, a2, AF1, AF2, BF, EF, AFa);
    k_g<<<1024, 256, 0, stream>>>(c1, d1, c2, d2, G);
    k_stage1m<<<1024, 256, 0, stream>>>(x, BF, Yt);
    k_cmfma<256, 2><<<512, 256, 0, stream>>>(AF1, Yt, XFh);
    k_prepBG<<<7168, 256, 0, stream>>>(b1, b2, G, bA, gB);
    k_contractA<<<512, 256, 0, stream>>>(XFh, bA, gB, tA);
    k_amfma<<<512, 256, 0, stream>>>(AFa, tA, OFh);      // overwrites G (dead after prepBG)
    k_ihinv<<<512, 512, 0, stream>>>(AF2, OFh, EF, out);

    (void)in_sizes; (void)n_in; (void)out_size;
}

// Round 23
// 177.557 us; speedup vs baseline: 1.3667x; 1.0288x over previous
//
#include <hip/hip_runtime.h>
#include <math.h>

// FactorizedSpectralConv2d: pruned-DFT + TT contraction, MFMA everywhere matmul-shaped.
// ALL operands bf16-hi (fp32 MFMA accumulation); contract phase A+B fused (t via LDS).
//
//   k_prepTables: bf16-hi A-frag tables FH/IH (3 planes) + FW B-frags (2 planes) +
//                 invW E B-frags + a A-frags (3 planes)
//   k_g         : g[r][j][x][y] = sum_k cc[j,x,k]*dc[k,y]  (G in then-dead OF region)
//   k_prepBG    : bf16 frag tables for b (A) and g (B) from G
//   k_stage1m   : W-DFT of x via MFMA -> Yt 2 bf16-HI planes (16KB LDS twiddle phases)
//   k_cmfma     : XFh[k][p] = sum_h FH[k][h] Yt[h][p], packed bf16-hi u32
//   k_contract2 : FUSED w-GEMM + fp32 t-update + a-epilogue MFMA (t via LDS) -> OFh
//   k_ihinv     : FUSED per-bo block: phase1 Z = IH·OFh; phase2 out = Re(Z . E)

#define TWO_PI 6.28318530717958647692f

typedef __attribute__((ext_vector_type(8))) short short8v;   // 8 bf16 (4 VGPRs)
typedef __attribute__((ext_vector_type(4))) float float4v;   // MFMA C/D

namespace {
constexpr size_t P_ = 32768;            // B*C*KW pixel batch width

// workspace float offsets
constexpr size_t oYT = 0;                     // Yt: 2 bf16-hi planes [32][32768][8]
                                              //   then bA/gB (contract)
constexpr size_t oXF = 16777216;              // XFh u32 16.7MB (packed bf16-hi re|im)
constexpr size_t oOF = 25165824;              // G f2 (2MB, until prepBG) then OFh u32 16.7MB
constexpr size_t oBF = 33554432;              // FW B-frag table: 32768 shorts (2 planes)
constexpr size_t oAF1 = 33587200;             // FH frags: 98304 shorts (3 planes)
constexpr size_t oAF2 = 33685504;             // IH frags: 98304 shorts (3 planes)
constexpr size_t oG  = 33792000;              // AFa (49152 shorts) then EF (32768 shorts)
constexpr size_t oEF = oG + 262144;
constexpr size_t WS_FLOATS = oG + 524288;     // ~137.3 MB
}

__device__ __forceinline__ unsigned short f2bf(float f) {   // RNE float->bf16 bits
    unsigned int u = __float_as_uint(f);
    unsigned int r = (u + 0x7FFFu + ((u >> 16) & 1u)) >> 16;
    return (unsigned short)r;
}
__device__ __forceinline__ float bf2f(unsigned short b) {
    return __uint_as_float(((unsigned int)b) << 16);
}

// All static fragment tables in one launch (same layout as round 21).
__global__ __launch_bounds__(256) void k_prepTables(const float* __restrict__ a1,
                                                    const float* __restrict__ a2,
                                                    unsigned short* __restrict__ AF1,
                                                    unsigned short* __restrict__ AF2,
                                                    unsigned short* __restrict__ BF,
                                                    unsigned short* __restrict__ EF,
                                                    unsigned short* __restrict__ AFa) {
    int idx = blockIdx.x * 256 + threadIdx.x;      // < 311296
    if (idx < 196608) {
        int tbl = (idx >= 98304);
        int id = tbl ? (idx - 98304) : idx;        // < 98304
        int e = id & 7, lane = (id >> 3) & 63;
        int pl = id >> 15;                          // 0..2
        float ang;
        if (!tbl) {
            int rt = (id >> 9) & 7, kc = (id >> 12) & 7;
            int r = rt * 16 + (lane & 15);             // k-row (128)
            int s = kc * 32 + 8 * (lane >> 4) + e;     // h (256)
            int kh = r + ((r >= 64) ? 128 : 0);
            int ph = (kh * s) & 255;
            ang = -TWO_PI * (float)ph / 256.0f;
        } else {
            int rt = (id >> 9) & 15, kc = (id >> 13) & 3;
            int r = rt * 16 + (lane & 15);             // h (256)
            int s = kc * 32 + 8 * (lane >> 4) + e;     // k (128)
            int kh = s + ((s >= 64) ? 128 : 0);
            int ph = (kh * r) & 255;
            ang = TWO_PI * (float)ph / 256.0f;
        }
        float sn, cs; sincosf(ang, &sn, &cs);
        float v = (pl == 0) ? cs : ((pl == 1) ? sn : -sn);
        (tbl ? AF2 : AF1)[id] = f2bf(v);
    } else if (idx < 229376) {
        int id = idx - 196608;                          // < 32768
        int e = id & 7, lane = (id >> 3) & 63;
        int nt = (id >> 9) & 3, kc = (id >> 11) & 7;
        int pl = id >> 14;                              // 0..1
        int kw = nt * 16 + (lane & 15);
        int w = kc * 32 + 8 * (lane >> 4) + e;
        int ph = (w * kw) & 255;
        float ang = -TWO_PI * (float)ph / 256.0f;
        float sn, cs; sincosf(ang, &sn, &cs);
        BF[id] = f2bf((pl == 0) ? cs : sn);
    } else if (idx < 262144) {
        int id = idx - 229376;                          // < 32768
        int e = id & 7, lane = (id >> 3) & 63;
        int nt = (id >> 9) & 15, kc = (id >> 13) & 1, pl = id >> 14;
        int w = nt * 16 + (lane & 15);
        int kw = kc * 32 + 8 * (lane >> 4) + e;
        int ph = (kw * w) & 255;
        float ang = TWO_PI * (float)ph / 256.0f;
        float sn, cs; sincosf(ang, &sn, &cs);
        float sc = ((kw == 0) ? 1.0f : 2.0f) / 65536.0f;
        float v = (pl == 0) ? (sc * cs) : (-sc * sn);
        EF[id] = f2bf(v);
    } else {
        int id = idx - 262144;                          // < 49152
        int e = id & 7, lane = (id >> 3) & 63;
        int rt = (id >> 9) & 7, kc = (id >> 12) & 1;
        int plreg = id >> 13;                           // 0..5
        int reg = plreg / 3, pl = plreg % 3;
        int o = rt * 16 + (lane & 15);
        int i = kc * 32 + 8 * (lane >> 4) + e;
        const float* ap = reg ? a2 : a1;
        float ar = ap[(o * 64 + i) * 2 + 0];
        float ai = ap[(o * 64 + i) * 2 + 1];
        float v = (pl == 0) ? ar : ((pl == 1) ? ai : -ai);
        AFa[id] = f2bf(v);
    }
}

// g[r][j][x][y] = sum_k cc[j,x,k] * dc[k,y]
__global__ __launch_bounds__(256) void k_g(const float* __restrict__ c1, const float* __restrict__ d1,
                                           const float* __restrict__ c2, const float* __restrict__ d2,
                                           float2* __restrict__ G) {
    int idx = blockIdx.x * 256 + threadIdx.x;      // < 262144
    int r = idx >> 17;
    int rem = idx & 131071;
    int j = rem >> 12;
    int xy = rem & 4095;
    int xm = xy >> 6, ym = xy & 63;
    const float* cp = r ? c2 : c1;
    const float* dp = r ? d2 : d1;
    float sr = 0.f, si = 0.f;
    for (int kk = 0; kk < 32; ++kk) {
        float cr = cp[((j * 64 + xm) * 32 + kk) * 2 + 0];
        float ci = cp[((j * 64 + xm) * 32 + kk) * 2 + 1];
        float dr = dp[(kk * 64 + ym) * 2 + 0];
        float di = dp[(kk * 64 + ym) * 2 + 1];
        sr = fmaf(cr, dr, fmaf(-ci, di, sr));
        si = fmaf(cr, di, fmaf( ci, dr, si));
    }
    G[(size_t)(r * 32 + j) * 4096 + xy] = make_float2(sr, si);
}

// bf16 fragment tables for the contraction (reads G).
__global__ __launch_bounds__(256) void k_prepBG(const float* __restrict__ b1, const float* __restrict__ b2,
                                                const float2* __restrict__ G,
                                                unsigned short* __restrict__ bA,
                                                unsigned short* __restrict__ gB) {
    size_t idx = (size_t)blockIdx.x * 256 + threadIdx.x;
    if (idx < 1048576) {
        int e     = idx & 7;
        int lane  = (idx >> 3) & 63;
        int c     = (idx >> 9) & 127;
        int itile = (idx >> 16) & 3;
        int reg   = (idx >> 18) & 1;
        int plane = (idx >> 19) & 1;
        int i = itile * 16 + (lane & 15);
        int j = 8 * (lane >> 4) + e;
        const float* bp = reg ? b2 : b1;
        float v = bp[((size_t)(i * 128 + c) * 32 + j) * 2 + plane];
        bA[idx] = f2bf(v);
    } else if (idx < 1048576 + 786432) {
        size_t i2 = idx - 1048576;
        int e     = i2 & 7;
        int lane  = (i2 >> 3) & 63;
        int ytile = (i2 >> 9) & 3;
        int x     = (i2 >> 11) & 63;
        int reg   = (i2 >> 17) & 1;
        int plane = (int)(i2 >> 18);           // 0,1,2
        int y = ytile * 16 + (lane & 15);
        int j = 8 * (lane >> 4) + e;
        float2 gv = G[(size_t)(reg * 32 + j) * 4096 + x * 64 + y];
        float v = (plane == 0) ? gv.x : ((plane == 1) ? gv.y : -gv.y);
        gB[i2] = f2bf(v);
    }
}

// MFMA W-DFT v6: BF (2 planes) staged via LDS in 16KB barrier-synced phases.
__global__ __launch_bounds__(256) void k_stage1m(const float* __restrict__ x,
                                                 const unsigned short* __restrict__ BF,
                                                 unsigned short* __restrict__ Yt) {
    __shared__ __align__(16) unsigned short es[8192];   // 16 KB
    int t = threadIdx.x;
    int wave = t >> 6, lane = t & 63;
    size_t row0 = (size_t)blockIdx.x * 128 + (size_t)wave * 32;
    int colp = lane & 15, rowq = lane >> 4;
    const short8v* esv = (const short8v*)es;

    float4v accR[2][4], accI[2][4];
#pragma unroll
    for (int rt = 0; rt < 2; ++rt)
#pragma unroll
        for (int nt = 0; nt < 4; ++nt) {
            accR[rt][nt] = (float4v){0.f, 0.f, 0.f, 0.f};
            accI[rt][nt] = (float4v){0.f, 0.f, 0.f, 0.f};
        }

    const float* xb0 = x + (row0 + colp) * 256 + 8 * rowq;
    const float* xb1 = xb0 + 16 * 256;
    float4 nv[2][2];
    nv[0][0] = *(const float4*)(xb0);  nv[0][1] = *(const float4*)(xb0 + 4);
    nv[1][0] = *(const float4*)(xb1);  nv[1][1] = *(const float4*)(xb1 + 4);

    const float4* bf4 = (const float4*)BF;
    for (int ph = 0; ph < 4; ++ph) {
        __syncthreads();
        {
#pragma unroll
            for (int i = 0; i < 4; ++i) {
                int idx = t + 256 * i;
                int li  = idx & 63;
                int nt  = (idx >> 6) & 3;
                int kcl = (idx >> 8) & 1;
                int pl  = idx >> 9;            // 0..1
                ((float4*)es)[idx] = bf4[((size_t)(pl * 8 + ph * 2 + kcl) * 4 + nt) * 64 + li];
            }
        }
        __syncthreads();
        for (int kcl = 0; kcl < 2; ++kcl) {
            int kc = ph * 2 + kcl;
            short8v xh[2];
#pragma unroll
            for (int rt = 0; rt < 2; ++rt) {
                float4 v0 = nv[rt][0], v1 = nv[rt][1];
                float vv[8] = {v0.x, v0.y, v0.z, v0.w, v1.x, v1.y, v1.z, v1.w};
#pragma unroll
                for (int j = 0; j < 8; ++j) xh[rt][j] = (short)f2bf(vv[j]);
            }
            if (kc < 7) {
                nv[0][0] = *(const float4*)(xb0 + (kc + 1) * 32);
                nv[0][1] = *(const float4*)(xb0 + (kc + 1) * 32 + 4);
                nv[1][0] = *(const float4*)(xb1 + (kc + 1) * 32);
                nv[1][1] = *(const float4*)(xb1 + (kc + 1) * 32 + 4);
            }
#pragma unroll
            for (int nt = 0; nt < 4; ++nt) {
                short8v Bch = esv[((0 * 2 + kcl) * 4 + nt) * 64 + lane];
                short8v Bsh = esv[((1 * 2 + kcl) * 4 + nt) * 64 + lane];
#pragma unroll
                for (int rt = 0; rt < 2; ++rt) {
                    accR[rt][nt] = __builtin_amdgcn_mfma_f32_16x16x32_bf16(xh[rt], Bch, accR[rt][nt], 0, 0, 0);
                    accI[rt][nt] = __builtin_amdgcn_mfma_f32_16x16x32_bf16(xh[rt], Bsh, accI[rt][nt], 0, 0, 0);
                }
            }
        }
    }

    short* Yts = (short*)Yt;
    const size_t PLY = (size_t)32 * 32768 * 8;
#pragma unroll
    for (int rt = 0; rt < 2; ++rt) {
        size_t xrow0 = row0 + rt * 16 + rowq * 4;
        int h = (int)(xrow0 & 255), bc = (int)(xrow0 >> 8);
        size_t gbase = (size_t)(h >> 3) * 32768;
        int e0 = h & 7;
#pragma unroll
        for (int nt = 0; nt < 4; ++nt) {
            size_t p = (size_t)bc * 64 + nt * 16 + colp;
            size_t off = (gbase + p) * 8 + e0;
            float4v R = accR[rt][nt], I = accI[rt][nt];
            short rh[4], ih[4];
#pragma unroll
            for (int q = 0; q < 4; ++q) {
                rh[q] = (short)f2bf(R[q]);
                ih[q] = (short)f2bf(I[q]);
            }
            *(short4*)&Yts[0 * PLY + off] = make_short4(rh[0], rh[1], rh[2], rh[3]);
            *(short4*)&Yts[1 * PLY + off] = make_short4(ih[0], ih[1], ih[2], ih[3]);
        }
    }
}

// bf16-hi complex MFMA GEMM (FH hi-A x Yt hi-B -> XFh packed bf16-hi u32).
template<int S, int RT_W>
__global__ __launch_bounds__(256) void k_cmfma(const unsigned short* __restrict__ AF,
                                               const unsigned short* __restrict__ Bt,
                                               unsigned int* __restrict__ XFh) {
    constexpr int KC = S / 32;
    constexpr int SG = S / 8;
    constexpr int RTOT = RT_W * 4;
    __shared__ __align__(16) unsigned short bs[2 * SG * 16 * 8];   // 16 KB (S=256)
    int t = threadIdx.x;
    int wave = t >> 6, lane = t & 63;
    int rt0 = wave * RT_W;
    int colp = lane & 15, rowq = lane >> 4;
    const short8v* AFv = (const short8v*)AF;
    const short8v* bsv = (const short8v*)bs;
    const size_t PLA = (size_t)KC * RTOT * 64;

    for (int pt = 0; pt < 4; ++pt) {
        int p0 = blockIdx.x * 64 + pt * 16;
        __syncthreads();
        {
            const float4* src = (const float4*)Bt;
            float4* dst = (float4*)bs;
            for (int e = t; e < 2 * SG * 16; e += 256) {
                int pl = e / (SG * 16); int rem = e - pl * (SG * 16);
                int g = rem >> 4, li = rem & 15;
                dst[e] = src[((size_t)pl * SG + g) * 32768 + p0 + li];
            }
        }
        __syncthreads();
        float4v accR[RT_W], accI[RT_W];
#pragma unroll
        for (int rt = 0; rt < RT_W; ++rt) {
            accR[rt] = (float4v){0.f, 0.f, 0.f, 0.f};
            accI[rt] = (float4v){0.f, 0.f, 0.f, 0.f};
        }
#pragma unroll
        for (int kc = 0; kc < KC; ++kc) {
            int gi = kc * 4 + rowq;
            short8v Brh = bsv[((0 * SG + gi) << 4) + colp];
            short8v Bih = bsv[((1 * SG + gi) << 4) + colp];
#pragma unroll
            for (int rt = 0; rt < RT_W; ++rt) {
                size_t ab = ((size_t)kc * RTOT + rt0 + rt) * 64 + lane;
                short8v Ac  = AFv[0 * PLA + ab];   // cos
                short8v As  = AFv[1 * PLA + ab];   // sin
                short8v Ans = AFv[2 * PLA + ab];   // -sin
                float4v r_ = accR[rt];
                r_ = __builtin_amdgcn_mfma_f32_16x16x32_bf16(Ac,  Brh, r_, 0, 0, 0);
                r_ = __builtin_amdgcn_mfma_f32_16x16x32_bf16(Ans, Bih, r_, 0, 0, 0);
                accR[rt] = r_;
                float4v i_ = accI[rt];
                i_ = __builtin_amdgcn_mfma_f32_16x16x32_bf16(As, Brh, i_, 0, 0, 0);
                i_ = __builtin_amdgcn_mfma_f32_16x16x32_bf16(Ac, Bih, i_, 0, 0, 0);
                accI[rt] = i_;
            }
        }
#pragma unroll
        for (int rt = 0; rt < RT_W; ++rt) {
            int rbase = (rt0 + rt) * 16 + rowq * 4;
#pragma unroll
            for (int q = 0; q < 4; ++q) {
                unsigned int pw = (unsigned int)f2bf(accR[rt][q])
                                | ((unsigned int)f2bf(accI[rt][q]) << 16);
                XFh[(size_t)(rbase + q) * P_ + p0 + colp] = pw;
            }
        }
    }
}

// FUSED contract: w-GEMM + fp32 t-update + a-epilogue MFMA (t via LDS) -> OFh.
// Block = (k, ytile), 256 threads. ts LDS: [pl(2)][g(8)][n(66 pad)][e(8)] bf16.
__global__ __launch_bounds__(256) void k_contract2(const unsigned int* __restrict__ XFh,
                                                   const unsigned short* __restrict__ bA,
                                                   const unsigned short* __restrict__ gB,
                                                   const unsigned short* __restrict__ AFa,
                                                   unsigned int* __restrict__ OFh) {
    __shared__ __align__(16) unsigned int xfs[4][128][16];        // 32 KB
    __shared__ __align__(16) unsigned short ts[2 * 8 * 66 * 8];   // ~17 KB
    int t = threadIdx.x;
    int k = blockIdx.x >> 2;
    int ytile = blockIdx.x & 3;
    int y0 = ytile << 4;
    int reg = (k >= 64) ? 1 : 0;
    int x = k & 63;
    int itile = t >> 6, lane = t & 63;
    int ylane = lane & 15, qg = lane >> 4;

    {   // stage XFh tile: 2048 uint4, 8 per thread
        const uint4* src = (const uint4*)XFh;
        uint4* dst = (uint4*)xfs;
        size_t kbase = ((size_t)k * 32768 + y0) >> 2;   // uint4 units
#pragma unroll
        for (int i = 0; i < 8; ++i) {
            int e = t + 256 * i;
            int f4w = e & 3;
            int bc  = e >> 2;
            int b   = bc >> 7, c = bc & 127;
            dst[e] = src[kbase + (size_t)b * 2048 + (size_t)c * 16 + f4w];
        }
    }

    const short8v* gBv = (const short8v*)gB;
    short8v g_r  = gBv[(((size_t)(0 * 2 + reg) * 64 + x) * 4 + ytile) * 64 + lane];
    short8v g_i  = gBv[(((size_t)(1 * 2 + reg) * 64 + x) * 4 + ytile) * 64 + lane];
    short8v g_ni = gBv[(((size_t)(2 * 2 + reg) * 64 + x) * 4 + ytile) * 64 + lane];

    const short8v* bAv = (const short8v*)bA;
    size_t aR = (((size_t)(0 * 2 + reg) * 4 + itile) * 128) * 64 + lane;
    size_t aI = (((size_t)(1 * 2 + reg) * 4 + itile) * 128) * 64 + lane;

    float tr[4][4], ti[4][4];
#pragma unroll
    for (int q = 0; q < 4; ++q)
#pragma unroll
        for (int b = 0; b < 4; ++b) { tr[q][b] = 0.f; ti[q][b] = 0.f; }

    __syncthreads();     // XFh tile ready

#pragma unroll 2
    for (int c = 0; c < 128; ++c) {
        short8v av = bAv[aR + (size_t)c * 64];
        short8v aw = bAv[aI + (size_t)c * 64];
        float4v z4 = {0.f, 0.f, 0.f, 0.f};
        float4v wr = __builtin_amdgcn_mfma_f32_16x16x32_bf16(av, g_r, z4, 0, 0, 0);
        wr = __builtin_amdgcn_mfma_f32_16x16x32_bf16(aw, g_ni, wr, 0, 0, 0);
        float4v wi = __builtin_amdgcn_mfma_f32_16x16x32_bf16(av, g_i, z4, 0, 0, 0);
        wi = __builtin_amdgcn_mfma_f32_16x16x32_bf16(aw, g_r, wi, 0, 0, 0);
#pragma unroll
        for (int b = 0; b < 4; ++b) {
            unsigned int xw = xfs[b][c][ylane];
            float xr = bf2f((unsigned short)(xw & 0xFFFFu));
            float xi = bf2f((unsigned short)(xw >> 16));
#pragma unroll
            for (int q = 0; q < 4; ++q) {
                tr[q][b] = fmaf(wr[q], xr, fmaf(-wi[q], xi, tr[q][b]));
                ti[q][b] = fmaf(wr[q], xi, fmaf( wi[q], xr, ti[q][b]));
            }
        }
    }

    // write t (bf16-hi) into LDS B-frag layout: [pl][g = i>>3][n = b*16+ylane][e = i&7]
    {
        int gidx = itile * 2 + (qg >> 1);
        int e0 = (qg & 1) * 4;
#pragma unroll
        for (int b = 0; b < 4; ++b) {
            int n = b * 16 + ylane;
            short rh[4], ih[4];
#pragma unroll
            for (int q = 0; q < 4; ++q) {
                rh[q] = (short)f2bf(tr[q][b]);
                ih[q] = (short)f2bf(ti[q][b]);
            }
            *(short4*)&ts[((0 * 8 + gidx) * 66 + n) * 8 + e0] = make_short4(rh[0], rh[1], rh[2], rh[3]);
            *(short4*)&ts[((1 * 8 + gidx) * 66 + n) * 8 + e0] = make_short4(ih[0], ih[1], ih[2], ih[3]);
        }
    }
    __syncthreads();

    // a-epilogue MFMA: OF[o, b, y0+m] = sum_i a[o,i] t[i, b, m]
    const short8v* tsv = (const short8v*)ts;
    const short8v* AFvE = (const short8v*)(AFa + (size_t)reg * 3 * 2 * 8 * 512);
    const size_t PLAe = 2 * 8 * 64;
    float4v eR[2][4], eI[2][4];
#pragma unroll
    for (int rtl = 0; rtl < 2; ++rtl)
#pragma unroll
        for (int nt = 0; nt < 4; ++nt) {
            eR[rtl][nt] = (float4v){0.f, 0.f, 0.f, 0.f};
            eI[rtl][nt] = (float4v){0.f, 0.f, 0.f, 0.f};
        }
#pragma unroll
    for (int kc = 0; kc < 2; ++kc) {
        int gi = kc * 4 + qg;               // i-group for this lane's k-slice
        short8v Brh[4], Bih[4];
#pragma unroll
        for (int nt = 0; nt < 4; ++nt) {
            Brh[nt] = tsv[(0 * 8 + gi) * 66 + nt * 16 + ylane];
            Bih[nt] = tsv[(1 * 8 + gi) * 66 + nt * 16 + ylane];
        }
#pragma unroll
        for (int rtl = 0; rtl < 2; ++rtl) {
            size_t ab = ((size_t)kc * 8 + itile * 2 + rtl) * 64 + lane;
            short8v Ar  = AFvE[0 * PLAe + ab];
            short8v Ai  = AFvE[1 * PLAe + ab];
            short8v Ani = AFvE[2 * PLAe + ab];
#pragma unroll
            for (int nt = 0; nt < 4; ++nt) {
                float4v r_ = eR[rtl][nt];
                r_ = __builtin_amdgcn_mfma_f32_16x16x32_bf16(Ar,  Brh[nt], r_, 0, 0, 0);
                r_ = __builtin_amdgcn_mfma_f32_16x16x32_bf16(Ani, Bih[nt], r_, 0, 0, 0);
                eR[rtl][nt] = r_;
                float4v i_ = eI[rtl][nt];
                i_ = __builtin_amdgcn_mfma_f32_16x16x32_bf16(Ai, Brh[nt], i_, 0, 0, 0);
                i_ = __builtin_amdgcn_mfma_f32_16x16x32_bf16(Ar, Bih[nt], i_, 0, 0, 0);
                eI[rtl][nt] = i_;
            }
        }
    }
#pragma unroll
    for (int rtl = 0; rtl < 2; ++rtl) {
        int o0 = (itile * 2 + rtl) * 16 + qg * 4;
#pragma unroll
        for (int nt = 0; nt < 4; ++nt) {
#pragma unroll
            for (int q = 0; q < 4; ++q) {
                unsigned int pw = (unsigned int)f2bf(eR[rtl][nt][q])
                                | ((unsigned int)f2bf(eI[rtl][nt][q]) << 16);
                OFh[(size_t)k * 32768 + (size_t)nt * 8192 + (size_t)(o0 + q) * 64 + y0 + ylane] = pw;
            }
        }
    }
}

// FUSED IH-GEMM + inverse-W MFMA. Block = one bo (b*128+o), 512 threads (8 waves).
__global__ __launch_bounds__(512) void k_ihinv(const unsigned short* __restrict__ AF2,
                                               const unsigned int* __restrict__ OFh,
                                               const unsigned short* __restrict__ EF,
                                               float* __restrict__ out) {
    constexpr int SG = 16, KC = 4, RTOT = 16;
    __shared__ __align__(16) unsigned short zs[2 * 256 * 64];     // 64 KB
    __shared__ __align__(16) unsigned short bs[2 * SG * 16 * 8];  // 8 KB
    int t = threadIdx.x;
    int wave = t >> 6, lane = t & 63;
    int colp = lane & 15, rowq = lane >> 4;
    int rt0 = wave * 2;
    int bo = blockIdx.x;
    size_t p0 = (size_t)bo * 64;
    const short8v* AFv = (const short8v*)AF2;
    const short8v* bsv = (const short8v*)bs;
    const size_t PLA = (size_t)KC * RTOT * 64;

    for (int pt = 0; pt < 4; ++pt) {
        __syncthreads();
        {   // stage B tile from OFh (packed): 512 threads x 4 rows each
            int li = t & 15, g = (t >> 4) & 15, half = t >> 8;
            int e0 = half * 4;
            short rh[4], ih[4];
#pragma unroll
            for (int j = 0; j < 4; ++j) {
                unsigned int w = OFh[(size_t)(g * 8 + e0 + j) * P_ + p0 + pt * 16 + li];
                rh[j] = (short)(w & 0xFFFFu);
                ih[j] = (short)(w >> 16);
            }
            int base = (g * 16 + li) * 8 + e0;
            *(short4*)&bs[0 * 2048 + base] = make_short4(rh[0], rh[1], rh[2], rh[3]);
            *(short4*)&bs[1 * 2048 + base] = make_short4(ih[0], ih[1], ih[2], ih[3]);
        }
        __syncthreads();
        float4v accR[2], accI[2];
#pragma unroll
        for (int rt = 0; rt < 2; ++rt) {
            accR[rt] = (float4v){0.f, 0.f, 0.f, 0.f};
            accI[rt] = (float4v){0.f, 0.f, 0.f, 0.f};
        }
#pragma unroll
        for (int kc = 0; kc < KC; ++kc) {
            int gi = kc * 4 + rowq;
            short8v Brh = bsv[((0 * SG + gi) << 4) + colp];
            short8v Bih = bsv[((1 * SG + gi) << 4) + colp];
#pragma unroll
            for (int rt = 0; rt < 2; ++rt) {
                size_t ab = ((size_t)kc * RTOT + rt0 + rt) * 64 + lane;
                short8v Ac  = AFv[0 * PLA + ab];
                short8v As  = AFv[1 * PLA + ab];
                short8v Ans = AFv[2 * PLA + ab];
                float4v r_ = accR[rt];
                r_ = __builtin_amdgcn_mfma_f32_16x16x32_bf16(Ac,  Brh, r_, 0, 0, 0);
                r_ = __builtin_amdgcn_mfma_f32_16x16x32_bf16(Ans, Bih, r_, 0, 0, 0);
                accR[rt] = r_;
                float4v i_ = accI[rt];
                i_ = __builtin_amdgcn_mfma_f32_16x16x32_bf16(As, Brh, i_, 0, 0, 0);
                i_ = __builtin_amdgcn_mfma_f32_16x16x32_bf16(Ac, Bih, i_, 0, 0, 0);
                accI[rt] = i_;
            }
        }
#pragma unroll
        for (int rt = 0; rt < 2; ++rt)
#pragma unroll
            for (int q = 0; q < 4; ++q) {
                int h = (rt0 + rt) * 16 + rowq * 4 + q;
                int kwsw = (pt * 16 + colp) ^ ((h & 7) << 3);
                zs[h * 64 + kwsw] = (unsigned short)f2bf(accR[rt][q]);
                zs[16384 + h * 64 + kwsw] = (unsigned short)f2bf(accI[rt][q]);
            }
    }
    __syncthreads();

    const short8v* EFv = (const short8v*)EF;
    for (int nt = 0; nt < 16; ++nt) {
        short8v Er0  = EFv[((0 * 2 + 0) * 16 + nt) * 64 + lane];
        short8v Er1  = EFv[((0 * 2 + 1) * 16 + nt) * 64 + lane];
        short8v nEi0 = EFv[((1 * 2 + 0) * 16 + nt) * 64 + lane];
        short8v nEi1 = EFv[((1 * 2 + 1) * 16 + nt) * 64 + lane];
#pragma unroll
        for (int mtl = 0; mtl < 2; ++mtl) {
            int h0 = (wave * 2 + mtl) * 16;
            int hA = h0 + colp;
            int sw = (hA & 7) << 3;
            short8v Zr0 = *(const short8v*)&zs[hA * 64 + ((8 * rowq) ^ sw)];
            short8v Zr1 = *(const short8v*)&zs[hA * 64 + ((32 + 8 * rowq) ^ sw)];
            short8v Zi0 = *(const short8v*)&zs[16384 + hA * 64 + ((8 * rowq) ^ sw)];
            short8v Zi1 = *(const short8v*)&zs[16384 + hA * 64 + ((32 + 8 * rowq) ^ sw)];
            float4v acc = {0.f, 0.f, 0.f, 0.f};
            acc = __builtin_amdgcn_mfma_f32_16x16x32_bf16(Zr0, Er0,  acc, 0, 0, 0);
            acc = __builtin_amdgcn_mfma_f32_16x16x32_bf16(Zi0, nEi0, acc, 0, 0, 0);
            acc = __builtin_amdgcn_mfma_f32_16x16x32_bf16(Zr1, Er1,  acc, 0, 0, 0);
            acc = __builtin_amdgcn_mfma_f32_16x16x32_bf16(Zi1, nEi1, acc, 0, 0, 0);
            size_t ob = ((size_t)bo * 256 + h0 + rowq * 4) * 256 + nt * 16 + colp;
#pragma unroll
            for (int q = 0; q < 4; ++q)
                out[ob + (size_t)q * 256] = acc[q];
        }
    }
}

extern "C" void kernel_launch(void* const* d_in, const int* in_sizes, int n_in,
                              void* d_out, int out_size, void* d_ws, size_t ws_size,
                              hipStream_t stream) {
    const float* x  = (const float*)d_in[0];
    const float* a1 = (const float*)d_in[1];
    const float* b1 = (const float*)d_in[2];
    const float* c1 = (const float*)d_in[3];
    const float* d1 = (const float*)d_in[4];
    const float* a2 = (const float*)d_in[5];
    const float* b2 = (const float*)d_in[6];
    const float* c2 = (const float*)d_in[7];
    const float* d2 = (const float*)d_in[8];
    float* out = (float*)d_out;
    float* wsf = (float*)d_ws;

    if (ws_size < WS_FLOATS * sizeof(float)) return;

    unsigned short* Yt  = (unsigned short*)(wsf + oYT);
    unsigned int*   XFh = (unsigned int*)(wsf + oXF);
    unsigned int*   OFh = (unsigned int*)(wsf + oOF);
    float2*         G   = (float2*)(wsf + oOF);          // G lives in OF region until prepBG
    unsigned short* BF  = (unsigned short*)(wsf + oBF);
    unsigned short* AF1 = (unsigned short*)(wsf + oAF1);
    unsigned short* AF2 = (unsigned short*)(wsf + oAF2);
    unsigned short* bA  = (unsigned short*)(wsf + oYT);  // after cmfma1, Yt region is dead
    unsigned short* gB  = bA + 1048576;
    unsigned short* AFa = (unsigned short*)(wsf + oG);
    unsigned short* EF  = (unsigned short*)(wsf + oEF);

    k_prepTables<<<1216, 256, 0, stream>>>(a1, a2, AF1, AF2, BF, EF, AFa);
    k_g<<<1024, 256, 0, stream>>>(c1, d1, c2, d2, G);
    k_stage1m<<<1024, 256, 0, stream>>>(x, BF, Yt);
    k_cmfma<256, 2><<<512, 256, 0, stream>>>(AF1, Yt, XFh);
    k_prepBG<<<7168, 256, 0, stream>>>(b1, b2, G, bA, gB);
    k_contract2<<<512, 256, 0, stream>>>(XFh, bA, gB, AFa, OFh);  // overwrites G (dead)
    k_ihinv<<<512, 512, 0, stream>>>(AF2, OFh, EF, out);

    (void)in_sizes; (void)n_in; (void)out_size;
}

// Round 24
// 155.200 us; speedup vs baseline: 1.5636x; 1.1440x over previous
//
#include <hip/hip_runtime.h>
#include <math.h>

// FactorizedSpectralConv2d: pruned-DFT + TT contraction, MFMA everywhere matmul-shaped.
// ALL operands bf16-hi (fp32 MFMA accumulation). Fusions: fwd W-DFT+H-DFT (Y via LDS),
// contract w-GEMM+a-epilogue (t via LDS), IH-GEMM+invW (Z via LDS).
//
//   k_prepTables: bf16-hi A-frag tables FH/IH (3 planes) + FW B-frags (2 planes) +
//                 invW E B-frags + a A-frags (3 planes)
//   k_g         : g[r][j][x][y] = sum_k cc[j,x,k]*dc[k,y]  (G in then-dead OF region)
//   k_prepBG    : bf16 frag tables for b (A) and g (B) from G
//   k_fwd       : FUSED per-bc block: phase1 Y = W-DFT(x) -> LDS bf16-hi;
//                 phase2 XFh[k][bc,kw] = FH . Y  (packed bf16-hi u32)
//   k_contract2 : FUSED w-GEMM + fp32 t-update + a-epilogue MFMA (t via LDS) -> OFh
//   k_ihinv     : FUSED per-bo block: phase1 Z = IH·OFh; phase2 out = Re(Z . E)

#define TWO_PI 6.28318530717958647692f

typedef __attribute__((ext_vector_type(8))) short short8v;   // 8 bf16 (4 VGPRs)
typedef __attribute__((ext_vector_type(4))) float float4v;   // MFMA C/D

namespace {
constexpr size_t P_ = 32768;            // B*C*KW pixel batch width

// workspace float offsets
constexpr size_t oYT = 0;                     // bA/gB (contract frag tables)
constexpr size_t oXF = 16777216;              // XFh u32 16.7MB (packed bf16-hi re|im)
constexpr size_t oOF = 25165824;              // G f2 (2MB, until prepBG) then OFh u32 16.7MB
constexpr size_t oBF = 33554432;              // FW B-frag table: 32768 shorts (2 planes)
constexpr size_t oAF1 = 33587200;             // FH frags: 98304 shorts (3 planes)
constexpr size_t oAF2 = 33685504;             // IH frags: 98304 shorts (3 planes)
constexpr size_t oG  = 33792000;              // AFa (49152 shorts) then EF (32768 shorts)
constexpr size_t oEF = oG + 262144;
constexpr size_t WS_FLOATS = oG + 524288;     // ~137.3 MB
}

__device__ __forceinline__ unsigned short f2bf(float f) {   // RNE float->bf16 bits
    unsigned int u = __float_as_uint(f);
    unsigned int r = (u + 0x7FFFu + ((u >> 16) & 1u)) >> 16;
    return (unsigned short)r;
}
__device__ __forceinline__ float bf2f(unsigned short b) {
    return __uint_as_float(((unsigned int)b) << 16);
}

// All static fragment tables in one launch (same layout as round 21).
__global__ __launch_bounds__(256) void k_prepTables(const float* __restrict__ a1,
                                                    const float* __restrict__ a2,
                                                    unsigned short* __restrict__ AF1,
                                                    unsigned short* __restrict__ AF2,
                                                    unsigned short* __restrict__ BF,
                                                    unsigned short* __restrict__ EF,
                                                    unsigned short* __restrict__ AFa) {
    int idx = blockIdx.x * 256 + threadIdx.x;      // < 311296
    if (idx < 196608) {
        int tbl = (idx >= 98304);
        int id = tbl ? (idx - 98304) : idx;        // < 98304
        int e = id & 7, lane = (id >> 3) & 63;
        int pl = id >> 15;                          // 0..2
        float ang;
        if (!tbl) {
            int rt = (id >> 9) & 7, kc = (id >> 12) & 7;
            int r = rt * 16 + (lane & 15);             // k-row (128)
            int s = kc * 32 + 8 * (lane >> 4) + e;     // h (256)
            int kh = r + ((r >= 64) ? 128 : 0);
            int ph = (kh * s) & 255;
            ang = -TWO_PI * (float)ph / 256.0f;
        } else {
            int rt = (id >> 9) & 15, kc = (id >> 13) & 3;
            int r = rt * 16 + (lane & 15);             // h (256)
            int s = kc * 32 + 8 * (lane >> 4) + e;     // k (128)
            int kh = s + ((s >= 64) ? 128 : 0);
            int ph = (kh * r) & 255;
            ang = TWO_PI * (float)ph / 256.0f;
        }
        float sn, cs; sincosf(ang, &sn, &cs);
        float v = (pl == 0) ? cs : ((pl == 1) ? sn : -sn);
        (tbl ? AF2 : AF1)[id] = f2bf(v);
    } else if (idx < 229376) {
        int id = idx - 196608;                          // < 32768
        int e = id & 7, lane = (id >> 3) & 63;
        int nt = (id >> 9) & 3, kc = (id >> 11) & 7;
        int pl = id >> 14;                              // 0..1
        int kw = nt * 16 + (lane & 15);
        int w = kc * 32 + 8 * (lane >> 4) + e;
        int ph = (w * kw) & 255;
        float ang = -TWO_PI * (float)ph / 256.0f;
        float sn, cs; sincosf(ang, &sn, &cs);
        BF[id] = f2bf((pl == 0) ? cs : sn);
    } else if (idx < 262144) {
        int id = idx - 229376;                          // < 32768
        int e = id & 7, lane = (id >> 3) & 63;
        int nt = (id >> 9) & 15, kc = (id >> 13) & 1, pl = id >> 14;
        int w = nt * 16 + (lane & 15);
        int kw = kc * 32 + 8 * (lane >> 4) + e;
        int ph = (kw * w) & 255;
        float ang = TWO_PI * (float)ph / 256.0f;
        float sn, cs; sincosf(ang, &sn, &cs);
        float sc = ((kw == 0) ? 1.0f : 2.0f) / 65536.0f;
        float v = (pl == 0) ? (sc * cs) : (-sc * sn);
        EF[id] = f2bf(v);
    } else {
        int id = idx - 262144;                          // < 49152
        int e = id & 7, lane = (id >> 3) & 63;
        int rt = (id >> 9) & 7, kc = (id >> 12) & 1;
        int plreg = id >> 13;                           // 0..5
        int reg = plreg / 3, pl = plreg % 3;
        int o = rt * 16 + (lane & 15);
        int i = kc * 32 + 8 * (lane >> 4) + e;
        const float* ap = reg ? a2 : a1;
        float ar = ap[(o * 64 + i) * 2 + 0];
        float ai = ap[(o * 64 + i) * 2 + 1];
        float v = (pl == 0) ? ar : ((pl == 1) ? ai : -ai);
        AFa[id] = f2bf(v);
    }
}

// g[r][j][x][y] = sum_k cc[j,x,k] * dc[k,y]
__global__ __launch_bounds__(256) void k_g(const float* __restrict__ c1, const float* __restrict__ d1,
                                           const float* __restrict__ c2, const float* __restrict__ d2,
                                           float2* __restrict__ G) {
    int idx = blockIdx.x * 256 + threadIdx.x;      // < 262144
    int r = idx >> 17;
    int rem = idx & 131071;
    int j = rem >> 12;
    int xy = rem & 4095;
    int xm = xy >> 6, ym = xy & 63;
    const float* cp = r ? c2 : c1;
    const float* dp = r ? d2 : d1;
    float sr = 0.f, si = 0.f;
    for (int kk = 0; kk < 32; ++kk) {
        float cr = cp[((j * 64 + xm) * 32 + kk) * 2 + 0];
        float ci = cp[((j * 64 + xm) * 32 + kk) * 2 + 1];
        float dr = dp[(kk * 64 + ym) * 2 + 0];
        float di = dp[(kk * 64 + ym) * 2 + 1];
        sr = fmaf(cr, dr, fmaf(-ci, di, sr));
        si = fmaf(cr, di, fmaf( ci, dr, si));
    }
    G[(size_t)(r * 32 + j) * 4096 + xy] = make_float2(sr, si);
}

// bf16 fragment tables for the contraction (reads G).
__global__ __launch_bounds__(256) void k_prepBG(const float* __restrict__ b1, const float* __restrict__ b2,
                                                const float2* __restrict__ G,
                                                unsigned short* __restrict__ bA,
                                                unsigned short* __restrict__ gB) {
    size_t idx = (size_t)blockIdx.x * 256 + threadIdx.x;
    if (idx < 1048576) {
        int e     = idx & 7;
        int lane  = (idx >> 3) & 63;
        int c     = (idx >> 9) & 127;
        int itile = (idx >> 16) & 3;
        int reg   = (idx >> 18) & 1;
        int plane = (idx >> 19) & 1;
        int i = itile * 16 + (lane & 15);
        int j = 8 * (lane >> 4) + e;
        const float* bp = reg ? b2 : b1;
        float v = bp[((size_t)(i * 128 + c) * 32 + j) * 2 + plane];
        bA[idx] = f2bf(v);
    } else if (idx < 1048576 + 786432) {
        size_t i2 = idx - 1048576;
        int e     = i2 & 7;
        int lane  = (i2 >> 3) & 63;
        int ytile = (i2 >> 9) & 3;
        int x     = (i2 >> 11) & 63;
        int reg   = (i2 >> 17) & 1;
        int plane = (int)(i2 >> 18);           // 0,1,2
        int y = ytile * 16 + (lane & 15);
        int j = 8 * (lane >> 4) + e;
        float2 gv = G[(size_t)(reg * 32 + j) * 4096 + x * 64 + y];
        float v = (plane == 0) ? gv.x : ((plane == 1) ? gv.y : -gv.y);
        gB[i2] = f2bf(v);
    }
}

// FUSED forward DFT: per-bc block, 512 threads (8 waves).
// Phase 1: Y[h][kw] = sum_w x[bc,h,w] FW[w,kw] (MFMA; BF staged 16KB/phase) -> LDS bf16-hi
//          ys[pl][g=h>>3][kw][e=h&7].
// Phase 2: XFh[k][bc*64+kw] = sum_h FH[k][h] Y[h][kw]  (AF1 hi-A x ys hi-B, 4 MFMAs/(kc,nt)).
__global__ __launch_bounds__(512) void k_fwd(const float* __restrict__ x,
                                             const unsigned short* __restrict__ BF,
                                             const unsigned short* __restrict__ AF1,
                                             unsigned int* __restrict__ XFh) {
    __shared__ __align__(16) unsigned short es[8192];           // 16 KB FW staging
    __shared__ __align__(16) unsigned short ys[2 * 32 * 64 * 8]; // 64 KB Y (B-frag layout)
    int t = threadIdx.x;
    int wave = t >> 6, lane = t & 63;
    int colp = lane & 15, rowq = lane >> 4;
    int bc = blockIdx.x;
    const short8v* esv = (const short8v*)es;

    // ---- phase 1: W-DFT ----
    float4v accR[2][4], accI[2][4];
#pragma unroll
    for (int rt = 0; rt < 2; ++rt)
#pragma unroll
        for (int nt = 0; nt < 4; ++nt) {
            accR[rt][nt] = (float4v){0.f, 0.f, 0.f, 0.f};
            accI[rt][nt] = (float4v){0.f, 0.f, 0.f, 0.f};
        }

    const float* xb0 = x + (size_t)bc * 65536 + (size_t)((2 * wave + 0) * 16 + colp) * 256 + 8 * rowq;
    const float* xb1 = x + (size_t)bc * 65536 + (size_t)((2 * wave + 1) * 16 + colp) * 256 + 8 * rowq;
    float4 nv[2][2];
    nv[0][0] = *(const float4*)(xb0);  nv[0][1] = *(const float4*)(xb0 + 4);
    nv[1][0] = *(const float4*)(xb1);  nv[1][1] = *(const float4*)(xb1 + 4);

    const float4* bf4 = (const float4*)BF;
    for (int ph = 0; ph < 4; ++ph) {
        __syncthreads();
        {   // stage 2 planes x 2 kcl x 4 nt x 64 lanes = 1024 float4 = 16 KB (512 thr x 2)
#pragma unroll
            for (int i = 0; i < 2; ++i) {
                int idx = t + 512 * i;
                int li  = idx & 63;
                int nt  = (idx >> 6) & 3;
                int kcl = (idx >> 8) & 1;
                int pl  = idx >> 9;            // 0..1
                ((float4*)es)[idx] = bf4[((size_t)(pl * 8 + ph * 2 + kcl) * 4 + nt) * 64 + li];
            }
        }
        __syncthreads();
        for (int kcl = 0; kcl < 2; ++kcl) {
            int kc = ph * 2 + kcl;
            short8v xh[2];
#pragma unroll
            for (int rt = 0; rt < 2; ++rt) {
                float4 v0 = nv[rt][0], v1 = nv[rt][1];
                float vv[8] = {v0.x, v0.y, v0.z, v0.w, v1.x, v1.y, v1.z, v1.w};
#pragma unroll
                for (int j = 0; j < 8; ++j) xh[rt][j] = (short)f2bf(vv[j]);
            }
            if (kc < 7) {
                nv[0][0] = *(const float4*)(xb0 + (kc + 1) * 32);
                nv[0][1] = *(const float4*)(xb0 + (kc + 1) * 32 + 4);
                nv[1][0] = *(const float4*)(xb1 + (kc + 1) * 32);
                nv[1][1] = *(const float4*)(xb1 + (kc + 1) * 32 + 4);
            }
#pragma unroll
            for (int nt = 0; nt < 4; ++nt) {
                short8v Bch = esv[((0 * 2 + kcl) * 4 + nt) * 64 + lane];
                short8v Bsh = esv[((1 * 2 + kcl) * 4 + nt) * 64 + lane];
#pragma unroll
                for (int rt = 0; rt < 2; ++rt) {
                    accR[rt][nt] = __builtin_amdgcn_mfma_f32_16x16x32_bf16(xh[rt], Bch, accR[rt][nt], 0, 0, 0);
                    accI[rt][nt] = __builtin_amdgcn_mfma_f32_16x16x32_bf16(xh[rt], Bsh, accI[rt][nt], 0, 0, 0);
                }
            }
        }
    }

    // write Y (bf16-hi) to LDS in phase-2 B-frag layout
    {
#pragma unroll
        for (int rt = 0; rt < 2; ++rt) {
            int mt = 2 * wave + rt;
            int g = mt * 2 + (rowq >> 1);
            int e0 = (rowq & 1) * 4;
#pragma unroll
            for (int nt = 0; nt < 4; ++nt) {
                int kw = nt * 16 + colp;
                float4v R = accR[rt][nt], I = accI[rt][nt];
                short rh[4], ih[4];
#pragma unroll
                for (int q = 0; q < 4; ++q) {
                    rh[q] = (short)f2bf(R[q]);
                    ih[q] = (short)f2bf(I[q]);
                }
                *(short4*)&ys[((0 * 32 + g) * 64 + kw) * 8 + e0] = make_short4(rh[0], rh[1], rh[2], rh[3]);
                *(short4*)&ys[((1 * 32 + g) * 64 + kw) * 8 + e0] = make_short4(ih[0], ih[1], ih[2], ih[3]);
            }
        }
    }
    __syncthreads();

    // ---- phase 2: FH GEMM (M=128 k, wave = one 16-k mtile; N=64 kw; K=256 h) ----
    const short8v* AFv = (const short8v*)AF1;
    const short8v* ysv = (const short8v*)ys;
    const size_t PLA = (size_t)8 * 8 * 64;
    float4v eR[4], eI[4];
#pragma unroll
    for (int nt = 0; nt < 4; ++nt) {
        eR[nt] = (float4v){0.f, 0.f, 0.f, 0.f};
        eI[nt] = (float4v){0.f, 0.f, 0.f, 0.f};
    }
#pragma unroll
    for (int kc2 = 0; kc2 < 8; ++kc2) {
        int g = kc2 * 4 + rowq;
        short8v Brh[4], Bih[4];
#pragma unroll
        for (int nt = 0; nt < 4; ++nt) {
            Brh[nt] = ysv[(0 * 32 + g) * 64 + nt * 16 + colp];
            Bih[nt] = ysv[(1 * 32 + g) * 64 + nt * 16 + colp];
        }
        size_t ab = ((size_t)kc2 * 8 + wave) * 64 + lane;
        short8v Ac  = AFv[0 * PLA + ab];
        short8v As  = AFv[1 * PLA + ab];
        short8v Ans = AFv[2 * PLA + ab];
#pragma unroll
        for (int nt = 0; nt < 4; ++nt) {
            float4v r_ = eR[nt];
            r_ = __builtin_amdgcn_mfma_f32_16x16x32_bf16(Ac,  Brh[nt], r_, 0, 0, 0);
            r_ = __builtin_amdgcn_mfma_f32_16x16x32_bf16(Ans, Bih[nt], r_, 0, 0, 0);
            eR[nt] = r_;
            float4v i_ = eI[nt];
            i_ = __builtin_amdgcn_mfma_f32_16x16x32_bf16(As, Brh[nt], i_, 0, 0, 0);
            i_ = __builtin_amdgcn_mfma_f32_16x16x32_bf16(Ac, Bih[nt], i_, 0, 0, 0);
            eI[nt] = i_;
        }
    }
#pragma unroll
    for (int nt = 0; nt < 4; ++nt) {
#pragma unroll
        for (int q = 0; q < 4; ++q) {
            int k = wave * 16 + rowq * 4 + q;
            unsigned int pw = (unsigned int)f2bf(eR[nt][q])
                            | ((unsigned int)f2bf(eI[nt][q]) << 16);
            XFh[(size_t)k * P_ + (size_t)bc * 64 + nt * 16 + colp] = pw;
        }
    }
}

// FUSED contract: w-GEMM + fp32 t-update + a-epilogue MFMA (t via LDS) -> OFh.
__global__ __launch_bounds__(256) void k_contract2(const unsigned int* __restrict__ XFh,
                                                   const unsigned short* __restrict__ bA,
                                                   const unsigned short* __restrict__ gB,
                                                   const unsigned short* __restrict__ AFa,
                                                   unsigned int* __restrict__ OFh) {
    __shared__ __align__(16) unsigned int xfs[4][128][16];        // 32 KB
    __shared__ __align__(16) unsigned short ts[2 * 8 * 66 * 8];   // ~17 KB
    int t = threadIdx.x;
    int k = blockIdx.x >> 2;
    int ytile = blockIdx.x & 3;
    int y0 = ytile << 4;
    int reg = (k >= 64) ? 1 : 0;
    int x = k & 63;
    int itile = t >> 6, lane = t & 63;
    int ylane = lane & 15, qg = lane >> 4;

    {   // stage XFh tile: 2048 uint4, 8 per thread
        const uint4* src = (const uint4*)XFh;
        uint4* dst = (uint4*)xfs;
        size_t kbase = ((size_t)k * 32768 + y0) >> 2;   // uint4 units
#pragma unroll
        for (int i = 0; i < 8; ++i) {
            int e = t + 256 * i;
            int f4w = e & 3;
            int bc  = e >> 2;
            int b   = bc >> 7, c = bc & 127;
            dst[e] = src[kbase + (size_t)b * 2048 + (size_t)c * 16 + f4w];
        }
    }

    const short8v* gBv = (const short8v*)gB;
    short8v g_r  = gBv[(((size_t)(0 * 2 + reg) * 64 + x) * 4 + ytile) * 64 + lane];
    short8v g_i  = gBv[(((size_t)(1 * 2 + reg) * 64 + x) * 4 + ytile) * 64 + lane];
    short8v g_ni = gBv[(((size_t)(2 * 2 + reg) * 64 + x) * 4 + ytile) * 64 + lane];

    const short8v* bAv = (const short8v*)bA;
    size_t aR = (((size_t)(0 * 2 + reg) * 4 + itile) * 128) * 64 + lane;
    size_t aI = (((size_t)(1 * 2 + reg) * 4 + itile) * 128) * 64 + lane;

    float tr[4][4], ti[4][4];
#pragma unroll
    for (int q = 0; q < 4; ++q)
#pragma unroll
        for (int b = 0; b < 4; ++b) { tr[q][b] = 0.f; ti[q][b] = 0.f; }

    __syncthreads();     // XFh tile ready

#pragma unroll 2
    for (int c = 0; c < 128; ++c) {
        short8v av = bAv[aR + (size_t)c * 64];
        short8v aw = bAv[aI + (size_t)c * 64];
        float4v z4 = {0.f, 0.f, 0.f, 0.f};
        float4v wr = __builtin_amdgcn_mfma_f32_16x16x32_bf16(av, g_r, z4, 0, 0, 0);
        wr = __builtin_amdgcn_mfma_f32_16x16x32_bf16(aw, g_ni, wr, 0, 0, 0);
        float4v wi = __builtin_amdgcn_mfma_f32_16x16x32_bf16(av, g_i, z4, 0, 0, 0);
        wi = __builtin_amdgcn_mfma_f32_16x16x32_bf16(aw, g_r, wi, 0, 0, 0);
#pragma unroll
        for (int b = 0; b < 4; ++b) {
            unsigned int xw = xfs[b][c][ylane];
            float xr = bf2f((unsigned short)(xw & 0xFFFFu));
            float xi = bf2f((unsigned short)(xw >> 16));
#pragma unroll
            for (int q = 0; q < 4; ++q) {
                tr[q][b] = fmaf(wr[q], xr, fmaf(-wi[q], xi, tr[q][b]));
                ti[q][b] = fmaf(wr[q], xi, fmaf( wi[q], xr, ti[q][b]));
            }
        }
    }

    // write t (bf16-hi) into LDS B-frag layout: [pl][g = i>>3][n = b*16+ylane][e = i&7]
    {
        int gidx = itile * 2 + (qg >> 1);
        int e0 = (qg & 1) * 4;
#pragma unroll
        for (int b = 0; b < 4; ++b) {
            int n = b * 16 + ylane;
            short rh[4], ih[4];
#pragma unroll
            for (int q = 0; q < 4; ++q) {
                rh[q] = (short)f2bf(tr[q][b]);
                ih[q] = (short)f2bf(ti[q][b]);
            }
            *(short4*)&ts[((0 * 8 + gidx) * 66 + n) * 8 + e0] = make_short4(rh[0], rh[1], rh[2], rh[3]);
            *(short4*)&ts[((1 * 8 + gidx) * 66 + n) * 8 + e0] = make_short4(ih[0], ih[1], ih[2], ih[3]);
        }
    }
    __syncthreads();

    // a-epilogue MFMA: OF[o, b, y0+m] = sum_i a[o,i] t[i, b, m]
    const short8v* tsv = (const short8v*)ts;
    const short8v* AFvE = (const short8v*)(AFa + (size_t)reg * 3 * 2 * 8 * 512);
    const size_t PLAe = 2 * 8 * 64;
    float4v eR[2][4], eI[2][4];
#pragma unroll
    for (int rtl = 0; rtl < 2; ++rtl)
#pragma unroll
        for (int nt = 0; nt < 4; ++nt) {
            eR[rtl][nt] = (float4v){0.f, 0.f, 0.f, 0.f};
            eI[rtl][nt] = (float4v){0.f, 0.f, 0.f, 0.f};
        }
#pragma unroll
    for (int kc = 0; kc < 2; ++kc) {
        int gi = kc * 4 + qg;               // i-group for this lane's k-slice
        short8v Brh[4], Bih[4];
#pragma unroll
        for (int nt = 0; nt < 4; ++nt) {
            Brh[nt] = tsv[(0 * 8 + gi) * 66 + nt * 16 + ylane];
            Bih[nt] = tsv[(1 * 8 + gi) * 66 + nt * 16 + ylane];
        }
#pragma unroll
        for (int rtl = 0; rtl < 2; ++rtl) {
            size_t ab = ((size_t)kc * 8 + itile * 2 + rtl) * 64 + lane;
            short8v Ar  = AFvE[0 * PLAe + ab];
            short8v Ai  = AFvE[1 * PLAe + ab];
            short8v Ani = AFvE[2 * PLAe + ab];
#pragma unroll
            for (int nt = 0; nt < 4; ++nt) {
                float4v r_ = eR[rtl][nt];
                r_ = __builtin_amdgcn_mfma_f32_16x16x32_bf16(Ar,  Brh[nt], r_, 0, 0, 0);
                r_ = __builtin_amdgcn_mfma_f32_16x16x32_bf16(Ani, Bih[nt], r_, 0, 0, 0);
                eR[rtl][nt] = r_;
                float4v i_ = eI[rtl][nt];
                i_ = __builtin_amdgcn_mfma_f32_16x16x32_bf16(Ai, Brh[nt], i_, 0, 0, 0);
                i_ = __builtin_amdgcn_mfma_f32_16x16x32_bf16(Ar, Bih[nt], i_, 0, 0, 0);
                eI[rtl][nt] = i_;
            }
        }
    }
#pragma unroll
    for (int rtl = 0; rtl < 2; ++rtl) {
        int o0 = (itile * 2 + rtl) * 16 + qg * 4;
#pragma unroll
        for (int nt = 0; nt < 4; ++nt) {
#pragma unroll
            for (int q = 0; q < 4; ++q) {
                unsigned int pw = (unsigned int)f2bf(eR[rtl][nt][q])
                                | ((unsigned int)f2bf(eI[rtl][nt][q]) << 16);
                OFh[(size_t)k * 32768 + (size_t)nt * 8192 + (size_t)(o0 + q) * 64 + y0 + ylane] = pw;
            }
        }
    }
}

// FUSED IH-GEMM + inverse-W MFMA. Block = one bo (b*128+o), 512 threads (8 waves).
__global__ __launch_bounds__(512) void k_ihinv(const unsigned short* __restrict__ AF2,
                                               const unsigned int* __restrict__ OFh,
                                               const unsigned short* __restrict__ EF,
                                               float* __restrict__ out) {
    constexpr int SG = 16, KC = 4, RTOT = 16;
    __shared__ __align__(16) unsigned short zs[2 * 256 * 64];     // 64 KB
    __shared__ __align__(16) unsigned short bs[2 * SG * 16 * 8];  // 8 KB
    int t = threadIdx.x;
    int wave = t >> 6, lane = t & 63;
    int colp = lane & 15, rowq = lane >> 4;
    int rt0 = wave * 2;
    int bo = blockIdx.x;
    size_t p0 = (size_t)bo * 64;
    const short8v* AFv = (const short8v*)AF2;
    const short8v* bsv = (const short8v*)bs;
    const size_t PLA = (size_t)KC * RTOT * 64;

    for (int pt = 0; pt < 4; ++pt) {
        __syncthreads();
        {   // stage B tile from OFh (packed): 512 threads x 4 rows each
            int li = t & 15, g = (t >> 4) & 15, half = t >> 8;
            int e0 = half * 4;
            short rh[4], ih[4];
#pragma unroll
            for (int j = 0; j < 4; ++j) {
                unsigned int w = OFh[(size_t)(g * 8 + e0 + j) * P_ + p0 + pt * 16 + li];
                rh[j] = (short)(w & 0xFFFFu);
                ih[j] = (short)(w >> 16);
            }
            int base = (g * 16 + li) * 8 + e0;
            *(short4*)&bs[0 * 2048 + base] = make_short4(rh[0], rh[1], rh[2], rh[3]);
            *(short4*)&bs[1 * 2048 + base] = make_short4(ih[0], ih[1], ih[2], ih[3]);
        }
        __syncthreads();
        float4v accR[2], accI[2];
#pragma unroll
        for (int rt = 0; rt < 2; ++rt) {
            accR[rt] = (float4v){0.f, 0.f, 0.f, 0.f};
            accI[rt] = (float4v){0.f, 0.f, 0.f, 0.f};
        }
#pragma unroll
        for (int kc = 0; kc < KC; ++kc) {
            int gi = kc * 4 + rowq;
            short8v Brh = bsv[((0 * SG + gi) << 4) + colp];
            short8v Bih = bsv[((1 * SG + gi) << 4) + colp];
#pragma unroll
            for (int rt = 0; rt < 2; ++rt) {
                size_t ab = ((size_t)kc * RTOT + rt0 + rt) * 64 + lane;
                short8v Ac  = AFv[0 * PLA + ab];
                short8v As  = AFv[1 * PLA + ab];
                short8v Ans = AFv[2 * PLA + ab];
                float4v r_ = accR[rt];
                r_ = __builtin_amdgcn_mfma_f32_16x16x32_bf16(Ac,  Brh, r_, 0, 0, 0);
                r_ = __builtin_amdgcn_mfma_f32_16x16x32_bf16(Ans, Bih, r_, 0, 0, 0);
                accR[rt] = r_;
                float4v i_ = accI[rt];
                i_ = __builtin_amdgcn_mfma_f32_16x16x32_bf16(As, Brh, i_, 0, 0, 0);
                i_ = __builtin_amdgcn_mfma_f32_16x16x32_bf16(Ac, Bih, i_, 0, 0, 0);
                accI[rt] = i_;
            }
        }
#pragma unroll
        for (int rt = 0; rt < 2; ++rt)
#pragma unroll
            for (int q = 0; q < 4; ++q) {
                int h = (rt0 + rt) * 16 + rowq * 4 + q;
                int kwsw = (pt * 16 + colp) ^ ((h & 7) << 3);
                zs[h * 64 + kwsw] = (unsigned short)f2bf(accR[rt][q]);
                zs[16384 + h * 64 + kwsw] = (unsigned short)f2bf(accI[rt][q]);
            }
    }
    __syncthreads();

    const short8v* EFv = (const short8v*)EF;
    for (int nt = 0; nt < 16; ++nt) {
        short8v Er0  = EFv[((0 * 2 + 0) * 16 + nt) * 64 + lane];
        short8v Er1  = EFv[((0 * 2 + 1) * 16 + nt) * 64 + lane];
        short8v nEi0 = EFv[((1 * 2 + 0) * 16 + nt) * 64 + lane];
        short8v nEi1 = EFv[((1 * 2 + 1) * 16 + nt) * 64 + lane];
#pragma unroll
        for (int mtl = 0; mtl < 2; ++mtl) {
            int h0 = (wave * 2 + mtl) * 16;
            int hA = h0 + colp;
            int sw = (hA & 7) << 3;
            short8v Zr0 = *(const short8v*)&zs[hA * 64 + ((8 * rowq) ^ sw)];
            short8v Zr1 = *(const short8v*)&zs[hA * 64 + ((32 + 8 * rowq) ^ sw)];
            short8v Zi0 = *(const short8v*)&zs[16384 + hA * 64 + ((8 * rowq) ^ sw)];
            short8v Zi1 = *(const short8v*)&zs[16384 + hA * 64 + ((32 + 8 * rowq) ^ sw)];
            float4v acc = {0.f, 0.f, 0.f, 0.f};
            acc = __builtin_amdgcn_mfma_f32_16x16x32_bf16(Zr0, Er0,  acc, 0, 0, 0);
            acc = __builtin_amdgcn_mfma_f32_16x16x32_bf16(Zi0, nEi0, acc, 0, 0, 0);
            acc = __builtin_amdgcn_mfma_f32_16x16x32_bf16(Zr1, Er1,  acc, 0, 0, 0);
            acc = __builtin_amdgcn_mfma_f32_16x16x32_bf16(Zi1, nEi1, acc, 0, 0, 0);
            size_t ob = ((size_t)bo * 256 + h0 + rowq * 4) * 256 + nt * 16 + colp;
#pragma unroll
            for (int q = 0; q < 4; ++q)
                out[ob + (size_t)q * 256] = acc[q];
        }
    }
}

extern "C" void kernel_launch(void* const* d_in, const int* in_sizes, int n_in,
                              void* d_out, int out_size, void* d_ws, size_t ws_size,
                              hipStream_t stream) {
    const float* x  = (const float*)d_in[0];
    const float* a1 = (const float*)d_in[1];
    const float* b1 = (const float*)d_in[2];
    const float* c1 = (const float*)d_in[3];
    const float* d1 = (const float*)d_in[4];
    const float* a2 = (const float*)d_in[5];
    const float* b2 = (const float*)d_in[6];
    const float* c2 = (const float*)d_in[7];
    const float* d2 = (const float*)d_in[8];
    float* out = (float*)d_out;
    float* wsf = (float*)d_ws;

    if (ws_size < WS_FLOATS * sizeof(float)) return;

    unsigned int*   XFh = (unsigned int*)(wsf + oXF);
    unsigned int*   OFh = (unsigned int*)(wsf + oOF);
    float2*         G   = (float2*)(wsf + oOF);          // G lives in OF region until prepBG
    unsigned short* BF  = (unsigned short*)(wsf + oBF);
    unsigned short* AF1 = (unsigned short*)(wsf + oAF1);
    unsigned short* AF2 = (unsigned short*)(wsf + oAF2);
    unsigned short* bA  = (unsigned short*)(wsf + oYT);
    unsigned short* gB  = bA + 1048576;
    unsigned short* AFa = (unsigned short*)(wsf + oG);
    unsigned short* EF  = (unsigned short*)(wsf + oEF);

    k_prepTables<<<1216, 256, 0, stream>>>(a1, a2, AF1, AF2, BF, EF, AFa);
    k_g<<<1024, 256, 0, stream>>>(c1, d1, c2, d2, G);
    k_fwd<<<512, 512, 0, stream>>>(x, BF, AF1, XFh);
    k_prepBG<<<7168, 256, 0, stream>>>(b1, b2, G, bA, gB);
    k_contract2<<<512, 256, 0, stream>>>(XFh, bA, gB, AFa, OFh);  // overwrites G (dead)
    k_ihinv<<<512, 512, 0, stream>>>(AF2, OFh, EF, out);

    (void)in_sizes; (void)n_in; (void)out_size;
}

// Round 25
// 152.492 us; speedup vs baseline: 1.5914x; 1.0178x over previous
//
#include <hip/hip_runtime.h>
#include <math.h>

// FactorizedSpectralConv2d: pruned-DFT + TT contraction, MFMA everywhere matmul-shaped.
// ALL operands bf16-hi (fp32 MFMA accumulation). Fusions: fwd W-DFT+H-DFT (Y via LDS),
// contract w-GEMM+a-epilogue (t via LDS), IH-GEMM+invW (Z via LDS).
//
//   k_prepAll   : bf16-hi A-frag tables FH/IH (3 planes) + FW B-frags (2 planes) +
//                 invW E B-frags + a A-frags (3 planes) + G = sum_k c*d (fp32, OF region)
//   k_prepBG    : bf16 frag tables for b (A) and g (B) from G
//   k_fwd       : FUSED per-bc block: phase1 Y = W-DFT(x) -> LDS bf16-hi;
//                 phase2 XFh[k][bc,kw] = FH . Y  (packed bf16-hi u32)
//   k_contract2 : FUSED w-GEMM + fp32 t-update + a-epilogue MFMA (t via LDS) -> OFh
//   k_ihinv     : FUSED per-bo block: phase1 Z = IH·OFh; phase2 out = Re(Z . E)

#define TWO_PI 6.28318530717958647692f

typedef __attribute__((ext_vector_type(8))) short short8v;   // 8 bf16 (4 VGPRs)
typedef __attribute__((ext_vector_type(4))) float float4v;   // MFMA C/D

namespace {
constexpr size_t P_ = 32768;            // B*C*KW pixel batch width

// workspace float offsets
constexpr size_t oYT = 0;                     // bA/gB (contract frag tables)
constexpr size_t oXF = 16777216;              // XFh u32 16.7MB (packed bf16-hi re|im)
constexpr size_t oOF = 25165824;              // G f2 (2MB, until prepBG) then OFh u32 16.7MB
constexpr size_t oBF = 33554432;              // FW B-frag table: 32768 shorts (2 planes)
constexpr size_t oAF1 = 33587200;             // FH frags: 98304 shorts (3 planes)
constexpr size_t oAF2 = 33685504;             // IH frags: 98304 shorts (3 planes)
constexpr size_t oG  = 33792000;              // AFa (49152 shorts) then EF (32768 shorts)
constexpr size_t oEF = oG + 262144;
constexpr size_t WS_FLOATS = oG + 524288;     // ~137.3 MB
}

__device__ __forceinline__ unsigned short f2bf(float f) {   // RNE float->bf16 bits
    unsigned int u = __float_as_uint(f);
    unsigned int r = (u + 0x7FFFu + ((u >> 16) & 1u)) >> 16;
    return (unsigned short)r;
}
__device__ __forceinline__ float bf2f(unsigned short b) {
    return __uint_as_float(((unsigned int)b) << 16);
}

// All static fragment tables + G in one launch:
//   [0, 98304)        AF1 (FH) bf16-hi A-frags, 3 planes: cos, sin, -sin
//   [98304, 196608)   AF2 (IH) bf16-hi A-frags, 3 planes
//   [196608, 229376)  BF: FW B-frags, 2 planes (cos, sin) bf16-hi
//   [229376, 262144)  EF: invW twiddle B-frags (2 planes Er, -Ei; bf16-hi, scaled)
//   [262144, 311296)  AFa: a1/a2 bf16-hi A-frags, 3 planes per reg: ar, ai, -ai
//   [311296, 573440)  G[r][j][x][y] = sum_k cc[j,x,k]*dc[k,y]  (fp32 f2)
__global__ __launch_bounds__(256) void k_prepAll(const float* __restrict__ a1,
                                                 const float* __restrict__ a2,
                                                 const float* __restrict__ c1,
                                                 const float* __restrict__ d1,
                                                 const float* __restrict__ c2,
                                                 const float* __restrict__ d2,
                                                 unsigned short* __restrict__ AF1,
                                                 unsigned short* __restrict__ AF2,
                                                 unsigned short* __restrict__ BF,
                                                 unsigned short* __restrict__ EF,
                                                 unsigned short* __restrict__ AFa,
                                                 float2* __restrict__ G) {
    int idx = blockIdx.x * 256 + threadIdx.x;      // < 573440
    if (idx < 196608) {
        int tbl = (idx >= 98304);
        int id = tbl ? (idx - 98304) : idx;        // < 98304
        int e = id & 7, lane = (id >> 3) & 63;
        int pl = id >> 15;                          // 0..2
        float ang;
        if (!tbl) {
            int rt = (id >> 9) & 7, kc = (id >> 12) & 7;
            int r = rt * 16 + (lane & 15);             // k-row (128)
            int s = kc * 32 + 8 * (lane >> 4) + e;     // h (256)
            int kh = r + ((r >= 64) ? 128 : 0);
            int ph = (kh * s) & 255;
            ang = -TWO_PI * (float)ph / 256.0f;
        } else {
            int rt = (id >> 9) & 15, kc = (id >> 13) & 3;
            int r = rt * 16 + (lane & 15);             // h (256)
            int s = kc * 32 + 8 * (lane >> 4) + e;     // k (128)
            int kh = s + ((s >= 64) ? 128 : 0);
            int ph = (kh * r) & 255;
            ang = TWO_PI * (float)ph / 256.0f;
        }
        float sn, cs; sincosf(ang, &sn, &cs);
        float v = (pl == 0) ? cs : ((pl == 1) ? sn : -sn);
        (tbl ? AF2 : AF1)[id] = f2bf(v);
    } else if (idx < 229376) {
        int id = idx - 196608;                          // < 32768
        int e = id & 7, lane = (id >> 3) & 63;
        int nt = (id >> 9) & 3, kc = (id >> 11) & 7;
        int pl = id >> 14;                              // 0..1
        int kw = nt * 16 + (lane & 15);
        int w = kc * 32 + 8 * (lane >> 4) + e;
        int ph = (w * kw) & 255;
        float ang = -TWO_PI * (float)ph / 256.0f;
        float sn, cs; sincosf(ang, &sn, &cs);
        BF[id] = f2bf((pl == 0) ? cs : sn);
    } else if (idx < 262144) {
        int id = idx - 229376;                          // < 32768
        int e = id & 7, lane = (id >> 3) & 63;
        int nt = (id >> 9) & 15, kc = (id >> 13) & 1, pl = id >> 14;
        int w = nt * 16 + (lane & 15);
        int kw = kc * 32 + 8 * (lane >> 4) + e;
        int ph = (kw * w) & 255;
        float ang = TWO_PI * (float)ph / 256.0f;
        float sn, cs; sincosf(ang, &sn, &cs);
        float sc = ((kw == 0) ? 1.0f : 2.0f) / 65536.0f;
        float v = (pl == 0) ? (sc * cs) : (-sc * sn);
        EF[id] = f2bf(v);
    } else if (idx < 311296) {
        int id = idx - 262144;                          // < 49152
        int e = id & 7, lane = (id >> 3) & 63;
        int rt = (id >> 9) & 7, kc = (id >> 12) & 1;
        int plreg = id >> 13;                           // 0..5
        int reg = plreg / 3, pl = plreg % 3;
        int o = rt * 16 + (lane & 15);
        int i = kc * 32 + 8 * (lane >> 4) + e;
        const float* ap = reg ? a2 : a1;
        float ar = ap[(o * 64 + i) * 2 + 0];
        float ai = ap[(o * 64 + i) * 2 + 1];
        float v = (pl == 0) ? ar : ((pl == 1) ? ai : -ai);
        AFa[id] = f2bf(v);
    } else {
        int id = idx - 311296;                          // < 262144
        int r = id >> 17;
        int rem = id & 131071;
        int j = rem >> 12;
        int xy = rem & 4095;
        int xm = xy >> 6, ym = xy & 63;
        const float* cp = r ? c2 : c1;
        const float* dp = r ? d2 : d1;
        float sr = 0.f, si = 0.f;
        for (int kk = 0; kk < 32; ++kk) {
            float cr = cp[((j * 64 + xm) * 32 + kk) * 2 + 0];
            float ci = cp[((j * 64 + xm) * 32 + kk) * 2 + 1];
            float dr = dp[(kk * 64 + ym) * 2 + 0];
            float di = dp[(kk * 64 + ym) * 2 + 1];
            sr = fmaf(cr, dr, fmaf(-ci, di, sr));
            si = fmaf(cr, di, fmaf( ci, dr, si));
        }
        G[(size_t)(r * 32 + j) * 4096 + xy] = make_float2(sr, si);
    }
}

// bf16 fragment tables for the contraction (reads G).
__global__ __launch_bounds__(256) void k_prepBG(const float* __restrict__ b1, const float* __restrict__ b2,
                                                const float2* __restrict__ G,
                                                unsigned short* __restrict__ bA,
                                                unsigned short* __restrict__ gB) {
    size_t idx = (size_t)blockIdx.x * 256 + threadIdx.x;
    if (idx < 1048576) {
        int e     = idx & 7;
        int lane  = (idx >> 3) & 63;
        int c     = (idx >> 9) & 127;
        int itile = (idx >> 16) & 3;
        int reg   = (idx >> 18) & 1;
        int plane = (idx >> 19) & 1;
        int i = itile * 16 + (lane & 15);
        int j = 8 * (lane >> 4) + e;
        const float* bp = reg ? b2 : b1;
        float v = bp[((size_t)(i * 128 + c) * 32 + j) * 2 + plane];
        bA[idx] = f2bf(v);
    } else if (idx < 1048576 + 786432) {
        size_t i2 = idx - 1048576;
        int e     = i2 & 7;
        int lane  = (i2 >> 3) & 63;
        int ytile = (i2 >> 9) & 3;
        int x     = (i2 >> 11) & 63;
        int reg   = (i2 >> 17) & 1;
        int plane = (int)(i2 >> 18);           // 0,1,2
        int y = ytile * 16 + (lane & 15);
        int j = 8 * (lane >> 4) + e;
        float2 gv = G[(size_t)(reg * 32 + j) * 4096 + x * 64 + y];
        float v = (plane == 0) ? gv.x : ((plane == 1) ? gv.y : -gv.y);
        gB[i2] = f2bf(v);
    }
}

// FUSED forward DFT: per-bc block, 512 threads (8 waves).
__global__ __launch_bounds__(512) void k_fwd(const float* __restrict__ x,
                                             const unsigned short* __restrict__ BF,
                                             const unsigned short* __restrict__ AF1,
                                             unsigned int* __restrict__ XFh) {
    __shared__ __align__(16) unsigned short es[8192];           // 16 KB FW staging
    __shared__ __align__(16) unsigned short ys[2 * 32 * 64 * 8]; // 64 KB Y (B-frag layout)
    int t = threadIdx.x;
    int wave = t >> 6, lane = t & 63;
    int colp = lane & 15, rowq = lane >> 4;
    int bc = blockIdx.x;
    const short8v* esv = (const short8v*)es;

    // ---- phase 1: W-DFT ----
    float4v accR[2][4], accI[2][4];
#pragma unroll
    for (int rt = 0; rt < 2; ++rt)
#pragma unroll
        for (int nt = 0; nt < 4; ++nt) {
            accR[rt][nt] = (float4v){0.f, 0.f, 0.f, 0.f};
            accI[rt][nt] = (float4v){0.f, 0.f, 0.f, 0.f};
        }

    const float* xb0 = x + (size_t)bc * 65536 + (size_t)((2 * wave + 0) * 16 + colp) * 256 + 8 * rowq;
    const float* xb1 = x + (size_t)bc * 65536 + (size_t)((2 * wave + 1) * 16 + colp) * 256 + 8 * rowq;
    float4 nv[2][2];
    nv[0][0] = *(const float4*)(xb0);  nv[0][1] = *(const float4*)(xb0 + 4);
    nv[1][0] = *(const float4*)(xb1);  nv[1][1] = *(const float4*)(xb1 + 4);

    const float4* bf4 = (const float4*)BF;
    for (int ph = 0; ph < 4; ++ph) {
        __syncthreads();
        {
#pragma unroll
            for (int i = 0; i < 2; ++i) {
                int idx = t + 512 * i;
                int li  = idx & 63;
                int nt  = (idx >> 6) & 3;
                int kcl = (idx >> 8) & 1;
                int pl  = idx >> 9;            // 0..1
                ((float4*)es)[idx] = bf4[((size_t)(pl * 8 + ph * 2 + kcl) * 4 + nt) * 64 + li];
            }
        }
        __syncthreads();
        for (int kcl = 0; kcl < 2; ++kcl) {
            int kc = ph * 2 + kcl;
            short8v xh[2];
#pragma unroll
            for (int rt = 0; rt < 2; ++rt) {
                float4 v0 = nv[rt][0], v1 = nv[rt][1];
                float vv[8] = {v0.x, v0.y, v0.z, v0.w, v1.x, v1.y, v1.z, v1.w};
#pragma unroll
                for (int j = 0; j < 8; ++j) xh[rt][j] = (short)f2bf(vv[j]);
            }
            if (kc < 7) {
                nv[0][0] = *(const float4*)(xb0 + (kc + 1) * 32);
                nv[0][1] = *(const float4*)(xb0 + (kc + 1) * 32 + 4);
                nv[1][0] = *(const float4*)(xb1 + (kc + 1) * 32);
                nv[1][1] = *(const float4*)(xb1 + (kc + 1) * 32 + 4);
            }
#pragma unroll
            for (int nt = 0; nt < 4; ++nt) {
                short8v Bch = esv[((0 * 2 + kcl) * 4 + nt) * 64 + lane];
                short8v Bsh = esv[((1 * 2 + kcl) * 4 + nt) * 64 + lane];
#pragma unroll
                for (int rt = 0; rt < 2; ++rt) {
                    accR[rt][nt] = __builtin_amdgcn_mfma_f32_16x16x32_bf16(xh[rt], Bch, accR[rt][nt], 0, 0, 0);
                    accI[rt][nt] = __builtin_amdgcn_mfma_f32_16x16x32_bf16(xh[rt], Bsh, accI[rt][nt], 0, 0, 0);
                }
            }
        }
    }

    // write Y (bf16-hi) to LDS in phase-2 B-frag layout
    {
#pragma unroll
        for (int rt = 0; rt < 2; ++rt) {
            int mt = 2 * wave + rt;
            int g = mt * 2 + (rowq >> 1);
            int e0 = (rowq & 1) * 4;
#pragma unroll
            for (int nt = 0; nt < 4; ++nt) {
                int kw = nt * 16 + colp;
                float4v R = accR[rt][nt], I = accI[rt][nt];
                short rh[4], ih[4];
#pragma unroll
                for (int q = 0; q < 4; ++q) {
                    rh[q] = (short)f2bf(R[q]);
                    ih[q] = (short)f2bf(I[q]);
                }
                *(short4*)&ys[((0 * 32 + g) * 64 + kw) * 8 + e0] = make_short4(rh[0], rh[1], rh[2], rh[3]);
                *(short4*)&ys[((1 * 32 + g) * 64 + kw) * 8 + e0] = make_short4(ih[0], ih[1], ih[2], ih[3]);
            }
        }
    }
    __syncthreads();

    // ---- phase 2: FH GEMM (M=128 k, wave = one 16-k mtile; N=64 kw; K=256 h) ----
    const short8v* AFv = (const short8v*)AF1;
    const short8v* ysv = (const short8v*)ys;
    const size_t PLA = (size_t)8 * 8 * 64;
    float4v eR[4], eI[4];
#pragma unroll
    for (int nt = 0; nt < 4; ++nt) {
        eR[nt] = (float4v){0.f, 0.f, 0.f, 0.f};
        eI[nt] = (float4v){0.f, 0.f, 0.f, 0.f};
    }
#pragma unroll
    for (int kc2 = 0; kc2 < 8; ++kc2) {
        int g = kc2 * 4 + rowq;
        short8v Brh[4], Bih[4];
#pragma unroll
        for (int nt = 0; nt < 4; ++nt) {
            Brh[nt] = ysv[(0 * 32 + g) * 64 + nt * 16 + colp];
            Bih[nt] = ysv[(1 * 32 + g) * 64 + nt * 16 + colp];
        }
        size_t ab = ((size_t)kc2 * 8 + wave) * 64 + lane;
        short8v Ac  = AFv[0 * PLA + ab];
        short8v As  = AFv[1 * PLA + ab];
        short8v Ans = AFv[2 * PLA + ab];
#pragma unroll
        for (int nt = 0; nt < 4; ++nt) {
            float4v r_ = eR[nt];
            r_ = __builtin_amdgcn_mfma_f32_16x16x32_bf16(Ac,  Brh[nt], r_, 0, 0, 0);
            r_ = __builtin_amdgcn_mfma_f32_16x16x32_bf16(Ans, Bih[nt], r_, 0, 0, 0);
            eR[nt] = r_;
            float4v i_ = eI[nt];
            i_ = __builtin_amdgcn_mfma_f32_16x16x32_bf16(As, Brh[nt], i_, 0, 0, 0);
            i_ = __builtin_amdgcn_mfma_f32_16x16x32_bf16(Ac, Bih[nt], i_, 0, 0, 0);
            eI[nt] = i_;
        }
    }
#pragma unroll
    for (int nt = 0; nt < 4; ++nt) {
#pragma unroll
        for (int q = 0; q < 4; ++q) {
            int k = wave * 16 + rowq * 4 + q;
            unsigned int pw = (unsigned int)f2bf(eR[nt][q])
                            | ((unsigned int)f2bf(eI[nt][q]) << 16);
            XFh[(size_t)k * P_ + (size_t)bc * 64 + nt * 16 + colp] = pw;
        }
    }
}

// FUSED contract: w-GEMM + fp32 t-update + a-epilogue MFMA (t via LDS) -> OFh.
__global__ __launch_bounds__(256) void k_contract2(const unsigned int* __restrict__ XFh,
                                                   const unsigned short* __restrict__ bA,
                                                   const unsigned short* __restrict__ gB,
                                                   const unsigned short* __restrict__ AFa,
                                                   unsigned int* __restrict__ OFh) {
    __shared__ __align__(16) unsigned int xfs[4][128][16];        // 32 KB
    __shared__ __align__(16) unsigned short ts[2 * 8 * 66 * 8];   // ~17 KB
    int t = threadIdx.x;
    int k = blockIdx.x >> 2;
    int ytile = blockIdx.x & 3;
    int y0 = ytile << 4;
    int reg = (k >= 64) ? 1 : 0;
    int x = k & 63;
    int itile = t >> 6, lane = t & 63;
    int ylane = lane & 15, qg = lane >> 4;

    {   // stage XFh tile: 2048 uint4, 8 per thread
        const uint4* src = (const uint4*)XFh;
        uint4* dst = (uint4*)xfs;
        size_t kbase = ((size_t)k * 32768 + y0) >> 2;   // uint4 units
#pragma unroll
        for (int i = 0; i < 8; ++i) {
            int e = t + 256 * i;
            int f4w = e & 3;
            int bc  = e >> 2;
            int b   = bc >> 7, c = bc & 127;
            dst[e] = src[kbase + (size_t)b * 2048 + (size_t)c * 16 + f4w];
        }
    }

    const short8v* gBv = (const short8v*)gB;
    short8v g_r  = gBv[(((size_t)(0 * 2 + reg) * 64 + x) * 4 + ytile) * 64 + lane];
    short8v g_i  = gBv[(((size_t)(1 * 2 + reg) * 64 + x) * 4 + ytile) * 64 + lane];
    short8v g_ni = gBv[(((size_t)(2 * 2 + reg) * 64 + x) * 4 + ytile) * 64 + lane];

    const short8v* bAv = (const short8v*)bA;
    size_t aR = (((size_t)(0 * 2 + reg) * 4 + itile) * 128) * 64 + lane;
    size_t aI = (((size_t)(1 * 2 + reg) * 4 + itile) * 128) * 64 + lane;

    float tr[4][4], ti[4][4];
#pragma unroll
    for (int q = 0; q < 4; ++q)
#pragma unroll
        for (int b = 0; b < 4; ++b) { tr[q][b] = 0.f; ti[q][b] = 0.f; }

    __syncthreads();     // XFh tile ready

#pragma unroll 2
    for (int c = 0; c < 128; ++c) {
        short8v av = bAv[aR + (size_t)c * 64];
        short8v aw = bAv[aI + (size_t)c * 64];
        float4v z4 = {0.f, 0.f, 0.f, 0.f};
        float4v wr = __builtin_amdgcn_mfma_f32_16x16x32_bf16(av, g_r, z4, 0, 0, 0);
        wr = __builtin_amdgcn_mfma_f32_16x16x32_bf16(aw, g_ni, wr, 0, 0, 0);
        float4v wi = __builtin_amdgcn_mfma_f32_16x16x32_bf16(av, g_i, z4, 0, 0, 0);
        wi = __builtin_amdgcn_mfma_f32_16x16x32_bf16(aw, g_r, wi, 0, 0, 0);
#pragma unroll
        for (int b = 0; b < 4; ++b) {
            unsigned int xw = xfs[b][c][ylane];
            float xr = bf2f((unsigned short)(xw & 0xFFFFu));
            float xi = bf2f((unsigned short)(xw >> 16));
#pragma unroll
            for (int q = 0; q < 4; ++q) {
                tr[q][b] = fmaf(wr[q], xr, fmaf(-wi[q], xi, tr[q][b]));
                ti[q][b] = fmaf(wr[q], xi, fmaf( wi[q], xr, ti[q][b]));
            }
        }
    }

    // write t (bf16-hi) into LDS B-frag layout: [pl][g = i>>3][n = b*16+ylane][e = i&7]
    {
        int gidx = itile * 2 + (qg >> 1);
        int e0 = (qg & 1) * 4;
#pragma unroll
        for (int b = 0; b < 4; ++b) {
            int n = b * 16 + ylane;
            short rh[4], ih[4];
#pragma unroll
            for (int q = 0; q < 4; ++q) {
                rh[q] = (short)f2bf(tr[q][b]);
                ih[q] = (short)f2bf(ti[q][b]);
            }
            *(short4*)&ts[((0 * 8 + gidx) * 66 + n) * 8 + e0] = make_short4(rh[0], rh[1], rh[2], rh[3]);
            *(short4*)&ts[((1 * 8 + gidx) * 66 + n) * 8 + e0] = make_short4(ih[0], ih[1], ih[2], ih[3]);
        }
    }
    __syncthreads();

    // a-epilogue MFMA: OF[o, b, y0+m] = sum_i a[o,i] t[i, b, m]
    const short8v* tsv = (const short8v*)ts;
    const short8v* AFvE = (const short8v*)(AFa + (size_t)reg * 3 * 2 * 8 * 512);
    const size_t PLAe = 2 * 8 * 64;
    float4v eR[2][4], eI[2][4];
#pragma unroll
    for (int rtl = 0; rtl < 2; ++rtl)
#pragma unroll
        for (int nt = 0; nt < 4; ++nt) {
            eR[rtl][nt] = (float4v){0.f, 0.f, 0.f, 0.f};
            eI[rtl][nt] = (float4v){0.f, 0.f, 0.f, 0.f};
        }
#pragma unroll
    for (int kc = 0; kc < 2; ++kc) {
        int gi = kc * 4 + qg;               // i-group for this lane's k-slice
        short8v Brh[4], Bih[4];
#pragma unroll
        for (int nt = 0; nt < 4; ++nt) {
            Brh[nt] = tsv[(0 * 8 + gi) * 66 + nt * 16 + ylane];
            Bih[nt] = tsv[(1 * 8 + gi) * 66 + nt * 16 + ylane];
        }
#pragma unroll
        for (int rtl = 0; rtl < 2; ++rtl) {
            size_t ab = ((size_t)kc * 8 + itile * 2 + rtl) * 64 + lane;
            short8v Ar  = AFvE[0 * PLAe + ab];
            short8v Ai  = AFvE[1 * PLAe + ab];
            short8v Ani = AFvE[2 * PLAe + ab];
#pragma unroll
            for (int nt = 0; nt < 4; ++nt) {
                float4v r_ = eR[rtl][nt];
                r_ = __builtin_amdgcn_mfma_f32_16x16x32_bf16(Ar,  Brh[nt], r_, 0, 0, 0);
                r_ = __builtin_amdgcn_mfma_f32_16x16x32_bf16(Ani, Bih[nt], r_, 0, 0, 0);
                eR[rtl][nt] = r_;
                float4v i_ = eI[rtl][nt];
                i_ = __builtin_amdgcn_mfma_f32_16x16x32_bf16(Ai, Brh[nt], i_, 0, 0, 0);
                i_ = __builtin_amdgcn_mfma_f32_16x16x32_bf16(Ar, Bih[nt], i_, 0, 0, 0);
                eI[rtl][nt] = i_;
            }
        }
    }
#pragma unroll
    for (int rtl = 0; rtl < 2; ++rtl) {
        int o0 = (itile * 2 + rtl) * 16 + qg * 4;
#pragma unroll
        for (int nt = 0; nt < 4; ++nt) {
#pragma unroll
            for (int q = 0; q < 4; ++q) {
                unsigned int pw = (unsigned int)f2bf(eR[rtl][nt][q])
                                | ((unsigned int)f2bf(eI[rtl][nt][q]) << 16);
                OFh[(size_t)k * 32768 + (size_t)nt * 8192 + (size_t)(o0 + q) * 64 + y0 + ylane] = pw;
            }
        }
    }
}

// FUSED IH-GEMM + inverse-W MFMA. Block = one bo (b*128+o), 512 threads (8 waves).
__global__ __launch_bounds__(512) void k_ihinv(const unsigned short* __restrict__ AF2,
                                               const unsigned int* __restrict__ OFh,
                                               const unsigned short* __restrict__ EF,
                                               float* __restrict__ out) {
    constexpr int SG = 16, KC = 4, RTOT = 16;
    __shared__ __align__(16) unsigned short zs[2 * 256 * 64];     // 64 KB
    __shared__ __align__(16) unsigned short bs[2 * SG * 16 * 8];  // 8 KB
    int t = threadIdx.x;
    int wave = t >> 6, lane = t & 63;
    int colp = lane & 15, rowq = lane >> 4;
    int rt0 = wave * 2;
    int bo = blockIdx.x;
    size_t p0 = (size_t)bo * 64;
    const short8v* AFv = (const short8v*)AF2;
    const short8v* bsv = (const short8v*)bs;
    const size_t PLA = (size_t)KC * RTOT * 64;

    for (int pt = 0; pt < 4; ++pt) {
        __syncthreads();
        {   // stage B tile from OFh (packed): 512 threads x 4 rows each
            int li = t & 15, g = (t >> 4) & 15, half = t >> 8;
            int e0 = half * 4;
            short rh[4], ih[4];
#pragma unroll
            for (int j = 0; j < 4; ++j) {
                unsigned int w = OFh[(size_t)(g * 8 + e0 + j) * P_ + p0 + pt * 16 + li];
                rh[j] = (short)(w & 0xFFFFu);
                ih[j] = (short)(w >> 16);
            }
            int base = (g * 16 + li) * 8 + e0;
            *(short4*)&bs[0 * 2048 + base] = make_short4(rh[0], rh[1], rh[2], rh[3]);
            *(short4*)&bs[1 * 2048 + base] = make_short4(ih[0], ih[1], ih[2], ih[3]);
        }
        __syncthreads();
        float4v accR[2], accI[2];
#pragma unroll
        for (int rt = 0; rt < 2; ++rt) {
            accR[rt] = (float4v){0.f, 0.f, 0.f, 0.f};
            accI[rt] = (float4v){0.f, 0.f, 0.f, 0.f};
        }
#pragma unroll
        for (int kc = 0; kc < KC; ++kc) {
            int gi = kc * 4 + rowq;
            short8v Brh = bsv[((0 * SG + gi) << 4) + colp];
            short8v Bih = bsv[((1 * SG + gi) << 4) + colp];
#pragma unroll
            for (int rt = 0; rt < 2; ++rt) {
                size_t ab = ((size_t)kc * RTOT + rt0 + rt) * 64 + lane;
                short8v Ac  = AFv[0 * PLA + ab];
                short8v As  = AFv[1 * PLA + ab];
                short8v Ans = AFv[2 * PLA + ab];
                float4v r_ = accR[rt];
                r_ = __builtin_amdgcn_mfma_f32_16x16x32_bf16(Ac,  Brh, r_, 0, 0, 0);
                r_ = __builtin_amdgcn_mfma_f32_16x16x32_bf16(Ans, Bih, r_, 0, 0, 0);
                accR[rt] = r_;
                float4v i_ = accI[rt];
                i_ = __builtin_amdgcn_mfma_f32_16x16x32_bf16(As, Brh, i_, 0, 0, 0);
                i_ = __builtin_amdgcn_mfma_f32_16x16x32_bf16(Ac, Bih, i_, 0, 0, 0);
                accI[rt] = i_;
            }
        }
#pragma unroll
        for (int rt = 0; rt < 2; ++rt)
#pragma unroll
            for (int q = 0; q < 4; ++q) {
                int h = (rt0 + rt) * 16 + rowq * 4 + q;
                int kwsw = (pt * 16 + colp) ^ ((h & 7) << 3);
                zs[h * 64 + kwsw] = (unsigned short)f2bf(accR[rt][q]);
                zs[16384 + h * 64 + kwsw] = (unsigned short)f2bf(accI[rt][q]);
            }
    }
    __syncthreads();

    const short8v* EFv = (const short8v*)EF;
    for (int nt = 0; nt < 16; ++nt) {
        short8v Er0  = EFv[((0 * 2 + 0) * 16 + nt) * 64 + lane];
        short8v Er1  = EFv[((0 * 2 + 1) * 16 + nt) * 64 + lane];
        short8v nEi0 = EFv[((1 * 2 + 0) * 16 + nt) * 64 + lane];
        short8v nEi1 = EFv[((1 * 2 + 1) * 16 + nt) * 64 + lane];
#pragma unroll
        for (int mtl = 0; mtl < 2; ++mtl) {
            int h0 = (wave * 2 + mtl) * 16;
            int hA = h0 + colp;
            int sw = (hA & 7) << 3;
            short8v Zr0 = *(const short8v*)&zs[hA * 64 + ((8 * rowq) ^ sw)];
            short8v Zr1 = *(const short8v*)&zs[hA * 64 + ((32 + 8 * rowq) ^ sw)];
            short8v Zi0 = *(const short8v*)&zs[16384 + hA * 64 + ((8 * rowq) ^ sw)];
            short8v Zi1 = *(const short8v*)&zs[16384 + hA * 64 + ((32 + 8 * rowq) ^ sw)];
            float4v acc = {0.f, 0.f, 0.f, 0.f};
            acc = __builtin_amdgcn_mfma_f32_16x16x32_bf16(Zr0, Er0,  acc, 0, 0, 0);
            acc = __builtin_amdgcn_mfma_f32_16x16x32_bf16(Zi0, nEi0, acc, 0, 0, 0);
            acc = __builtin_amdgcn_mfma_f32_16x16x32_bf16(Zr1, Er1,  acc, 0, 0, 0);
            acc = __builtin_amdgcn_mfma_f32_16x16x32_bf16(Zi1, nEi1, acc, 0, 0, 0);
            size_t ob = ((size_t)bo * 256 + h0 + rowq * 4) * 256 + nt * 16 + colp;
#pragma unroll
            for (int q = 0; q < 4; ++q)
                out[ob + (size_t)q * 256] = acc[q];
        }
    }
}

extern "C" void kernel_launch(void* const* d_in, const int* in_sizes, int n_in,
                              void* d_out, int out_size, void* d_ws, size_t ws_size,
                              hipStream_t stream) {
    const float* x  = (const float*)d_in[0];
    const float* a1 = (const float*)d_in[1];
    const float* b1 = (const float*)d_in[2];
    const float* c1 = (const float*)d_in[3];
    const float* d1 = (const float*)d_in[4];
    const float* a2 = (const float*)d_in[5];
    const float* b2 = (const float*)d_in[6];
    const float* c2 = (const float*)d_in[7];
    const float* d2 = (const float*)d_in[8];
    float* out = (float*)d_out;
    float* wsf = (float*)d_ws;

    if (ws_size < WS_FLOATS * sizeof(float)) return;

    unsigned int*   XFh = (unsigned int*)(wsf + oXF);
    unsigned int*   OFh = (unsigned int*)(wsf + oOF);
    float2*         G   = (float2*)(wsf + oOF);          // G lives in OF region until prepBG
    unsigned short* BF  = (unsigned short*)(wsf + oBF);
    unsigned short* AF1 = (unsigned short*)(wsf + oAF1);
    unsigned short* AF2 = (unsigned short*)(wsf + oAF2);
    unsigned short* bA  = (unsigned short*)(wsf + oYT);
    unsigned short* gB  = bA + 1048576;
    unsigned short* AFa = (unsigned short*)(wsf + oG);
    unsigned short* EF  = (unsigned short*)(wsf + oEF);

    k_prepAll<<<2240, 256, 0, stream>>>(a1, a2, c1, d1, c2, d2, AF1, AF2, BF, EF, AFa, G);
    k_fwd<<<512, 512, 0, stream>>>(x, BF, AF1, XFh);
    k_prepBG<<<7168, 256, 0, stream>>>(b1, b2, G, bA, gB);
    k_contract2<<<512, 256, 0, stream>>>(XFh, bA, gB, AFa, OFh);  // overwrites G (dead)
    k_ihinv<<<512, 512, 0, stream>>>(AF2, OFh, EF, out);

    (void)in_sizes; (void)n_in; (void)out_size;
}